// Round 2
// baseline (2075.322 us; speedup 1.0000x reference)
//
#include <hip/hip_runtime.h>
#include <hip/hip_bf16.h>
#include <math.h>

#define N_NODES 100000
#define N_EDGES 1600000
#define ORIG    92
#define NBR     41
#define ATOM    64
#define NCONV   3
#define HFEA    128
#define NGRAPH  256
#define ZD      169           // 2*ATOM + NBR
#define TBINS   5120
#define TMAX    10.0f         // beyond d=10 RBF values < 3e-9

__device__ __forceinline__ float softplus_f(float x) {
    return fmaxf(x, 0.0f) + log1pf(expf(-fabsf(x)));
}
__device__ __forceinline__ float sigmoid_f(float x) {
    return 1.0f / (1.0f + expf(-x));
}
// round fp32 -> bf16 bits (RNE)
__device__ __forceinline__ unsigned int bfr(float x) {
    unsigned int u = __float_as_uint(x);
    return (u + 0x7fffu + ((u >> 16) & 1u)) >> 16;
}
__device__ __forceinline__ float bf_lo(unsigned int p) {  // low 16 = gate
    return __uint_as_float(p << 16);
}
__device__ __forceinline__ float bf_hi(unsigned int p) {  // high 16 = core
    return __uint_as_float(p & 0xffff0000u);
}

// h = x @ W_emb + b_emb   [N,92]x[92,64]
__global__ __launch_bounds__(256) void k_embed(const float* __restrict__ x,
                                               const float* __restrict__ W,
                                               const float* __restrict__ b,
                                               float* __restrict__ h) {
    __shared__ float xt[16][ORIG];
    int n0 = blockIdx.x * 16;
    for (int i = threadIdx.x; i < 16 * ORIG; i += 256) {
        int nn = i / ORIG, kk = i - nn * ORIG;
        xt[nn][kk] = x[(n0 + nn) * ORIG + kk];
    }
    __syncthreads();
    int c = threadIdx.x & 63, jg = threadIdx.x >> 6;
    float acc[4];
    float bias = b[c];
#pragma unroll
    for (int j = 0; j < 4; ++j) acc[j] = bias;
    for (int k = 0; k < ORIG; ++k) {
        float w = W[k * ATOM + c];
#pragma unroll
        for (int j = 0; j < 4; ++j) acc[j] += xt[jg * 4 + j][k] * w;
    }
#pragma unroll
    for (int j = 0; j < 4; ++j) h[(n0 + jg * 4 + j) * ATOM + c] = acc[j];
}

__global__ __launch_bounds__(256) void k_dist(const float* __restrict__ ea,
                                              float* __restrict__ dvec) {
    int e = blockIdx.x * 256 + threadIdx.x;
    if (e >= N_EDGES) return;
    float a = ea[3 * e], b = ea[3 * e + 1], c = ea[3 * e + 2];
    dvec[e] = sqrtf(a * a + b * b + c * c);
}

__global__ __launch_bounds__(256) void k_hist(const int* __restrict__ ei,
                                              int* __restrict__ cnt) {
    int e = blockIdx.x * 256 + threadIdx.x;
    if (e < N_EDGES) atomicAdd(&cnt[ei[N_EDGES + e]], 1);
}

// single-block exclusive scan of cnt[N] -> offs[N+1], cursor[N]
__global__ __launch_bounds__(1024) void k_scan(const int* __restrict__ cnt,
                                               int* __restrict__ offs,
                                               int* __restrict__ cursor) {
    __shared__ int part[1024];
    const int CH = (N_NODES + 1023) / 1024;  // 98
    int t = threadIdx.x;
    int lo = t * CH, hi = lo + CH;
    if (hi > N_NODES) hi = N_NODES;
    int s = 0;
    for (int i = lo; i < hi; ++i) s += cnt[i];
    part[t] = s;
    __syncthreads();
    for (int d = 1; d < 1024; d <<= 1) {
        int v = (t >= d) ? part[t - d] : 0;
        __syncthreads();
        part[t] += v;
        __syncthreads();
    }
    int run = part[t] - s;  // exclusive prefix
    for (int i = lo; i < hi; ++i) {
        offs[i] = run;
        cursor[i] = run;
        run += cnt[i];
    }
    if (t == 1023) offs[N_NODES] = part[1023];
}

__global__ __launch_bounds__(256) void k_scatter(const int* __restrict__ ei,
                                                 const float* __restrict__ dvec,
                                                 int* __restrict__ cursor,
                                                 int2* __restrict__ sed) {
    int e = blockIdx.x * 256 + threadIdx.x;
    if (e >= N_EDGES) return;
    int dst = ei[N_EDGES + e];
    int pos = atomicAdd(&cursor[dst], 1);
    int2 v;
    v.x = ei[e];
    v.y = __float_as_int(dvec[e]);
    sed[pos] = v;
}

// Pi[n][c] = pack(h@Wf_i, h@Ws_i)  Pj[n][c] = pack(h@Wf_j, h@Ws_j)  (bf16 pairs)
__global__ __launch_bounds__(256) void k_nodeP(const float* __restrict__ h,
                                               const float* __restrict__ Wf,
                                               const float* __restrict__ Ws,
                                               int l,
                                               unsigned int* __restrict__ Pi,
                                               unsigned int* __restrict__ Pj) {
    __shared__ float ht[8][ATOM];
    __shared__ float sm[4][8][ATOM];
    int n0 = blockIdx.x * 8;
    for (int i = threadIdx.x; i < 8 * ATOM; i += 256)
        ht[i >> 6][i & 63] = h[n0 * ATOM + i];
    __syncthreads();
    int m = threadIdx.x >> 6, c = threadIdx.x & 63;
    const float* Wb = ((m & 2) ? Ws : Wf) + l * ZD * ATOM + (m & 1) * ATOM * ATOM + c;
    float acc[8] = {0, 0, 0, 0, 0, 0, 0, 0};
    for (int k = 0; k < ATOM; ++k) {
        float w = Wb[k * ATOM];
#pragma unroll
        for (int j = 0; j < 8; ++j) acc[j] += ht[j][k] * w;
    }
#pragma unroll
    for (int j = 0; j < 8; ++j) sm[m][j][c] = acc[j];
    __syncthreads();
    for (int i = threadIdx.x; i < 8 * ATOM; i += 256) {
        int j = i >> 6, cc = i & 63;
        Pi[(size_t)(n0 + j) * 64 + cc] = bfr(sm[0][j][cc]) | (bfr(sm[2][j][cc]) << 16);
        Pj[(size_t)(n0 + j) * 64 + cc] = bfr(sm[1][j][cc]) | (bfr(sm[3][j][cc]) << 16);
    }
}

// T[b][c] = (e(d_b)@Wf_e + bf, e(d_b)@Ws_e + bs)
__global__ __launch_bounds__(256) void k_table(const float* __restrict__ Wf,
                                               const float* __restrict__ bf,
                                               const float* __restrict__ Ws,
                                               const float* __restrict__ bs,
                                               int l, float2* __restrict__ T) {
    int c = threadIdx.x & 63;
    int b = blockIdx.x * 4 + (threadIdx.x >> 6);
    if (b > TBINS) return;
    float d = b * (TMAX / TBINS);
    const float* Wfe = Wf + l * ZD * ATOM + 2 * ATOM * ATOM + c;
    const float* Wse = Ws + l * ZD * ATOM + 2 * ATOM * ATOM + c;
    float af = bf[l * ATOM + c], as = bs[l * ATOM + c];
    for (int k = 0; k < NBR; ++k) {
        float diff = d - 0.2f * k;
        float r = expf(-5.0f * diff * diff);
        af += r * Wfe[k * ATOM];
        as += r * Wse[k * ATOM];
    }
    float2 o; o.x = af; o.y = as;
    T[b * 64 + c] = o;
}

// one wave per node over its dst-sorted edges; register accumulate, single write
__global__ __launch_bounds__(256) void k_edge_sorted(const int* __restrict__ offs,
                                                     const int2* __restrict__ sed,
                                                     const unsigned int* __restrict__ Pi,
                                                     const unsigned int* __restrict__ Pj,
                                                     const float2* __restrict__ T,
                                                     float* __restrict__ agg) {
    int wid = (blockIdx.x * 256 + threadIdx.x) >> 6;
    int c = threadIdx.x & 63;
    int n = __builtin_amdgcn_readfirstlane(wid);
    if (n >= N_NODES) return;
    int ko = offs[n], ke = offs[n + 1];
    unsigned int pi = Pi[(size_t)n * 64 + c];
    float gi = bf_lo(pi), ci = bf_hi(pi);
    float acc = 0.0f;
    for (int k = ko; k < ke; ++k) {
        int2 sd = sed[k];
        int src = sd.x;
        float d = __int_as_float(sd.y);
        float tb = fminf(d * ((float)TBINS / TMAX) + 0.5f, (float)TBINS);
        int b = (int)tb;
        float2 t2 = T[(size_t)b * 64 + c];
        unsigned int pj = Pj[(size_t)src * 64 + c];
        float gate = gi + bf_lo(pj) + t2.x;
        float core = ci + bf_hi(pj) + t2.y;
        acc += sigmoid_f(gate) * softplus_f(core);
    }
    agg[(size_t)n * 64 + c] = acc;
}

__global__ __launch_bounds__(256) void k_bnstats(const float* __restrict__ agg,
                                                 float* __restrict__ stats) {
    __shared__ float ls[256], ls2[256];
    int c = threadIdx.x & 63, rg = threadIdx.x >> 6;
    float s = 0.0f, s2 = 0.0f;
    for (int n = blockIdx.x * 4 + rg; n < N_NODES; n += gridDim.x * 4) {
        float v = agg[(size_t)n * ATOM + c];
        s += v; s2 += v * v;
    }
    ls[threadIdx.x] = s; ls2[threadIdx.x] = s2;
    __syncthreads();
    if (threadIdx.x < 64) {
        s = ls[c] + ls[64 + c] + ls[128 + c] + ls[192 + c];
        s2 = ls2[c] + ls2[64 + c] + ls2[128 + c] + ls2[192 + c];
        atomicAdd(&stats[c], s);
        atomicAdd(&stats[64 + c], s2);
    }
}

__global__ __launch_bounds__(64) void k_bnfinal(const float* __restrict__ stats,
                                                const float* __restrict__ gamma,
                                                const float* __restrict__ beta,
                                                int l, float* __restrict__ ss) {
    int c = threadIdx.x;
    const float inv = 1.0f / (float)N_NODES;
    float mu = stats[c] * inv;
    float var = stats[64 + c] * inv - mu * mu;
    float sc = gamma[l * ATOM + c] * rsqrtf(var + 1e-5f);
    ss[c] = sc;
    ss[64 + c] = beta[l * ATOM + c] - mu * sc;
}

__global__ __launch_bounds__(256) void k_update(const float* __restrict__ agg,
                                                const float* __restrict__ ss,
                                                float* __restrict__ h) {
    int t = blockIdx.x * 256 + threadIdx.x;
    int c = t & 63;
    float x = ss[c] * agg[t] + ss[64 + c] + h[t];
    h[t] = softplus_f(x);
}

__global__ __launch_bounds__(256) void k_pool(const float* __restrict__ h,
                                              const int* __restrict__ batch,
                                              float* __restrict__ g) {
    int t = blockIdx.x * 256 + threadIdx.x;
    int n = t >> 6, c = t & 63;
    atomicAdd(&g[(size_t)batch[n] * ATOM + c], h[t]);
}

__global__ __launch_bounds__(128) void k_head(const float* __restrict__ g,
                                              const float* __restrict__ W1,
                                              const float* __restrict__ b1,
                                              const float* __restrict__ W2,
                                              const float* __restrict__ b2,
                                              float* __restrict__ out) {
    __shared__ float red[128];
    int gid = blockIdx.x, j = threadIdx.x;
    float acc = b1[j];
    for (int k = 0; k < ATOM; ++k) acc += g[gid * ATOM + k] * W1[k * HFEA + j];
    red[j] = softplus_f(acc) * W2[j];
    __syncthreads();
    for (int s = 64; s > 0; s >>= 1) {
        if (j < s) red[j] += red[j + s];
        __syncthreads();
    }
    if (j == 0) out[gid] = red[0] + b2[0];
}

extern "C" void kernel_launch(void* const* d_in, const int* in_sizes, int n_in,
                              void* d_out, int out_size, void* d_ws, size_t ws_size,
                              hipStream_t stream) {
    const float* x       = (const float*)d_in[0];
    const float* ea      = (const float*)d_in[1];
    const float* W_emb   = (const float*)d_in[2];
    const float* b_emb   = (const float*)d_in[3];
    const float* Wf      = (const float*)d_in[4];
    const float* bf      = (const float*)d_in[5];
    const float* Ws      = (const float*)d_in[6];
    const float* bs      = (const float*)d_in[7];
    const float* bn_g    = (const float*)d_in[8];
    const float* bn_b    = (const float*)d_in[9];
    const float* W1      = (const float*)d_in[10];
    const float* b1      = (const float*)d_in[11];
    const float* W2      = (const float*)d_in[12];
    const float* b2      = (const float*)d_in[13];
    const int*   ei      = (const int*)d_in[14];
    const int*   batch   = (const int*)d_in[15];
    float* out = (float*)d_out;

    char* wsb = (char*)d_ws;
    size_t off = 0;
    auto alloc = [&](size_t bytes) { char* p = wsb + off; off += (bytes + 255) & ~(size_t)255; return p; };
    float*        h      = (float*)alloc((size_t)N_NODES * 64 * 4);
    float*        agg    = (float*)alloc((size_t)N_NODES * 64 * 4);
    float*        dvec   = (float*)alloc((size_t)N_EDGES * 4);
    unsigned int* Pi     = (unsigned int*)alloc((size_t)N_NODES * 64 * 4);
    unsigned int* Pj     = (unsigned int*)alloc((size_t)N_NODES * 64 * 4);
    int2*         sed    = (int2*)alloc((size_t)N_EDGES * 8);
    int*          cnt    = (int*)alloc((size_t)N_NODES * 4);
    int*          offs   = (int*)alloc((size_t)(N_NODES + 1) * 4);
    int*          cursor = (int*)alloc((size_t)N_NODES * 4);
    float2*       T      = (float2*)alloc((size_t)(TBINS + 1) * 64 * 8);
    float*        stats  = (float*)alloc(128 * 4);
    float*        ss     = (float*)alloc(128 * 4);
    float*        g      = (float*)alloc((size_t)NGRAPH * 64 * 4);

    k_embed<<<N_NODES / 16, 256, 0, stream>>>(x, W_emb, b_emb, h);
    k_dist<<<(N_EDGES + 255) / 256, 256, 0, stream>>>(ea, dvec);

    hipMemsetAsync(cnt, 0, (size_t)N_NODES * 4, stream);
    k_hist<<<(N_EDGES + 255) / 256, 256, 0, stream>>>(ei, cnt);
    k_scan<<<1, 1024, 0, stream>>>(cnt, offs, cursor);
    k_scatter<<<(N_EDGES + 255) / 256, 256, 0, stream>>>(ei, dvec, cursor, sed);

    for (int l = 0; l < NCONV; ++l) {
        k_nodeP<<<N_NODES / 8, 256, 0, stream>>>(h, Wf, Ws, l, Pi, Pj);
        k_table<<<(TBINS + 4) / 4, 256, 0, stream>>>(Wf, bf, Ws, bs, l, T);
        k_edge_sorted<<<(N_NODES + 3) / 4, 256, 0, stream>>>(offs, sed, Pi, Pj, T, agg);
        hipMemsetAsync(stats, 0, 128 * 4, stream);
        k_bnstats<<<512, 256, 0, stream>>>(agg, stats);
        k_bnfinal<<<1, 64, 0, stream>>>(stats, bn_g, bn_b, l, ss);
        k_update<<<(size_t)N_NODES * 64 / 256, 256, 0, stream>>>(agg, ss, h);
    }

    hipMemsetAsync(g, 0, (size_t)NGRAPH * 64 * 4, stream);
    k_pool<<<(size_t)N_NODES * 64 / 256, 256, 0, stream>>>(h, batch, g);
    k_head<<<NGRAPH, 128, 0, stream>>>(g, W1, b1, W2, b2, out);
}

// Round 3
// 1882.464 us; speedup vs baseline: 1.1024x; 1.1024x over previous
//
#include <hip/hip_runtime.h>
#include <hip/hip_bf16.h>
#include <math.h>

#define N_NODES 100000
#define N_EDGES 1600000
#define ORIG    92
#define NBR     41
#define ATOM    64
#define NCONV   3
#define HFEA    128
#define NGRAPH  256
#define ZD      169           // 2*ATOM + NBR
#define TBINS   5120
#define TMAX    10.0f         // beyond d=10 RBF values < 3e-9
#define SCAN_BS 256
#define NTILE   ((N_NODES + SCAN_BS - 1) / SCAN_BS)

__device__ __forceinline__ float softplus_f(float x) {
    return fmaxf(x, 0.0f) + log1pf(expf(-fabsf(x)));
}
__device__ __forceinline__ float sigmoid_f(float x) {
    return 1.0f / (1.0f + expf(-x));
}
// round fp32 -> bf16 bits (RNE)
__device__ __forceinline__ unsigned int bfr(float x) {
    unsigned int u = __float_as_uint(x);
    return (u + 0x7fffu + ((u >> 16) & 1u)) >> 16;
}
__device__ __forceinline__ float bf_lo(unsigned int p) { return __uint_as_float(p << 16); }
__device__ __forceinline__ float bf_hi(unsigned int p) { return __uint_as_float(p & 0xffff0000u); }

// h = x @ W_emb + b_emb   [N,92]x[92,64]
__global__ __launch_bounds__(256) void k_embed(const float* __restrict__ x,
                                               const float* __restrict__ W,
                                               const float* __restrict__ b,
                                               float* __restrict__ h) {
    __shared__ float xt[16][ORIG];
    int n0 = blockIdx.x * 16;
    for (int i = threadIdx.x; i < 16 * ORIG; i += 256) {
        int nn = i / ORIG, kk = i - nn * ORIG;
        xt[nn][kk] = x[(n0 + nn) * ORIG + kk];
    }
    __syncthreads();
    int c = threadIdx.x & 63, jg = threadIdx.x >> 6;
    float acc[4];
    float bias = b[c];
#pragma unroll
    for (int j = 0; j < 4; ++j) acc[j] = bias;
    for (int k = 0; k < ORIG; ++k) {
        float w = W[k * ATOM + c];
#pragma unroll
        for (int j = 0; j < 4; ++j) acc[j] += xt[jg * 4 + j][k] * w;
    }
#pragma unroll
    for (int j = 0; j < 4; ++j) h[(n0 + jg * 4 + j) * ATOM + c] = acc[j];
}

__global__ __launch_bounds__(256) void k_hist(const int* __restrict__ ei,
                                              int* __restrict__ cnt) {
    int e = blockIdx.x * 256 + threadIdx.x;
    if (e < N_EDGES) atomicAdd(&cnt[ei[N_EDGES + e]], 1);
}

// --- 3-kernel coalesced scan of cnt[N] -> offs[N+1], cursor[N] ---
__global__ __launch_bounds__(SCAN_BS) void k_tilesum(const int* __restrict__ cnt,
                                                     int* __restrict__ bsum) {
    __shared__ int s[SCAN_BS];
    int i = blockIdx.x * SCAN_BS + threadIdx.x;
    s[threadIdx.x] = (i < N_NODES) ? cnt[i] : 0;
    __syncthreads();
    for (int d = SCAN_BS / 2; d > 0; d >>= 1) {
        if (threadIdx.x < d) s[threadIdx.x] += s[threadIdx.x + d];
        __syncthreads();
    }
    if (threadIdx.x == 0) bsum[blockIdx.x] = s[0];
}

__global__ __launch_bounds__(512) void k_bscan(const int* __restrict__ bsum,
                                               int* __restrict__ bpre,
                                               int* __restrict__ offs) {
    __shared__ int s[512];
    int t = threadIdx.x;
    int v = (t < NTILE) ? bsum[t] : 0;
    s[t] = v;
    __syncthreads();
    for (int d = 1; d < 512; d <<= 1) {
        int u = (t >= d) ? s[t - d] : 0;
        __syncthreads();
        s[t] += u;
        __syncthreads();
    }
    if (t < NTILE) bpre[t] = s[t] - v;   // exclusive
    if (t == 511) offs[N_NODES] = s[511];
}

__global__ __launch_bounds__(SCAN_BS) void k_tilescan(const int* __restrict__ cnt,
                                                      const int* __restrict__ bpre,
                                                      int* __restrict__ offs,
                                                      int* __restrict__ cursor) {
    __shared__ int s[SCAN_BS];
    int i = blockIdx.x * SCAN_BS + threadIdx.x;
    int v = (i < N_NODES) ? cnt[i] : 0;
    s[threadIdx.x] = v;
    __syncthreads();
    for (int d = 1; d < SCAN_BS; d <<= 1) {
        int u = (threadIdx.x >= d) ? s[threadIdx.x - d] : 0;
        __syncthreads();
        s[threadIdx.x] += u;
        __syncthreads();
    }
    if (i < N_NODES) {
        int ex = bpre[blockIdx.x] + s[threadIdx.x] - v;
        offs[i] = ex;
        cursor[i] = ex;
    }
}

// scatter (src, dist) packed per edge, sorted by dst (dist computed inline)
__global__ __launch_bounds__(256) void k_scatter(const int* __restrict__ ei,
                                                 const float* __restrict__ ea,
                                                 int* __restrict__ cursor,
                                                 int2* __restrict__ sed) {
    int e = blockIdx.x * 256 + threadIdx.x;
    if (e >= N_EDGES) return;
    float a = ea[3 * e], b = ea[3 * e + 1], c = ea[3 * e + 2];
    float d = sqrtf(a * a + b * b + c * c);
    int dst = ei[N_EDGES + e];
    int pos = atomicAdd(&cursor[dst], 1);
    int2 v;
    v.x = ei[e];
    v.y = __float_as_int(d);
    sed[pos] = v;
}

// Pi[n][c] = pack(h@Wf_i, h@Ws_i)  Pj[n][c] = pack(h@Wf_j, h@Ws_j)  (bf16 pairs)
__global__ __launch_bounds__(256) void k_nodeP(const float* __restrict__ h,
                                               const float* __restrict__ Wf,
                                               const float* __restrict__ Ws,
                                               int l,
                                               unsigned int* __restrict__ Pi,
                                               unsigned int* __restrict__ Pj) {
    __shared__ float ht[8][ATOM];
    __shared__ float sm[4][8][ATOM];
    int n0 = blockIdx.x * 8;
    for (int i = threadIdx.x; i < 8 * ATOM; i += 256)
        ht[i >> 6][i & 63] = h[n0 * ATOM + i];
    __syncthreads();
    int m = threadIdx.x >> 6, c = threadIdx.x & 63;
    const float* Wb = ((m & 2) ? Ws : Wf) + l * ZD * ATOM + (m & 1) * ATOM * ATOM + c;
    float acc[8] = {0, 0, 0, 0, 0, 0, 0, 0};
    for (int k = 0; k < ATOM; ++k) {
        float w = Wb[k * ATOM];
#pragma unroll
        for (int j = 0; j < 8; ++j) acc[j] += ht[j][k] * w;
    }
#pragma unroll
    for (int j = 0; j < 8; ++j) sm[m][j][c] = acc[j];
    __syncthreads();
    for (int i = threadIdx.x; i < 8 * ATOM; i += 256) {
        int j = i >> 6, cc = i & 63;
        Pi[(size_t)(n0 + j) * 64 + cc] = bfr(sm[0][j][cc]) | (bfr(sm[2][j][cc]) << 16);
        Pj[(size_t)(n0 + j) * 64 + cc] = bfr(sm[1][j][cc]) | (bfr(sm[3][j][cc]) << 16);
    }
}

// T[b][c] = (e(d_b)@Wf_e + bf, e(d_b)@Ws_e + bs)
__global__ __launch_bounds__(256) void k_table(const float* __restrict__ Wf,
                                               const float* __restrict__ bf,
                                               const float* __restrict__ Ws,
                                               const float* __restrict__ bs,
                                               int l, float2* __restrict__ T) {
    int c = threadIdx.x & 63;
    int b = blockIdx.x * 4 + (threadIdx.x >> 6);
    if (b > TBINS) return;
    float d = b * (TMAX / TBINS);
    const float* Wfe = Wf + l * ZD * ATOM + 2 * ATOM * ATOM + c;
    const float* Wse = Ws + l * ZD * ATOM + 2 * ATOM * ATOM + c;
    float af = bf[l * ATOM + c], as = bs[l * ATOM + c];
    for (int k = 0; k < NBR; ++k) {
        float diff = d - 0.2f * k;
        float r = expf(-5.0f * diff * diff);
        af += r * Wfe[k * ATOM];
        as += r * Wse[k * ATOM];
    }
    float2 o; o.x = af; o.y = as;
    T[b * 64 + c] = o;
}

// one wave per node; lane-cooperative sed load + unroll-8 batched gathers
#define UN 8
__global__ __launch_bounds__(256) void k_edge_sorted(const int* __restrict__ offs,
                                                     const int2* __restrict__ sed,
                                                     const unsigned int* __restrict__ Pi,
                                                     const unsigned int* __restrict__ Pj,
                                                     const float2* __restrict__ T,
                                                     float* __restrict__ agg) {
    int wid = (blockIdx.x * 256 + threadIdx.x) >> 6;
    int lane = threadIdx.x & 63;
    if (wid >= N_NODES) return;
    int ko = offs[wid], ke = offs[wid + 1];
    unsigned int pi = Pi[(size_t)wid * 64 + lane];
    float gi = bf_lo(pi), ci = bf_hi(pi);
    float acc = 0.0f;
    for (int base = ko; base < ke; base += 64) {
        int m = ke - base;
        if (m > 64) m = 64;
        int2 my = sed[base + (lane < m ? lane : m - 1)];
        for (int k = 0; k < m; k += UN) {
            float2 t2[UN];
            unsigned int pj[UN];
#pragma unroll
            for (int j = 0; j < UN; ++j) {
                int kk = k + j;
                if (kk > m - 1) kk = m - 1;
                int src = __shfl(my.x, kk, 64);
                float d = __int_as_float(__shfl(my.y, kk, 64));
                float tb = fminf(fmaf(d, (float)TBINS / TMAX, 0.5f), (float)TBINS);
                int b = (int)tb;
                t2[j] = T[(size_t)b * 64 + lane];
                pj[j] = Pj[(size_t)src * 64 + lane];
            }
#pragma unroll
            for (int j = 0; j < UN; ++j) {
                if (k + j < m) {
                    float gate = gi + bf_lo(pj[j]) + t2[j].x;
                    float core = ci + bf_hi(pj[j]) + t2[j].y;
                    acc += sigmoid_f(gate) * softplus_f(core);
                }
            }
        }
    }
    agg[(size_t)wid * 64 + lane] = acc;
}

__global__ __launch_bounds__(256) void k_bnstats(const float* __restrict__ agg,
                                                 float* __restrict__ stats) {
    __shared__ float ls[256], ls2[256];
    int c = threadIdx.x & 63, rg = threadIdx.x >> 6;
    float s = 0.0f, s2 = 0.0f;
    for (int n = blockIdx.x * 4 + rg; n < N_NODES; n += gridDim.x * 4) {
        float v = agg[(size_t)n * ATOM + c];
        s += v; s2 += v * v;
    }
    ls[threadIdx.x] = s; ls2[threadIdx.x] = s2;
    __syncthreads();
    if (threadIdx.x < 64) {
        s = ls[c] + ls[64 + c] + ls[128 + c] + ls[192 + c];
        s2 = ls2[c] + ls2[64 + c] + ls2[128 + c] + ls2[192 + c];
        atomicAdd(&stats[c], s);
        atomicAdd(&stats[64 + c], s2);
    }
}

__global__ __launch_bounds__(64) void k_bnfinal(const float* __restrict__ stats,
                                                const float* __restrict__ gamma,
                                                const float* __restrict__ beta,
                                                int l, float* __restrict__ ss) {
    int c = threadIdx.x;
    const float inv = 1.0f / (float)N_NODES;
    float mu = stats[c] * inv;
    float var = stats[64 + c] * inv - mu * mu;
    float sc = gamma[l * ATOM + c] * rsqrtf(var + 1e-5f);
    ss[c] = sc;
    ss[64 + c] = beta[l * ATOM + c] - mu * sc;
}

__global__ __launch_bounds__(256) void k_update(const float* __restrict__ agg,
                                                const float* __restrict__ ss,
                                                float* __restrict__ h) {
    int t = blockIdx.x * 256 + threadIdx.x;
    int c = t & 63;
    float x = ss[c] * agg[t] + ss[64 + c] + h[t];
    h[t] = softplus_f(x);
}

__global__ __launch_bounds__(256) void k_pool(const float* __restrict__ h,
                                              const int* __restrict__ batch,
                                              float* __restrict__ g) {
    int t = blockIdx.x * 256 + threadIdx.x;
    int n = t >> 6, c = t & 63;
    atomicAdd(&g[(size_t)batch[n] * ATOM + c], h[t]);
}

__global__ __launch_bounds__(128) void k_head(const float* __restrict__ g,
                                              const float* __restrict__ W1,
                                              const float* __restrict__ b1,
                                              const float* __restrict__ W2,
                                              const float* __restrict__ b2,
                                              float* __restrict__ out) {
    __shared__ float red[128];
    int gid = blockIdx.x, j = threadIdx.x;
    float acc = b1[j];
    for (int k = 0; k < ATOM; ++k) acc += g[gid * ATOM + k] * W1[k * HFEA + j];
    red[j] = softplus_f(acc) * W2[j];
    __syncthreads();
    for (int s = 64; s > 0; s >>= 1) {
        if (j < s) red[j] += red[j + s];
        __syncthreads();
    }
    if (j == 0) out[gid] = red[0] + b2[0];
}

extern "C" void kernel_launch(void* const* d_in, const int* in_sizes, int n_in,
                              void* d_out, int out_size, void* d_ws, size_t ws_size,
                              hipStream_t stream) {
    const float* x       = (const float*)d_in[0];
    const float* ea      = (const float*)d_in[1];
    const float* W_emb   = (const float*)d_in[2];
    const float* b_emb   = (const float*)d_in[3];
    const float* Wf      = (const float*)d_in[4];
    const float* bf      = (const float*)d_in[5];
    const float* Ws      = (const float*)d_in[6];
    const float* bs      = (const float*)d_in[7];
    const float* bn_g    = (const float*)d_in[8];
    const float* bn_b    = (const float*)d_in[9];
    const float* W1      = (const float*)d_in[10];
    const float* b1      = (const float*)d_in[11];
    const float* W2      = (const float*)d_in[12];
    const float* b2      = (const float*)d_in[13];
    const int*   ei      = (const int*)d_in[14];
    const int*   batch   = (const int*)d_in[15];
    float* out = (float*)d_out;

    char* wsb = (char*)d_ws;
    size_t off = 0;
    auto alloc = [&](size_t bytes) { char* p = wsb + off; off += (bytes + 255) & ~(size_t)255; return p; };
    float*        h      = (float*)alloc((size_t)N_NODES * 64 * 4);
    float*        agg    = (float*)alloc((size_t)N_NODES * 64 * 4);
    unsigned int* Pi     = (unsigned int*)alloc((size_t)N_NODES * 64 * 4);
    unsigned int* Pj     = (unsigned int*)alloc((size_t)N_NODES * 64 * 4);
    int2*         sed    = (int2*)alloc((size_t)N_EDGES * 8);
    int*          cnt    = (int*)alloc((size_t)N_NODES * 4);
    int*          offs   = (int*)alloc((size_t)(N_NODES + 1) * 4);
    int*          cursor = (int*)alloc((size_t)N_NODES * 4);
    int*          bsum   = (int*)alloc((size_t)NTILE * 4);
    int*          bpre   = (int*)alloc((size_t)NTILE * 4);
    float2*       T      = (float2*)alloc((size_t)(TBINS + 1) * 64 * 8);
    float*        stats  = (float*)alloc(128 * 4);
    float*        ss     = (float*)alloc(128 * 4);
    float*        g      = (float*)alloc((size_t)NGRAPH * 64 * 4);

    k_embed<<<N_NODES / 16, 256, 0, stream>>>(x, W_emb, b_emb, h);

    hipMemsetAsync(cnt, 0, (size_t)N_NODES * 4, stream);
    k_hist<<<(N_EDGES + 255) / 256, 256, 0, stream>>>(ei, cnt);
    k_tilesum<<<NTILE, SCAN_BS, 0, stream>>>(cnt, bsum);
    k_bscan<<<1, 512, 0, stream>>>(bsum, bpre, offs);
    k_tilescan<<<NTILE, SCAN_BS, 0, stream>>>(cnt, bpre, offs, cursor);
    k_scatter<<<(N_EDGES + 255) / 256, 256, 0, stream>>>(ei, ea, cursor, sed);

    for (int l = 0; l < NCONV; ++l) {
        k_nodeP<<<N_NODES / 8, 256, 0, stream>>>(h, Wf, Ws, l, Pi, Pj);
        k_table<<<(TBINS + 4) / 4, 256, 0, stream>>>(Wf, bf, Ws, bs, l, T);
        k_edge_sorted<<<(N_NODES * 64 + 255) / 256, 256, 0, stream>>>(offs, sed, Pi, Pj, T, agg);
        hipMemsetAsync(stats, 0, 128 * 4, stream);
        k_bnstats<<<512, 256, 0, stream>>>(agg, stats);
        k_bnfinal<<<1, 64, 0, stream>>>(stats, bn_g, bn_b, l, ss);
        k_update<<<(size_t)N_NODES * 64 / 256, 256, 0, stream>>>(agg, ss, h);
    }

    hipMemsetAsync(g, 0, (size_t)NGRAPH * 64 * 4, stream);
    k_pool<<<(size_t)N_NODES * 64 / 256, 256, 0, stream>>>(h, batch, g);
    k_head<<<NGRAPH, 128, 0, stream>>>(g, W1, b1, W2, b2, out);
}

// Round 4
// 1094.039 us; speedup vs baseline: 1.8969x; 1.7207x over previous
//
#include <hip/hip_runtime.h>
#include <hip/hip_bf16.h>
#include <math.h>

#define N_NODES 100000
#define N_EDGES 1600000
#define ORIG    92
#define NBR     41
#define ATOM    64
#define NCONV   3
#define HFEA    128
#define NGRAPH  256
#define ZD      169           // 2*ATOM + NBR
#define TBINS   5120
#define TMAX    10.0f         // beyond d=10 RBF values < 3e-9
#define SCAN_BS 256
#define NTILE   ((N_NODES + SCAN_BS - 1) / SCAN_BS)

__device__ __forceinline__ float softplus_f(float x) {
    return fmaxf(x, 0.0f) + log1pf(expf(-fabsf(x)));
}
__device__ __forceinline__ float sigmoid_f(float x) {
    return 1.0f / (1.0f + expf(-x));
}
// round fp32 -> bf16 bits (RNE)
__device__ __forceinline__ unsigned int bfr(float x) {
    unsigned int u = __float_as_uint(x);
    return (u + 0x7fffu + ((u >> 16) & 1u)) >> 16;
}
__device__ __forceinline__ float bf_lo(unsigned int p) { return __uint_as_float(p << 16); }
__device__ __forceinline__ float bf_hi(unsigned int p) { return __uint_as_float(p & 0xffff0000u); }

// h = x @ W_emb + b_emb   [N,92]x[92,64]
__global__ __launch_bounds__(256) void k_embed(const float* __restrict__ x,
                                               const float* __restrict__ W,
                                               const float* __restrict__ b,
                                               float* __restrict__ h) {
    __shared__ float xt[16][ORIG];
    int n0 = blockIdx.x * 16;
    for (int i = threadIdx.x; i < 16 * ORIG; i += 256) {
        int nn = i / ORIG, kk = i - nn * ORIG;
        xt[nn][kk] = x[(n0 + nn) * ORIG + kk];
    }
    __syncthreads();
    int c = threadIdx.x & 63, jg = threadIdx.x >> 6;
    float acc[4];
    float bias = b[c];
#pragma unroll
    for (int j = 0; j < 4; ++j) acc[j] = bias;
    for (int k = 0; k < ORIG; ++k) {
        float w = W[k * ATOM + c];
#pragma unroll
        for (int j = 0; j < 4; ++j) acc[j] += xt[jg * 4 + j][k] * w;
    }
#pragma unroll
    for (int j = 0; j < 4; ++j) h[(n0 + jg * 4 + j) * ATOM + c] = acc[j];
}

__global__ __launch_bounds__(256) void k_hist(const int* __restrict__ ei,
                                              int* __restrict__ cnt) {
    int e = blockIdx.x * 256 + threadIdx.x;
    if (e < N_EDGES) atomicAdd(&cnt[ei[N_EDGES + e]], 1);
}

// --- 3-kernel coalesced scan of cnt[N] -> offs[N+1], cursor[N] ---
__global__ __launch_bounds__(SCAN_BS) void k_tilesum(const int* __restrict__ cnt,
                                                     int* __restrict__ bsum) {
    __shared__ int s[SCAN_BS];
    int i = blockIdx.x * SCAN_BS + threadIdx.x;
    s[threadIdx.x] = (i < N_NODES) ? cnt[i] : 0;
    __syncthreads();
    for (int d = SCAN_BS / 2; d > 0; d >>= 1) {
        if (threadIdx.x < d) s[threadIdx.x] += s[threadIdx.x + d];
        __syncthreads();
    }
    if (threadIdx.x == 0) bsum[blockIdx.x] = s[0];
}

__global__ __launch_bounds__(512) void k_bscan(const int* __restrict__ bsum,
                                               int* __restrict__ bpre,
                                               int* __restrict__ offs) {
    __shared__ int s[512];
    int t = threadIdx.x;
    int v = (t < NTILE) ? bsum[t] : 0;
    s[t] = v;
    __syncthreads();
    for (int d = 1; d < 512; d <<= 1) {
        int u = (t >= d) ? s[t - d] : 0;
        __syncthreads();
        s[t] += u;
        __syncthreads();
    }
    if (t < NTILE) bpre[t] = s[t] - v;   // exclusive
    if (t == 511) offs[N_NODES] = s[511];
}

__global__ __launch_bounds__(SCAN_BS) void k_tilescan(const int* __restrict__ cnt,
                                                      const int* __restrict__ bpre,
                                                      int* __restrict__ offs,
                                                      int* __restrict__ cursor) {
    __shared__ int s[SCAN_BS];
    int i = blockIdx.x * SCAN_BS + threadIdx.x;
    int v = (i < N_NODES) ? cnt[i] : 0;
    s[threadIdx.x] = v;
    __syncthreads();
    for (int d = 1; d < SCAN_BS; d <<= 1) {
        int u = (threadIdx.x >= d) ? s[threadIdx.x - d] : 0;
        __syncthreads();
        s[threadIdx.x] += u;
        __syncthreads();
    }
    if (i < N_NODES) {
        int ex = bpre[blockIdx.x] + s[threadIdx.x] - v;
        offs[i] = ex;
        cursor[i] = ex;
    }
}

// scatter (src, dist) packed per edge, sorted by dst (dist computed inline)
__global__ __launch_bounds__(256) void k_scatter(const int* __restrict__ ei,
                                                 const float* __restrict__ ea,
                                                 int* __restrict__ cursor,
                                                 int2* __restrict__ sed) {
    int e = blockIdx.x * 256 + threadIdx.x;
    if (e >= N_EDGES) return;
    float a = ea[3 * e], b = ea[3 * e + 1], c = ea[3 * e + 2];
    float d = sqrtf(a * a + b * b + c * c);
    int dst = ei[N_EDGES + e];
    int pos = atomicAdd(&cursor[dst], 1);
    int2 v;
    v.x = ei[e];
    v.y = __float_as_int(d);
    sed[pos] = v;
}

// Pi[n][c] = pack(h@Wf_i, h@Ws_i)  Pj[n][c] = pack(h@Wf_j, h@Ws_j)  (bf16 pairs)
__global__ __launch_bounds__(256) void k_nodeP(const float* __restrict__ h,
                                               const float* __restrict__ Wf,
                                               const float* __restrict__ Ws,
                                               int l,
                                               unsigned int* __restrict__ Pi,
                                               unsigned int* __restrict__ Pj) {
    __shared__ float ht[8][ATOM];
    __shared__ float sm[4][8][ATOM];
    int n0 = blockIdx.x * 8;
    for (int i = threadIdx.x; i < 8 * ATOM; i += 256)
        ht[i >> 6][i & 63] = h[n0 * ATOM + i];
    __syncthreads();
    int m = threadIdx.x >> 6, c = threadIdx.x & 63;
    const float* Wb = ((m & 2) ? Ws : Wf) + l * ZD * ATOM + (m & 1) * ATOM * ATOM + c;
    float acc[8] = {0, 0, 0, 0, 0, 0, 0, 0};
    for (int k = 0; k < ATOM; ++k) {
        float w = Wb[k * ATOM];
#pragma unroll
        for (int j = 0; j < 8; ++j) acc[j] += ht[j][k] * w;
    }
#pragma unroll
    for (int j = 0; j < 8; ++j) sm[m][j][c] = acc[j];
    __syncthreads();
    for (int i = threadIdx.x; i < 8 * ATOM; i += 256) {
        int j = i >> 6, cc = i & 63;
        Pi[(size_t)(n0 + j) * 64 + cc] = bfr(sm[0][j][cc]) | (bfr(sm[2][j][cc]) << 16);
        Pj[(size_t)(n0 + j) * 64 + cc] = bfr(sm[1][j][cc]) | (bfr(sm[3][j][cc]) << 16);
    }
}

// Tp[b][c] = pack_bf16(e(d_b)@Wf_e + bf, e(d_b)@Ws_e + bs)
__global__ __launch_bounds__(256) void k_table(const float* __restrict__ Wf,
                                               const float* __restrict__ bf,
                                               const float* __restrict__ Ws,
                                               const float* __restrict__ bs,
                                               int l, unsigned int* __restrict__ Tp) {
    int c = threadIdx.x & 63;
    int b = blockIdx.x * 4 + (threadIdx.x >> 6);
    if (b > TBINS) return;
    float d = b * (TMAX / TBINS);
    const float* Wfe = Wf + l * ZD * ATOM + 2 * ATOM * ATOM + c;
    const float* Wse = Ws + l * ZD * ATOM + 2 * ATOM * ATOM + c;
    float af = bf[l * ATOM + c], as = bs[l * ATOM + c];
    for (int k = 0; k < NBR; ++k) {
        float diff = d - 0.2f * k;
        float r = expf(-5.0f * diff * diff);
        af += r * Wfe[k * ATOM];
        as += r * Wse[k * ATOM];
    }
    Tp[b * 64 + c] = bfr(af) | (bfr(as) << 16);
}

// one wave per node; scalar sed reads + UN-deep independent gathers + fast math
#define UN 8
__global__ __launch_bounds__(256) void k_edge_sorted(const int* __restrict__ offs,
                                                     const int2* __restrict__ sed,
                                                     const unsigned int* __restrict__ Pi,
                                                     const unsigned int* __restrict__ Pj,
                                                     const unsigned int* __restrict__ Tp,
                                                     float* __restrict__ agg) {
    int wid = (blockIdx.x * 256 + threadIdx.x) >> 6;
    int lane = threadIdx.x & 63;
    if (wid >= N_NODES) return;
    int ko = offs[wid], ke = offs[wid + 1];
    unsigned int pi = Pi[(size_t)wid * 64 + lane];
    float gi = bf_lo(pi), ci = bf_hi(pi);
    float acc = 0.0f;
    for (int k0 = ko; k0 < ke; k0 += UN) {
        unsigned int tj[UN], pj[UN];
        float msk[UN];
#pragma unroll
        for (int j = 0; j < UN; ++j) {
            int kk = k0 + j;
            int kc = (kk < ke) ? kk : (ke - 1);
            int2 sd = sed[kc];
            int src = __builtin_amdgcn_readfirstlane(sd.x);
            float d = __uint_as_float((unsigned int)__builtin_amdgcn_readfirstlane(sd.y));
            int b = (int)fminf(fmaf(d, (float)TBINS / TMAX, 0.5f), (float)TBINS);
            tj[j] = Tp[(size_t)b * 64 + lane];
            pj[j] = Pj[(size_t)src * 64 + lane];
            msk[j] = (kk < ke) ? 1.0f : 0.0f;
        }
#pragma unroll
        for (int j = 0; j < UN; ++j) {
            float g = gi + bf_lo(pj[j]) + bf_lo(tj[j]);
            float c = ci + bf_hi(pj[j]) + bf_hi(tj[j]);
            float sg = __builtin_amdgcn_rcpf(1.0f + __expf(-g));
            float sp = fmaxf(c, 0.0f) + __logf(1.0f + __expf(-fabsf(c)));
            acc = fmaf(sg * sp, msk[j], acc);
        }
    }
    agg[(size_t)wid * 64 + lane] = acc;
}

__global__ __launch_bounds__(256) void k_bnstats(const float* __restrict__ agg,
                                                 float* __restrict__ stats) {
    __shared__ float ls[256], ls2[256];
    int c = threadIdx.x & 63, rg = threadIdx.x >> 6;
    float s = 0.0f, s2 = 0.0f;
    for (int n = blockIdx.x * 4 + rg; n < N_NODES; n += gridDim.x * 4) {
        float v = agg[(size_t)n * ATOM + c];
        s += v; s2 += v * v;
    }
    ls[threadIdx.x] = s; ls2[threadIdx.x] = s2;
    __syncthreads();
    if (threadIdx.x < 64) {
        s = ls[c] + ls[64 + c] + ls[128 + c] + ls[192 + c];
        s2 = ls2[c] + ls2[64 + c] + ls2[128 + c] + ls2[192 + c];
        atomicAdd(&stats[c], s);
        atomicAdd(&stats[64 + c], s2);
    }
}

__global__ __launch_bounds__(64) void k_bnfinal(const float* __restrict__ stats,
                                                const float* __restrict__ gamma,
                                                const float* __restrict__ beta,
                                                int l, float* __restrict__ ss) {
    int c = threadIdx.x;
    const float inv = 1.0f / (float)N_NODES;
    float mu = stats[c] * inv;
    float var = stats[64 + c] * inv - mu * mu;
    float sc = gamma[l * ATOM + c] * rsqrtf(var + 1e-5f);
    ss[c] = sc;
    ss[64 + c] = beta[l * ATOM + c] - mu * sc;
}

__global__ __launch_bounds__(256) void k_update(const float* __restrict__ agg,
                                                const float* __restrict__ ss,
                                                float* __restrict__ h) {
    int t = blockIdx.x * 256 + threadIdx.x;
    int c = t & 63;
    float x = ss[c] * agg[t] + ss[64 + c] + h[t];
    h[t] = softplus_f(x);
}

__global__ __launch_bounds__(256) void k_pool(const float* __restrict__ h,
                                              const int* __restrict__ batch,
                                              float* __restrict__ g) {
    int t = blockIdx.x * 256 + threadIdx.x;
    int n = t >> 6, c = t & 63;
    atomicAdd(&g[(size_t)batch[n] * ATOM + c], h[t]);
}

__global__ __launch_bounds__(128) void k_head(const float* __restrict__ g,
                                              const float* __restrict__ W1,
                                              const float* __restrict__ b1,
                                              const float* __restrict__ W2,
                                              const float* __restrict__ b2,
                                              float* __restrict__ out) {
    __shared__ float red[128];
    int gid = blockIdx.x, j = threadIdx.x;
    float acc = b1[j];
    for (int k = 0; k < ATOM; ++k) acc += g[gid * ATOM + k] * W1[k * HFEA + j];
    red[j] = softplus_f(acc) * W2[j];
    __syncthreads();
    for (int s = 64; s > 0; s >>= 1) {
        if (j < s) red[j] += red[j + s];
        __syncthreads();
    }
    if (j == 0) out[gid] = red[0] + b2[0];
}

extern "C" void kernel_launch(void* const* d_in, const int* in_sizes, int n_in,
                              void* d_out, int out_size, void* d_ws, size_t ws_size,
                              hipStream_t stream) {
    const float* x       = (const float*)d_in[0];
    const float* ea      = (const float*)d_in[1];
    const float* W_emb   = (const float*)d_in[2];
    const float* b_emb   = (const float*)d_in[3];
    const float* Wf      = (const float*)d_in[4];
    const float* bf      = (const float*)d_in[5];
    const float* Ws      = (const float*)d_in[6];
    const float* bs      = (const float*)d_in[7];
    const float* bn_g    = (const float*)d_in[8];
    const float* bn_b    = (const float*)d_in[9];
    const float* W1      = (const float*)d_in[10];
    const float* b1      = (const float*)d_in[11];
    const float* W2      = (const float*)d_in[12];
    const float* b2      = (const float*)d_in[13];
    const int*   ei      = (const int*)d_in[14];
    const int*   batch   = (const int*)d_in[15];
    float* out = (float*)d_out;

    char* wsb = (char*)d_ws;
    size_t off = 0;
    auto alloc = [&](size_t bytes) { char* p = wsb + off; off += (bytes + 255) & ~(size_t)255; return p; };
    float*        h      = (float*)alloc((size_t)N_NODES * 64 * 4);
    float*        agg    = (float*)alloc((size_t)N_NODES * 64 * 4);
    unsigned int* Pi     = (unsigned int*)alloc((size_t)N_NODES * 64 * 4);
    unsigned int* Pj     = (unsigned int*)alloc((size_t)N_NODES * 64 * 4);
    int2*         sed    = (int2*)alloc((size_t)N_EDGES * 8);
    int*          cnt    = (int*)alloc((size_t)N_NODES * 4);
    int*          offs   = (int*)alloc((size_t)(N_NODES + 1) * 4);
    int*          cursor = (int*)alloc((size_t)N_NODES * 4);
    int*          bsum   = (int*)alloc((size_t)NTILE * 4);
    int*          bpre   = (int*)alloc((size_t)NTILE * 4);
    unsigned int* Tp     = (unsigned int*)alloc((size_t)(TBINS + 1) * 64 * 4);
    float*        stats  = (float*)alloc(128 * 4);
    float*        ss     = (float*)alloc(128 * 4);
    float*        g      = (float*)alloc((size_t)NGRAPH * 64 * 4);

    k_embed<<<N_NODES / 16, 256, 0, stream>>>(x, W_emb, b_emb, h);

    hipMemsetAsync(cnt, 0, (size_t)N_NODES * 4, stream);
    k_hist<<<(N_EDGES + 255) / 256, 256, 0, stream>>>(ei, cnt);
    k_tilesum<<<NTILE, SCAN_BS, 0, stream>>>(cnt, bsum);
    k_bscan<<<1, 512, 0, stream>>>(bsum, bpre, offs);
    k_tilescan<<<NTILE, SCAN_BS, 0, stream>>>(cnt, bpre, offs, cursor);
    k_scatter<<<(N_EDGES + 255) / 256, 256, 0, stream>>>(ei, ea, cursor, sed);

    for (int l = 0; l < NCONV; ++l) {
        k_nodeP<<<N_NODES / 8, 256, 0, stream>>>(h, Wf, Ws, l, Pi, Pj);
        k_table<<<(TBINS + 4) / 4, 256, 0, stream>>>(Wf, bf, Ws, bs, l, Tp);
        k_edge_sorted<<<(N_NODES * 64 + 255) / 256, 256, 0, stream>>>(offs, sed, Pi, Pj, Tp, agg);
        hipMemsetAsync(stats, 0, 128 * 4, stream);
        k_bnstats<<<512, 256, 0, stream>>>(agg, stats);
        k_bnfinal<<<1, 64, 0, stream>>>(stats, bn_g, bn_b, l, ss);
        k_update<<<(size_t)N_NODES * 64 / 256, 256, 0, stream>>>(agg, ss, h);
    }

    hipMemsetAsync(g, 0, (size_t)NGRAPH * 64 * 4, stream);
    k_pool<<<(size_t)N_NODES * 64 / 256, 256, 0, stream>>>(h, batch, g);
    k_head<<<NGRAPH, 128, 0, stream>>>(g, W1, b1, W2, b2, out);
}

// Round 5
// 1072.257 us; speedup vs baseline: 1.9355x; 1.0203x over previous
//
#include <hip/hip_runtime.h>
#include <hip/hip_bf16.h>
#include <math.h>

#define N_NODES 100000
#define N_EDGES 1600000
#define ORIG    92
#define NBR     41
#define ATOM    64
#define NCONV   3
#define HFEA    128
#define NGRAPH  256
#define ZD      169           // 2*ATOM + NBR
#define TBINS   5120
#define TMAX    10.0f
#define TS      ((TBINS + 1) * 64)   // per-layer table stride (uints)
#define SCAN_BS 256
#define NTILE   ((N_NODES + SCAN_BS - 1) / SCAN_BS)
#define SP      72                   // LDS row pad (elements) -> 144B, 16B-aligned
#define NPBLK   128                  // bnstats partial blocks

typedef __attribute__((ext_vector_type(8))) short short8;
typedef __attribute__((ext_vector_type(4))) float f32x4;

__device__ __forceinline__ float softplus_f(float x) {
    return fmaxf(x, 0.0f) + log1pf(expf(-fabsf(x)));
}
// round fp32 -> bf16 bits (RNE)
__device__ __forceinline__ unsigned int bfr(float x) {
    unsigned int u = __float_as_uint(x);
    return (u + 0x7fffu + ((u >> 16) & 1u)) >> 16;
}
__device__ __forceinline__ float bf_lo(unsigned int p) { return __uint_as_float(p << 16); }
__device__ __forceinline__ float bf_hi(unsigned int p) { return __uint_as_float(p & 0xffff0000u); }

// h = x @ W_emb + b_emb   [N,92]x[92,64]
__global__ __launch_bounds__(256) void k_embed(const float* __restrict__ x,
                                               const float* __restrict__ W,
                                               const float* __restrict__ b,
                                               float* __restrict__ h) {
    __shared__ float xt[16][ORIG];
    int n0 = blockIdx.x * 16;
    for (int i = threadIdx.x; i < 16 * ORIG; i += 256) {
        int nn = i / ORIG, kk = i - nn * ORIG;
        xt[nn][kk] = x[(n0 + nn) * ORIG + kk];
    }
    __syncthreads();
    int c = threadIdx.x & 63, jg = threadIdx.x >> 6;
    float acc[4];
    float bias = b[c];
#pragma unroll
    for (int j = 0; j < 4; ++j) acc[j] = bias;
    for (int k = 0; k < ORIG; ++k) {
        float w = W[k * ATOM + c];
#pragma unroll
        for (int j = 0; j < 4; ++j) acc[j] += xt[jg * 4 + j][k] * w;
    }
#pragma unroll
    for (int j = 0; j < 4; ++j) h[(n0 + jg * 4 + j) * ATOM + c] = acc[j];
}

__global__ __launch_bounds__(256) void k_hist(const int* __restrict__ ei,
                                              int* __restrict__ cnt) {
    int e = blockIdx.x * 256 + threadIdx.x;
    if (e < N_EDGES) atomicAdd(&cnt[ei[N_EDGES + e]], 1);
}

__global__ __launch_bounds__(SCAN_BS) void k_tilesum(const int* __restrict__ cnt,
                                                     int* __restrict__ bsum) {
    __shared__ int s[SCAN_BS];
    int i = blockIdx.x * SCAN_BS + threadIdx.x;
    s[threadIdx.x] = (i < N_NODES) ? cnt[i] : 0;
    __syncthreads();
    for (int d = SCAN_BS / 2; d > 0; d >>= 1) {
        if (threadIdx.x < d) s[threadIdx.x] += s[threadIdx.x + d];
        __syncthreads();
    }
    if (threadIdx.x == 0) bsum[blockIdx.x] = s[0];
}

__global__ __launch_bounds__(512) void k_bscan(const int* __restrict__ bsum,
                                               int* __restrict__ bpre,
                                               int* __restrict__ offs) {
    __shared__ int s[512];
    int t = threadIdx.x;
    int v = (t < NTILE) ? bsum[t] : 0;
    s[t] = v;
    __syncthreads();
    for (int d = 1; d < 512; d <<= 1) {
        int u = (t >= d) ? s[t - d] : 0;
        __syncthreads();
        s[t] += u;
        __syncthreads();
    }
    if (t < NTILE) bpre[t] = s[t] - v;
    if (t == 511) offs[N_NODES] = s[511];
}

__global__ __launch_bounds__(SCAN_BS) void k_tilescan(const int* __restrict__ cnt,
                                                      const int* __restrict__ bpre,
                                                      int* __restrict__ offs,
                                                      int* __restrict__ cursor) {
    __shared__ int s[SCAN_BS];
    int i = blockIdx.x * SCAN_BS + threadIdx.x;
    int v = (i < N_NODES) ? cnt[i] : 0;
    s[threadIdx.x] = v;
    __syncthreads();
    for (int d = 1; d < SCAN_BS; d <<= 1) {
        int u = (threadIdx.x >= d) ? s[threadIdx.x - d] : 0;
        __syncthreads();
        s[threadIdx.x] += u;
        __syncthreads();
    }
    if (i < N_NODES) {
        int ex = bpre[blockIdx.x] + s[threadIdx.x] - v;
        offs[i] = ex;
        cursor[i] = ex;
    }
}

__global__ __launch_bounds__(256) void k_scatter(const int* __restrict__ ei,
                                                 const float* __restrict__ ea,
                                                 int* __restrict__ cursor,
                                                 int2* __restrict__ sed) {
    int e = blockIdx.x * 256 + threadIdx.x;
    if (e >= N_EDGES) return;
    float a = ea[3 * e], b = ea[3 * e + 1], c = ea[3 * e + 2];
    float d = sqrtf(a * a + b * b + c * c);
    int dst = ei[N_EDGES + e];
    int pos = atomicAdd(&cursor[dst], 1);
    int2 v;
    v.x = ei[e];
    v.y = __float_as_int(d);
    sed[pos] = v;
}

// all-layers table: Tp[l][b][c] = pack_bf16(e(d_b)@Wf_e + bf, e(d_b)@Ws_e + bs)
__global__ __launch_bounds__(256) void k_table_all(const float* __restrict__ Wf,
                                                   const float* __restrict__ bf,
                                                   const float* __restrict__ Ws,
                                                   const float* __restrict__ bs,
                                                   unsigned int* __restrict__ Tp) {
    int c = threadIdx.x & 63;
    int b = blockIdx.x * 4 + (threadIdx.x >> 6);
    int l = blockIdx.y;
    if (b > TBINS) return;
    float d = b * (TMAX / TBINS);
    const float* Wfe = Wf + (size_t)l * ZD * ATOM + 2 * ATOM * ATOM + c;
    const float* Wse = Ws + (size_t)l * ZD * ATOM + 2 * ATOM * ATOM + c;
    float af = bf[l * ATOM + c], as = bs[l * ATOM + c];
    for (int k = 0; k < NBR; ++k) {
        float diff = d - 0.2f * k;
        float r = expf(-5.0f * diff * diff);
        af += r * Wfe[k * ATOM];
        as += r * Wse[k * ATOM];
    }
    Tp[(size_t)l * TS + b * 64 + c] = bfr(af) | (bfr(as) << 16);
}

// fused: (optional) BN+residual update of h, then MFMA projection -> Pi, Pj
// block = 256 thr (4 waves) = 64 nodes; N-tile 256 cols, K=64
__global__ __launch_bounds__(256) void k_nodeP_mfma(float* __restrict__ h,
                                                    const float* __restrict__ agg,
                                                    const float* __restrict__ ss,
                                                    const float* __restrict__ Wf,
                                                    const float* __restrict__ Ws,
                                                    int l, int upd,
                                                    unsigned int* __restrict__ Pi,
                                                    unsigned int* __restrict__ Pj) {
    __shared__ short A[64 * SP];
    __shared__ short B[256 * SP];
    int tid = threadIdx.x;
    int n0 = blockIdx.x * 64;
    // --- A fill (+fused update), feature pairs ---
    for (int i = tid; i < 64 * 32; i += 256) {
        int r = i >> 5, kp = i & 31;
        int node = n0 + r;
        int gi = node * 32 + kp;   // float2 index
        float2 hv = make_float2(0.f, 0.f);
        if (node < N_NODES) {
            hv = ((const float2*)h)[gi];
            if (upd) {
                float2 av = ((const float2*)agg)[gi];
                int c = kp * 2;
                float x0 = ss[c] * av.x + ss[64 + c] + hv.x;
                float x1 = ss[c + 1] * av.y + ss[64 + c + 1] + hv.y;
                hv.x = softplus_f(x0);
                hv.y = softplus_f(x1);
                ((float2*)h)[gi] = hv;
            }
        }
        *(unsigned int*)&A[r * SP + kp * 2] = bfr(hv.x) | (bfr(hv.y) << 16);
    }
    // --- B fill: thread -> fixed output col n, loop k pairs ---
    {
        int n = tid, m = n >> 6, c = n & 63;
        const float* Wb = ((m & 2) ? Ws : Wf) + (size_t)l * ZD * ATOM + (m & 1) * ATOM * ATOM + c;
        for (int kp = 0; kp < 32; ++kp) {
            float w0 = Wb[(2 * kp) * ATOM];
            float w1 = Wb[(2 * kp + 1) * ATOM];
            *(unsigned int*)&B[n * SP + kp * 2] = bfr(w0) | (bfr(w1) << 16);
        }
    }
    __syncthreads();
    int lane = tid & 63, w = tid >> 6;
    int c15 = lane & 15, kb = lane >> 4;
    short8 af[2];
#pragma unroll
    for (int s = 0; s < 2; ++s)
        af[s] = *(const short8*)&A[(16 * w + c15) * SP + s * 32 + kb * 8];
    f32x4 acc[16];
#pragma unroll
    for (int t = 0; t < 16; ++t) acc[t] = (f32x4){0.f, 0.f, 0.f, 0.f};
#pragma unroll
    for (int t = 0; t < 16; ++t) {
#pragma unroll
        for (int s = 0; s < 2; ++s) {
            short8 bf8 = *(const short8*)&B[(16 * t + c15) * SP + s * 32 + kb * 8];
            acc[t] = __builtin_amdgcn_mfma_f32_16x16x32_bf16(af[s], bf8, acc[t], 0, 0, 0);
        }
    }
    // epilogue: cols 0-63=Wf_i, 64-127=Wf_j, 128-191=Ws_i, 192-255=Ws_j
#pragma unroll
    for (int t = 0; t < 4; ++t) {
#pragma unroll
        for (int reg = 0; reg < 4; ++reg) {
            int row = kb * 4 + reg;
            int node = n0 + 16 * w + row;
            if (node < N_NODES) {
                Pi[(size_t)node * 64 + 16 * t + c15] =
                    bfr(acc[t][reg]) | (bfr(acc[t + 8][reg]) << 16);
                Pj[(size_t)node * 64 + 16 * t + c15] =
                    bfr(acc[t + 4][reg]) | (bfr(acc[t + 12][reg]) << 16);
            }
        }
    }
}

// one wave per node; scalar sed reads + UN-deep independent gathers + fast math
#define UN 16
__global__ __launch_bounds__(256) void k_edge_sorted(const int* __restrict__ offs,
                                                     const int2* __restrict__ sed,
                                                     const unsigned int* __restrict__ Pi,
                                                     const unsigned int* __restrict__ Pj,
                                                     const unsigned int* __restrict__ Tp,
                                                     float* __restrict__ agg) {
    int wid = (blockIdx.x * 256 + threadIdx.x) >> 6;
    int lane = threadIdx.x & 63;
    if (wid >= N_NODES) return;
    int ko = offs[wid], ke = offs[wid + 1];
    unsigned int pi = Pi[(size_t)wid * 64 + lane];
    float gi = bf_lo(pi), ci = bf_hi(pi);
    float acc = 0.0f;
    for (int k0 = ko; k0 < ke; k0 += UN) {
        unsigned int tj[UN], pj[UN];
#pragma unroll
        for (int j = 0; j < UN; ++j) {
            int kk = k0 + j;
            int kc = (kk < ke) ? kk : (ke - 1);
            int2 sd = sed[kc];
            int src = __builtin_amdgcn_readfirstlane(sd.x);
            float d = __uint_as_float((unsigned int)__builtin_amdgcn_readfirstlane(sd.y));
            int b = (int)fminf(fmaf(d, (float)TBINS / TMAX, 0.5f), (float)TBINS);
            tj[j] = Tp[(size_t)b * 64 + lane];
            pj[j] = Pj[(size_t)src * 64 + lane];
        }
#pragma unroll
        for (int j = 0; j < UN; ++j) {
            float g = gi + bf_lo(pj[j]) + bf_lo(tj[j]);
            float c = ci + bf_hi(pj[j]) + bf_hi(tj[j]);
            float sg = __builtin_amdgcn_rcpf(1.0f + __expf(-g));
            float sp = fmaxf(c, 0.0f) + __logf(1.0f + __expf(-fabsf(c)));
            float msk = (k0 + j < ke) ? 1.0f : 0.0f;
            acc = fmaf(sg * sp, msk, acc);
        }
    }
    agg[(size_t)wid * 64 + lane] = acc;
}

// fixed-grid partials, no atomics
__global__ __launch_bounds__(256) void k_bnstats(const float* __restrict__ agg,
                                                 float* __restrict__ partial) {
    __shared__ float ls[256], ls2[256];
    int c = threadIdx.x & 63, rg = threadIdx.x >> 6;
    float s = 0.0f, s2 = 0.0f;
    for (int n = blockIdx.x * 4 + rg; n < N_NODES; n += NPBLK * 4) {
        float v = agg[(size_t)n * ATOM + c];
        s += v; s2 += v * v;
    }
    ls[threadIdx.x] = s; ls2[threadIdx.x] = s2;
    __syncthreads();
    if (threadIdx.x < 64) {
        s = ls[c] + ls[64 + c] + ls[128 + c] + ls[192 + c];
        s2 = ls2[c] + ls2[64 + c] + ls2[128 + c] + ls2[192 + c];
        partial[blockIdx.x * 128 + c] = s;
        partial[blockIdx.x * 128 + 64 + c] = s2;
    }
}

__global__ __launch_bounds__(128) void k_bnfinal(const float* __restrict__ partial,
                                                 const float* __restrict__ gamma,
                                                 const float* __restrict__ beta,
                                                 int l, float* __restrict__ ss) {
    __shared__ float red[128];
    int t = threadIdx.x;
    float s = 0.0f;
    for (int b = 0; b < NPBLK; ++b) s += partial[b * 128 + t];
    red[t] = s;
    __syncthreads();
    if (t < 64) {
        const float inv = 1.0f / (float)N_NODES;
        float mu = red[t] * inv;
        float var = red[64 + t] * inv - mu * mu;
        float sc = gamma[l * ATOM + t] * rsqrtf(var + 1e-5f);
        ss[t] = sc;
        ss[64 + t] = beta[l * ATOM + t] - mu * sc;
    }
}

// fused final update + pool
__global__ __launch_bounds__(256) void k_pool(const float* __restrict__ agg,
                                              const float* __restrict__ ss,
                                              const float* __restrict__ h,
                                              const int* __restrict__ batch,
                                              float* __restrict__ g) {
    int t = blockIdx.x * 256 + threadIdx.x;
    int n = t >> 6, c = t & 63;
    float x = ss[c] * agg[t] + ss[64 + c] + h[t];
    atomicAdd(&g[(size_t)batch[n] * ATOM + c], softplus_f(x));
}

__global__ __launch_bounds__(128) void k_head(const float* __restrict__ g,
                                              const float* __restrict__ W1,
                                              const float* __restrict__ b1,
                                              const float* __restrict__ W2,
                                              const float* __restrict__ b2,
                                              float* __restrict__ out) {
    __shared__ float red[128];
    int gid = blockIdx.x, j = threadIdx.x;
    float acc = b1[j];
    for (int k = 0; k < ATOM; ++k) acc += g[gid * ATOM + k] * W1[k * HFEA + j];
    red[j] = softplus_f(acc) * W2[j];
    __syncthreads();
    for (int s = 64; s > 0; s >>= 1) {
        if (j < s) red[j] += red[j + s];
        __syncthreads();
    }
    if (j == 0) out[gid] = red[0] + b2[0];
}

extern "C" void kernel_launch(void* const* d_in, const int* in_sizes, int n_in,
                              void* d_out, int out_size, void* d_ws, size_t ws_size,
                              hipStream_t stream) {
    const float* x       = (const float*)d_in[0];
    const float* ea      = (const float*)d_in[1];
    const float* W_emb   = (const float*)d_in[2];
    const float* b_emb   = (const float*)d_in[3];
    const float* Wf      = (const float*)d_in[4];
    const float* bf      = (const float*)d_in[5];
    const float* Ws      = (const float*)d_in[6];
    const float* bs      = (const float*)d_in[7];
    const float* bn_g    = (const float*)d_in[8];
    const float* bn_b    = (const float*)d_in[9];
    const float* W1      = (const float*)d_in[10];
    const float* b1      = (const float*)d_in[11];
    const float* W2      = (const float*)d_in[12];
    const float* b2      = (const float*)d_in[13];
    const int*   ei      = (const int*)d_in[14];
    const int*   batch   = (const int*)d_in[15];
    float* out = (float*)d_out;

    char* wsb = (char*)d_ws;
    size_t off = 0;
    auto alloc = [&](size_t bytes) { char* p = wsb + off; off += (bytes + 255) & ~(size_t)255; return p; };
    float*        h      = (float*)alloc((size_t)N_NODES * 64 * 4);
    float*        agg    = (float*)alloc((size_t)N_NODES * 64 * 4);
    unsigned int* Pi     = (unsigned int*)alloc((size_t)N_NODES * 64 * 4);
    unsigned int* Pj     = (unsigned int*)alloc((size_t)N_NODES * 64 * 4);
    int2*         sed    = (int2*)alloc((size_t)N_EDGES * 8);
    int*          cnt    = (int*)alloc((size_t)N_NODES * 4);
    int*          offs   = (int*)alloc((size_t)(N_NODES + 1) * 4);
    int*          cursor = (int*)alloc((size_t)N_NODES * 4);
    int*          bsum   = (int*)alloc((size_t)NTILE * 4);
    int*          bpre   = (int*)alloc((size_t)NTILE * 4);
    unsigned int* Tp     = (unsigned int*)alloc((size_t)NCONV * TS * 4);
    float*        partial= (float*)alloc((size_t)NPBLK * 128 * 4);
    float*        ss     = (float*)alloc(128 * 4);
    float*        g      = (float*)alloc((size_t)NGRAPH * 64 * 4);

    k_embed<<<N_NODES / 16, 256, 0, stream>>>(x, W_emb, b_emb, h);

    hipMemsetAsync(cnt, 0, (size_t)N_NODES * 4, stream);
    k_hist<<<(N_EDGES + 255) / 256, 256, 0, stream>>>(ei, cnt);
    k_tilesum<<<NTILE, SCAN_BS, 0, stream>>>(cnt, bsum);
    k_bscan<<<1, 512, 0, stream>>>(bsum, bpre, offs);
    k_tilescan<<<NTILE, SCAN_BS, 0, stream>>>(cnt, bpre, offs, cursor);
    k_scatter<<<(N_EDGES + 255) / 256, 256, 0, stream>>>(ei, ea, cursor, sed);

    dim3 tg((TBINS + 4) / 4, NCONV);
    k_table_all<<<tg, 256, 0, stream>>>(Wf, bf, Ws, bs, Tp);

    for (int l = 0; l < NCONV; ++l) {
        k_nodeP_mfma<<<(N_NODES + 63) / 64, 256, 0, stream>>>(h, agg, ss, Wf, Ws, l, l > 0, Pi, Pj);
        k_edge_sorted<<<(N_NODES * 64 + 255) / 256, 256, 0, stream>>>(
            offs, sed, Pi, Pj, Tp + (size_t)l * TS, agg);
        k_bnstats<<<NPBLK, 256, 0, stream>>>(agg, partial);
        k_bnfinal<<<1, 128, 0, stream>>>(partial, bn_g, bn_b, l, ss);
    }

    hipMemsetAsync(g, 0, (size_t)NGRAPH * 64 * 4, stream);
    k_pool<<<(size_t)N_NODES * 64 / 256, 256, 0, stream>>>(agg, ss, h, batch, g);
    k_head<<<NGRAPH, 128, 0, stream>>>(g, W1, b1, W2, b2, out);
}

// Round 6
// 916.759 us; speedup vs baseline: 2.2638x; 1.1696x over previous
//
#include <hip/hip_runtime.h>
#include <hip/hip_bf16.h>
#include <math.h>

#define N_NODES 100000
#define N_EDGES 1600000
#define ORIG    92
#define NBR     41
#define ATOM    64
#define NCONV   3
#define HFEA    128
#define NGRAPH  256
#define ZD      169           // 2*ATOM + NBR
#define TBINS   5120
#define TMAX    10.0f
#define TS      ((TBINS + 1) * 64)   // per-layer table stride (uints)
#define SCAN_BS 256
#define NTILE   ((N_NODES + SCAN_BS - 1) / SCAN_BS)
#define SP      72                   // LDS row pad (elements) -> 144B, 16B-aligned
#define NPBLK   128                  // bnstats partial blocks

typedef __attribute__((ext_vector_type(8))) short short8;
typedef __attribute__((ext_vector_type(4))) float f32x4;

__device__ __forceinline__ float softplus_f(float x) {
    return fmaxf(x, 0.0f) + log1pf(expf(-fabsf(x)));
}
// round fp32 -> bf16 bits (RNE)
__device__ __forceinline__ unsigned int bfr(float x) {
    unsigned int u = __float_as_uint(x);
    return (u + 0x7fffu + ((u >> 16) & 1u)) >> 16;
}
__device__ __forceinline__ float bf_lo(unsigned int p) { return __uint_as_float(p << 16); }
__device__ __forceinline__ float bf_hi(unsigned int p) { return __uint_as_float(p & 0xffff0000u); }
__device__ __forceinline__ float sig_fast(float x) {
    return __builtin_amdgcn_rcpf(1.0f + __expf(-x));
}
__device__ __forceinline__ float sp_fast(float x) {
    return fmaxf(x, 0.0f) + __logf(1.0f + __expf(-fabsf(x)));
}

// h = x @ W_emb + b_emb   [N,92]x[92,64]
__global__ __launch_bounds__(256) void k_embed(const float* __restrict__ x,
                                               const float* __restrict__ W,
                                               const float* __restrict__ b,
                                               float* __restrict__ h) {
    __shared__ float xt[16][ORIG];
    int n0 = blockIdx.x * 16;
    for (int i = threadIdx.x; i < 16 * ORIG; i += 256) {
        int nn = i / ORIG, kk = i - nn * ORIG;
        xt[nn][kk] = x[(n0 + nn) * ORIG + kk];
    }
    __syncthreads();
    int c = threadIdx.x & 63, jg = threadIdx.x >> 6;
    float acc[4];
    float bias = b[c];
#pragma unroll
    for (int j = 0; j < 4; ++j) acc[j] = bias;
    for (int k = 0; k < ORIG; ++k) {
        float w = W[k * ATOM + c];
#pragma unroll
        for (int j = 0; j < 4; ++j) acc[j] += xt[jg * 4 + j][k] * w;
    }
#pragma unroll
    for (int j = 0; j < 4; ++j) h[(n0 + jg * 4 + j) * ATOM + c] = acc[j];
}

__global__ __launch_bounds__(256) void k_hist(const int* __restrict__ ei,
                                              int* __restrict__ cnt) {
    int e = blockIdx.x * 256 + threadIdx.x;
    if (e < N_EDGES) atomicAdd(&cnt[ei[N_EDGES + e]], 1);
}

__global__ __launch_bounds__(SCAN_BS) void k_tilesum(const int* __restrict__ cnt,
                                                     int* __restrict__ bsum) {
    __shared__ int s[SCAN_BS];
    int i = blockIdx.x * SCAN_BS + threadIdx.x;
    s[threadIdx.x] = (i < N_NODES) ? cnt[i] : 0;
    __syncthreads();
    for (int d = SCAN_BS / 2; d > 0; d >>= 1) {
        if (threadIdx.x < d) s[threadIdx.x] += s[threadIdx.x + d];
        __syncthreads();
    }
    if (threadIdx.x == 0) bsum[blockIdx.x] = s[0];
}

__global__ __launch_bounds__(512) void k_bscan(const int* __restrict__ bsum,
                                               int* __restrict__ bpre,
                                               int* __restrict__ offs) {
    __shared__ int s[512];
    int t = threadIdx.x;
    int v = (t < NTILE) ? bsum[t] : 0;
    s[t] = v;
    __syncthreads();
    for (int d = 1; d < 512; d <<= 1) {
        int u = (t >= d) ? s[t - d] : 0;
        __syncthreads();
        s[t] += u;
        __syncthreads();
    }
    if (t < NTILE) bpre[t] = s[t] - v;
    if (t == 511) offs[N_NODES] = s[511];
}

__global__ __launch_bounds__(SCAN_BS) void k_tilescan(const int* __restrict__ cnt,
                                                      const int* __restrict__ bpre,
                                                      int* __restrict__ offs,
                                                      int* __restrict__ cursor) {
    __shared__ int s[SCAN_BS];
    int i = blockIdx.x * SCAN_BS + threadIdx.x;
    int v = (i < N_NODES) ? cnt[i] : 0;
    s[threadIdx.x] = v;
    __syncthreads();
    for (int d = 1; d < SCAN_BS; d <<= 1) {
        int u = (threadIdx.x >= d) ? s[threadIdx.x - d] : 0;
        __syncthreads();
        s[threadIdx.x] += u;
        __syncthreads();
    }
    if (i < N_NODES) {
        int ex = bpre[blockIdx.x] + s[threadIdx.x] - v;
        offs[i] = ex;
        cursor[i] = ex;
    }
}

__global__ __launch_bounds__(256) void k_scatter(const int* __restrict__ ei,
                                                 const float* __restrict__ ea,
                                                 int* __restrict__ cursor,
                                                 int2* __restrict__ sed) {
    int e = blockIdx.x * 256 + threadIdx.x;
    if (e >= N_EDGES) return;
    float a = ea[3 * e], b = ea[3 * e + 1], c = ea[3 * e + 2];
    float d = sqrtf(a * a + b * b + c * c);
    int dst = ei[N_EDGES + e];
    int pos = atomicAdd(&cursor[dst], 1);
    int2 v;
    v.x = ei[e];
    v.y = __float_as_int(d);
    sed[pos] = v;
}

// all-layers table: Tp[l][b][c] = pack_bf16(e(d_b)@Wf_e + bf, e(d_b)@Ws_e + bs)
__global__ __launch_bounds__(256) void k_table_all(const float* __restrict__ Wf,
                                                   const float* __restrict__ bf,
                                                   const float* __restrict__ Ws,
                                                   const float* __restrict__ bs,
                                                   unsigned int* __restrict__ Tp) {
    int c = threadIdx.x & 63;
    int b = blockIdx.x * 4 + (threadIdx.x >> 6);
    int l = blockIdx.y;
    if (b > TBINS) return;
    float d = b * (TMAX / TBINS);
    const float* Wfe = Wf + (size_t)l * ZD * ATOM + 2 * ATOM * ATOM + c;
    const float* Wse = Ws + (size_t)l * ZD * ATOM + 2 * ATOM * ATOM + c;
    float af = bf[l * ATOM + c], as = bs[l * ATOM + c];
    for (int k = 0; k < NBR; ++k) {
        float diff = d - 0.2f * k;
        float r = expf(-5.0f * diff * diff);
        af += r * Wfe[k * ATOM];
        as += r * Wse[k * ATOM];
    }
    Tp[(size_t)l * TS + b * 64 + c] = bfr(af) | (bfr(as) << 16);
}

// fused: (optional) BN+residual update of h, then MFMA projection -> Pi, Pj
__global__ __launch_bounds__(256) void k_nodeP_mfma(float* __restrict__ h,
                                                    const float* __restrict__ agg,
                                                    const float* __restrict__ ss,
                                                    const float* __restrict__ Wf,
                                                    const float* __restrict__ Ws,
                                                    int l, int upd,
                                                    unsigned int* __restrict__ Pi,
                                                    unsigned int* __restrict__ Pj) {
    __shared__ short A[64 * SP];
    __shared__ short B[256 * SP];
    int tid = threadIdx.x;
    int n0 = blockIdx.x * 64;
    for (int i = tid; i < 64 * 32; i += 256) {
        int r = i >> 5, kp = i & 31;
        int node = n0 + r;
        int gi = node * 32 + kp;
        float2 hv = make_float2(0.f, 0.f);
        if (node < N_NODES) {
            hv = ((const float2*)h)[gi];
            if (upd) {
                float2 av = ((const float2*)agg)[gi];
                int c = kp * 2;
                float x0 = ss[c] * av.x + ss[64 + c] + hv.x;
                float x1 = ss[c + 1] * av.y + ss[64 + c + 1] + hv.y;
                hv.x = softplus_f(x0);
                hv.y = softplus_f(x1);
                ((float2*)h)[gi] = hv;
            }
        }
        *(unsigned int*)&A[r * SP + kp * 2] = bfr(hv.x) | (bfr(hv.y) << 16);
    }
    {
        int n = tid, m = n >> 6, c = n & 63;
        const float* Wb = ((m & 2) ? Ws : Wf) + (size_t)l * ZD * ATOM + (m & 1) * ATOM * ATOM + c;
        for (int kp = 0; kp < 32; ++kp) {
            float w0 = Wb[(2 * kp) * ATOM];
            float w1 = Wb[(2 * kp + 1) * ATOM];
            *(unsigned int*)&B[n * SP + kp * 2] = bfr(w0) | (bfr(w1) << 16);
        }
    }
    __syncthreads();
    int lane = tid & 63, w = tid >> 6;
    int c15 = lane & 15, kb = lane >> 4;
    short8 af[2];
#pragma unroll
    for (int s = 0; s < 2; ++s)
        af[s] = *(const short8*)&A[(16 * w + c15) * SP + s * 32 + kb * 8];
    f32x4 acc[16];
#pragma unroll
    for (int t = 0; t < 16; ++t) acc[t] = (f32x4){0.f, 0.f, 0.f, 0.f};
#pragma unroll
    for (int t = 0; t < 16; ++t) {
#pragma unroll
        for (int s = 0; s < 2; ++s) {
            short8 bf8 = *(const short8*)&B[(16 * t + c15) * SP + s * 32 + kb * 8];
            acc[t] = __builtin_amdgcn_mfma_f32_16x16x32_bf16(af[s], bf8, acc[t], 0, 0, 0);
        }
    }
#pragma unroll
    for (int t = 0; t < 4; ++t) {
#pragma unroll
        for (int reg = 0; reg < 4; ++reg) {
            int row = kb * 4 + reg;
            int node = n0 + 16 * w + row;
            if (node < N_NODES) {
                Pi[(size_t)node * 64 + 16 * t + c15] =
                    bfr(acc[t][reg]) | (bfr(acc[t + 8][reg]) << 16);
                Pj[(size_t)node * 64 + 16 * t + c15] =
                    bfr(acc[t + 4][reg]) | (bfr(acc[t + 12][reg]) << 16);
            }
        }
    }
}

// one wave per node; pair-lane (2 edges/iter, uint2 per lane), 8-slot batches
#define UN 8
__global__ __launch_bounds__(256) void k_edge_sorted(const int* __restrict__ offs,
                                                     const int2* __restrict__ sed,
                                                     const unsigned int* __restrict__ Pi,
                                                     const unsigned int* __restrict__ Pj,
                                                     const unsigned int* __restrict__ Tp,
                                                     float* __restrict__ agg) {
    int wid = (blockIdx.x * 256 + threadIdx.x) >> 6;
    int lane = threadIdx.x & 63;
    if (wid >= N_NODES) return;
    int half = lane >> 5;          // 0: even-slot edge, 1: odd-slot edge
    int cp = lane & 31;            // column pair: cols 2cp, 2cp+1
    int ko = offs[wid], ke = offs[wid + 1];
    const uint2* Pi2 = (const uint2*)Pi;
    const uint2* Pj2 = (const uint2*)Pj;
    const uint2* Tp2 = (const uint2*)Tp;
    uint2 pi2 = Pi2[(size_t)wid * 32 + cp];
    float gi0 = bf_lo(pi2.x), ci0 = bf_hi(pi2.x);
    float gi1 = bf_lo(pi2.y), ci1 = bf_hi(pi2.y);
    float acc0 = 0.0f, acc1 = 0.0f;
    int k0 = ko;
    // ---- full 16-edge tiles: branch-free, mask-free ----
    for (; k0 + 2 * UN <= ke; k0 += 2 * UN) {
        uint2 tj[UN], pj[UN];
#pragma unroll
        for (int j = 0; j < UN; ++j) {
            int kk = k0 + 2 * j;
            int2 sd0 = sed[kk];
            int2 sd1 = sed[kk + 1];
            int s0 = __builtin_amdgcn_readfirstlane(sd0.x);
            int s1 = __builtin_amdgcn_readfirstlane(sd1.x);
            float d0 = __uint_as_float((unsigned int)__builtin_amdgcn_readfirstlane(sd0.y));
            float d1 = __uint_as_float((unsigned int)__builtin_amdgcn_readfirstlane(sd1.y));
            int src = half ? s1 : s0;
            float dv = half ? d1 : d0;
            int b = (int)fminf(fmaf(dv, (float)TBINS / TMAX, 0.5f), (float)TBINS);
            tj[j] = Tp2[(size_t)b * 32 + cp];
            pj[j] = Pj2[(size_t)src * 32 + cp];
        }
#pragma unroll
        for (int j = 0; j < UN; ++j) {
            float g0 = gi0 + bf_lo(pj[j].x) + bf_lo(tj[j].x);
            float c0 = ci0 + bf_hi(pj[j].x) + bf_hi(tj[j].x);
            float g1 = gi1 + bf_lo(pj[j].y) + bf_lo(tj[j].y);
            float c1 = ci1 + bf_hi(pj[j].y) + bf_hi(tj[j].y);
            acc0 += sig_fast(g0) * sp_fast(c0);
            acc1 += sig_fast(g1) * sp_fast(c1);
        }
    }
    // ---- remainder (<16 edges): one batch, uniform-branch guarded ----
    if (k0 < ke) {
        uint2 tj[UN], pj[UN];
#pragma unroll
        for (int j = 0; j < UN; ++j) {
            int kk = k0 + 2 * j;
            if (kk < ke) {
                int e1 = (kk + 1 < ke) ? (kk + 1) : kk;
                int2 sd0 = sed[kk];
                int2 sd1 = sed[e1];
                int s0 = __builtin_amdgcn_readfirstlane(sd0.x);
                int s1 = __builtin_amdgcn_readfirstlane(sd1.x);
                float d0 = __uint_as_float((unsigned int)__builtin_amdgcn_readfirstlane(sd0.y));
                float d1 = __uint_as_float((unsigned int)__builtin_amdgcn_readfirstlane(sd1.y));
                int src = half ? s1 : s0;
                float dv = half ? d1 : d0;
                int b = (int)fminf(fmaf(dv, (float)TBINS / TMAX, 0.5f), (float)TBINS);
                tj[j] = Tp2[(size_t)b * 32 + cp];
                pj[j] = Pj2[(size_t)src * 32 + cp];
            }
        }
#pragma unroll
        for (int j = 0; j < UN; ++j) {
            int kk = k0 + 2 * j;
            if (kk < ke) {
                float valid = (kk + half < ke) ? 1.0f : 0.0f;
                float g0 = gi0 + bf_lo(pj[j].x) + bf_lo(tj[j].x);
                float c0 = ci0 + bf_hi(pj[j].x) + bf_hi(tj[j].x);
                float g1 = gi1 + bf_lo(pj[j].y) + bf_lo(tj[j].y);
                float c1 = ci1 + bf_hi(pj[j].y) + bf_hi(tj[j].y);
                acc0 = fmaf(sig_fast(g0) * sp_fast(c0), valid, acc0);
                acc1 = fmaf(sig_fast(g1) * sp_fast(c1), valid, acc1);
            }
        }
    }
    // combine even/odd halves and store once
    acc0 += __shfl_xor(acc0, 32, 64);
    acc1 += __shfl_xor(acc1, 32, 64);
    if (lane < 32) {
        float2 o; o.x = acc0; o.y = acc1;
        ((float2*)agg)[(size_t)wid * 32 + cp] = o;
    }
}

// fixed-grid partials, no atomics
__global__ __launch_bounds__(256) void k_bnstats(const float* __restrict__ agg,
                                                 float* __restrict__ partial) {
    __shared__ float ls[256], ls2[256];
    int c = threadIdx.x & 63, rg = threadIdx.x >> 6;
    float s = 0.0f, s2 = 0.0f;
    for (int n = blockIdx.x * 4 + rg; n < N_NODES; n += NPBLK * 4) {
        float v = agg[(size_t)n * ATOM + c];
        s += v; s2 += v * v;
    }
    ls[threadIdx.x] = s; ls2[threadIdx.x] = s2;
    __syncthreads();
    if (threadIdx.x < 64) {
        s = ls[c] + ls[64 + c] + ls[128 + c] + ls[192 + c];
        s2 = ls2[c] + ls2[64 + c] + ls2[128 + c] + ls2[192 + c];
        partial[blockIdx.x * 128 + c] = s;
        partial[blockIdx.x * 128 + 64 + c] = s2;
    }
}

__global__ __launch_bounds__(128) void k_bnfinal(const float* __restrict__ partial,
                                                 const float* __restrict__ gamma,
                                                 const float* __restrict__ beta,
                                                 int l, float* __restrict__ ss) {
    __shared__ float red[128];
    int t = threadIdx.x;
    float s = 0.0f;
    for (int b = 0; b < NPBLK; ++b) s += partial[b * 128 + t];
    red[t] = s;
    __syncthreads();
    if (t < 64) {
        const float inv = 1.0f / (float)N_NODES;
        float mu = red[t] * inv;
        float var = red[64 + t] * inv - mu * mu;
        float sc = gamma[l * ATOM + t] * rsqrtf(var + 1e-5f);
        ss[t] = sc;
        ss[64 + t] = beta[l * ATOM + t] - mu * sc;
    }
}

// fused final update + pool
__global__ __launch_bounds__(256) void k_pool(const float* __restrict__ agg,
                                              const float* __restrict__ ss,
                                              const float* __restrict__ h,
                                              const int* __restrict__ batch,
                                              float* __restrict__ g) {
    int t = blockIdx.x * 256 + threadIdx.x;
    int n = t >> 6, c = t & 63;
    float x = ss[c] * agg[t] + ss[64 + c] + h[t];
    atomicAdd(&g[(size_t)batch[n] * ATOM + c], softplus_f(x));
}

__global__ __launch_bounds__(128) void k_head(const float* __restrict__ g,
                                              const float* __restrict__ W1,
                                              const float* __restrict__ b1,
                                              const float* __restrict__ W2,
                                              const float* __restrict__ b2,
                                              float* __restrict__ out) {
    __shared__ float red[128];
    int gid = blockIdx.x, j = threadIdx.x;
    float acc = b1[j];
    for (int k = 0; k < ATOM; ++k) acc += g[gid * ATOM + k] * W1[k * HFEA + j];
    red[j] = softplus_f(acc) * W2[j];
    __syncthreads();
    for (int s = 64; s > 0; s >>= 1) {
        if (j < s) red[j] += red[j + s];
        __syncthreads();
    }
    if (j == 0) out[gid] = red[0] + b2[0];
}

extern "C" void kernel_launch(void* const* d_in, const int* in_sizes, int n_in,
                              void* d_out, int out_size, void* d_ws, size_t ws_size,
                              hipStream_t stream) {
    const float* x       = (const float*)d_in[0];
    const float* ea      = (const float*)d_in[1];
    const float* W_emb   = (const float*)d_in[2];
    const float* b_emb   = (const float*)d_in[3];
    const float* Wf      = (const float*)d_in[4];
    const float* bf      = (const float*)d_in[5];
    const float* Ws      = (const float*)d_in[6];
    const float* bs      = (const float*)d_in[7];
    const float* bn_g    = (const float*)d_in[8];
    const float* bn_b    = (const float*)d_in[9];
    const float* W1      = (const float*)d_in[10];
    const float* b1      = (const float*)d_in[11];
    const float* W2      = (const float*)d_in[12];
    const float* b2      = (const float*)d_in[13];
    const int*   ei      = (const int*)d_in[14];
    const int*   batch   = (const int*)d_in[15];
    float* out = (float*)d_out;

    char* wsb = (char*)d_ws;
    size_t off = 0;
    auto alloc = [&](size_t bytes) { char* p = wsb + off; off += (bytes + 255) & ~(size_t)255; return p; };
    float*        h      = (float*)alloc((size_t)N_NODES * 64 * 4);
    float*        agg    = (float*)alloc((size_t)N_NODES * 64 * 4);
    unsigned int* Pi     = (unsigned int*)alloc((size_t)N_NODES * 64 * 4);
    unsigned int* Pj     = (unsigned int*)alloc((size_t)N_NODES * 64 * 4);
    int2*         sed    = (int2*)alloc((size_t)N_EDGES * 8);
    int*          cnt    = (int*)alloc((size_t)N_NODES * 4);
    int*          offs   = (int*)alloc((size_t)(N_NODES + 1) * 4);
    int*          cursor = (int*)alloc((size_t)N_NODES * 4);
    int*          bsum   = (int*)alloc((size_t)NTILE * 4);
    int*          bpre   = (int*)alloc((size_t)NTILE * 4);
    unsigned int* Tp     = (unsigned int*)alloc((size_t)NCONV * TS * 4);
    float*        partial= (float*)alloc((size_t)NPBLK * 128 * 4);
    float*        ss     = (float*)alloc(128 * 4);
    float*        g      = (float*)alloc((size_t)NGRAPH * 64 * 4);

    k_embed<<<N_NODES / 16, 256, 0, stream>>>(x, W_emb, b_emb, h);

    hipMemsetAsync(cnt, 0, (size_t)N_NODES * 4, stream);
    k_hist<<<(N_EDGES + 255) / 256, 256, 0, stream>>>(ei, cnt);
    k_tilesum<<<NTILE, SCAN_BS, 0, stream>>>(cnt, bsum);
    k_bscan<<<1, 512, 0, stream>>>(bsum, bpre, offs);
    k_tilescan<<<NTILE, SCAN_BS, 0, stream>>>(cnt, bpre, offs, cursor);
    k_scatter<<<(N_EDGES + 255) / 256, 256, 0, stream>>>(ei, ea, cursor, sed);

    dim3 tg((TBINS + 4) / 4, NCONV);
    k_table_all<<<tg, 256, 0, stream>>>(Wf, bf, Ws, bs, Tp);

    for (int l = 0; l < NCONV; ++l) {
        k_nodeP_mfma<<<(N_NODES + 63) / 64, 256, 0, stream>>>(h, agg, ss, Wf, Ws, l, l > 0, Pi, Pj);
        k_edge_sorted<<<(N_NODES * 64 + 255) / 256, 256, 0, stream>>>(
            offs, sed, Pi, Pj, Tp + (size_t)l * TS, agg);
        k_bnstats<<<NPBLK, 256, 0, stream>>>(agg, partial);
        k_bnfinal<<<1, 128, 0, stream>>>(partial, bn_g, bn_b, l, ss);
    }

    hipMemsetAsync(g, 0, (size_t)NGRAPH * 64 * 4, stream);
    k_pool<<<(size_t)N_NODES * 64 / 256, 256, 0, stream>>>(agg, ss, h, batch, g);
    k_head<<<NGRAPH, 128, 0, stream>>>(g, W1, b1, W2, b2, out);
}

// Round 7
// 887.772 us; speedup vs baseline: 2.3377x; 1.0327x over previous
//
#include <hip/hip_runtime.h>
#include <hip/hip_bf16.h>
#include <math.h>

#define N_NODES 100000
#define N_EDGES 1600000
#define ORIG    92
#define NBR     41
#define ATOM    64
#define NCONV   3
#define HFEA    128
#define NGRAPH  256
#define ZD      169           // 2*ATOM + NBR
#define TBINS   5120
#define TMAX    10.0f
#define TS      ((TBINS + 1) * 64)   // per-layer table stride (uints)
#define SCAN_BS 256
#define NTILE   ((N_NODES + SCAN_BS - 1) / SCAN_BS)
#define SP      72                   // LDS row pad (shorts) -> 144B, 16B-aligned
#define NPBLK   128                  // bnstats partial blocks

typedef __attribute__((ext_vector_type(8))) short short8;
typedef __attribute__((ext_vector_type(4))) float f32x4;

__device__ __forceinline__ float softplus_f(float x) {
    return fmaxf(x, 0.0f) + log1pf(expf(-fabsf(x)));
}
// round fp32 -> bf16 bits (RNE)
__device__ __forceinline__ unsigned int bfr(float x) {
    unsigned int u = __float_as_uint(x);
    return (u + 0x7fffu + ((u >> 16) & 1u)) >> 16;
}
__device__ __forceinline__ float bf_lo(unsigned int p) { return __uint_as_float(p << 16); }
__device__ __forceinline__ float bf_hi(unsigned int p) { return __uint_as_float(p & 0xffff0000u); }
__device__ __forceinline__ float sig_fast(float x) {
    return __builtin_amdgcn_rcpf(1.0f + __expf(-x));
}
__device__ __forceinline__ float sp_fast(float x) {
    return fmaxf(x, 0.0f) + __logf(1.0f + __expf(-fabsf(x)));
}

// h = x @ W_emb + b_emb   [N,92]x[92,64]
__global__ __launch_bounds__(256) void k_embed(const float* __restrict__ x,
                                               const float* __restrict__ W,
                                               const float* __restrict__ b,
                                               float* __restrict__ h) {
    __shared__ float xt[16][ORIG];
    int n0 = blockIdx.x * 16;
    for (int i = threadIdx.x; i < 16 * ORIG; i += 256) {
        int nn = i / ORIG, kk = i - nn * ORIG;
        xt[nn][kk] = x[(n0 + nn) * ORIG + kk];
    }
    __syncthreads();
    int c = threadIdx.x & 63, jg = threadIdx.x >> 6;
    float acc[4];
    float bias = b[c];
#pragma unroll
    for (int j = 0; j < 4; ++j) acc[j] = bias;
    for (int k = 0; k < ORIG; ++k) {
        float w = W[k * ATOM + c];
#pragma unroll
        for (int j = 0; j < 4; ++j) acc[j] += xt[jg * 4 + j][k] * w;
    }
#pragma unroll
    for (int j = 0; j < 4; ++j) h[(n0 + jg * 4 + j) * ATOM + c] = acc[j];
}

__global__ __launch_bounds__(256) void k_hist(const int* __restrict__ ei,
                                              int* __restrict__ cnt) {
    int e = blockIdx.x * 256 + threadIdx.x;
    if (e < N_EDGES) atomicAdd(&cnt[ei[N_EDGES + e]], 1);
}

__global__ __launch_bounds__(SCAN_BS) void k_tilesum(const int* __restrict__ cnt,
                                                     int* __restrict__ bsum) {
    __shared__ int s[SCAN_BS];
    int i = blockIdx.x * SCAN_BS + threadIdx.x;
    s[threadIdx.x] = (i < N_NODES) ? cnt[i] : 0;
    __syncthreads();
    for (int d = SCAN_BS / 2; d > 0; d >>= 1) {
        if (threadIdx.x < d) s[threadIdx.x] += s[threadIdx.x + d];
        __syncthreads();
    }
    if (threadIdx.x == 0) bsum[blockIdx.x] = s[0];
}

__global__ __launch_bounds__(512) void k_bscan(const int* __restrict__ bsum,
                                               int* __restrict__ bpre,
                                               int* __restrict__ offs) {
    __shared__ int s[512];
    int t = threadIdx.x;
    int v = (t < NTILE) ? bsum[t] : 0;
    s[t] = v;
    __syncthreads();
    for (int d = 1; d < 512; d <<= 1) {
        int u = (t >= d) ? s[t - d] : 0;
        __syncthreads();
        s[t] += u;
        __syncthreads();
    }
    if (t < NTILE) bpre[t] = s[t] - v;
    if (t == 511) offs[N_NODES] = s[511];
}

__global__ __launch_bounds__(SCAN_BS) void k_tilescan(const int* __restrict__ cnt,
                                                      const int* __restrict__ bpre,
                                                      int* __restrict__ offs,
                                                      int* __restrict__ cursor) {
    __shared__ int s[SCAN_BS];
    int i = blockIdx.x * SCAN_BS + threadIdx.x;
    int v = (i < N_NODES) ? cnt[i] : 0;
    s[threadIdx.x] = v;
    __syncthreads();
    for (int d = 1; d < SCAN_BS; d <<= 1) {
        int u = (threadIdx.x >= d) ? s[threadIdx.x - d] : 0;
        __syncthreads();
        s[threadIdx.x] += u;
        __syncthreads();
    }
    if (i < N_NODES) {
        int ex = bpre[blockIdx.x] + s[threadIdx.x] - v;
        offs[i] = ex;
        cursor[i] = ex;
    }
}

__global__ __launch_bounds__(256) void k_scatter(const int* __restrict__ ei,
                                                 const float* __restrict__ ea,
                                                 int* __restrict__ cursor,
                                                 int2* __restrict__ sed) {
    int e = blockIdx.x * 256 + threadIdx.x;
    if (e >= N_EDGES) return;
    float a = ea[3 * e], b = ea[3 * e + 1], c = ea[3 * e + 2];
    float d = sqrtf(a * a + b * b + c * c);
    int dst = ei[N_EDGES + e];
    int pos = atomicAdd(&cursor[dst], 1);
    int2 v;
    v.x = ei[e];
    v.y = __float_as_int(d);
    sed[pos] = v;
}

// pre-pack node-part weights to bf16: Bp[l][n(0..255)][kp(0..31)]
__global__ __launch_bounds__(256) void k_prepW(const float* __restrict__ Wf,
                                               const float* __restrict__ Ws,
                                               unsigned int* __restrict__ Bp) {
    int l = blockIdx.x;
    int tid = threadIdx.x;
    int m = tid >> 6, c = tid & 63;
    const float* Wb = ((m & 2) ? Ws : Wf) + (size_t)l * ZD * ATOM + (m & 1) * ATOM * ATOM + c;
    unsigned int* dst = Bp + (size_t)l * 8192 + (size_t)tid * 32;
    for (int kp = 0; kp < 32; ++kp) {
        float w0 = Wb[(2 * kp) * ATOM];
        float w1 = Wb[(2 * kp + 1) * ATOM];
        dst[kp] = bfr(w0) | (bfr(w1) << 16);
    }
}

// T = R(d) @ W_e  (RBF computed once per bin, W_e cached in LDS)
__global__ __launch_bounds__(256) void k_table2(const float* __restrict__ Wf,
                                                const float* __restrict__ bf,
                                                const float* __restrict__ Ws,
                                                const float* __restrict__ bs,
                                                unsigned int* __restrict__ Tp) {
    __shared__ float Wc[NBR * 64], Wsc[NBR * 64], R[32 * NBR];
    int tid = threadIdx.x;
    int l = blockIdx.y;
    int b0 = blockIdx.x * 32;
    const float* srcf = Wf + (size_t)l * ZD * ATOM + 2 * ATOM * ATOM;
    const float* srcs = Ws + (size_t)l * ZD * ATOM + 2 * ATOM * ATOM;
    for (int i = tid; i < NBR * 64; i += 256) {
        Wc[i] = srcf[i];
        Wsc[i] = srcs[i];
    }
    for (int i = tid; i < 32 * NBR; i += 256) {
        int bin = i / NBR, k = i - bin * NBR;
        float d = (b0 + bin) * (TMAX / TBINS);
        float diff = d - 0.2f * k;
        R[i] = __expf(-5.0f * diff * diff * 1.4426950408889634f);  // exp2 scale
    }
    __syncthreads();
    int c = tid & 63;
    float afb = bf[l * ATOM + c], asb = bs[l * ATOM + c];
#pragma unroll
    for (int it = 0; it < 8; ++it) {
        int bin = (tid >> 6) + 4 * it;
        int gb = b0 + bin;
        if (gb <= TBINS) {
            float af = afb, as = asb;
            for (int k = 0; k < NBR; ++k) {
                float r = R[bin * NBR + k];
                af += r * Wc[k * 64 + c];
                as += r * Wsc[k * 64 + c];
            }
            Tp[(size_t)l * TS + (size_t)gb * 64 + c] = bfr(af) | (bfr(as) << 16);
        }
    }
}

// fused: (optional) BN+residual update of h, then MFMA projection -> Pi, Pj
__global__ __launch_bounds__(256) void k_nodeP_mfma(float* __restrict__ h,
                                                    const float* __restrict__ agg,
                                                    const float* __restrict__ ss,
                                                    const unsigned int* __restrict__ Bp,
                                                    int l, int upd,
                                                    unsigned int* __restrict__ Pi,
                                                    unsigned int* __restrict__ Pj) {
    __shared__ short A[64 * SP];
    __shared__ short B[256 * SP];
    int tid = threadIdx.x;
    int n0 = blockIdx.x * 64;
    for (int i = tid; i < 64 * 32; i += 256) {
        int r = i >> 5, kp = i & 31;
        int node = n0 + r;
        int gi = node * 32 + kp;
        float2 hv = make_float2(0.f, 0.f);
        if (node < N_NODES) {
            hv = ((const float2*)h)[gi];
            if (upd) {
                float2 av = ((const float2*)agg)[gi];
                int c = kp * 2;
                float x0 = ss[c] * av.x + ss[64 + c] + hv.x;
                float x1 = ss[c + 1] * av.y + ss[64 + c + 1] + hv.y;
                hv.x = softplus_f(x0);
                hv.y = softplus_f(x1);
                ((float2*)h)[gi] = hv;
            }
        }
        *(unsigned int*)&A[r * SP + kp * 2] = bfr(hv.x) | (bfr(hv.y) << 16);
    }
    {
        const uint4* src = (const uint4*)(Bp + (size_t)l * 8192);
        for (int i = tid; i < 2048; i += 256) {
            int row = i >> 3, j = i & 7;
            *(uint4*)&B[row * SP + j * 8] = src[row * 8 + j];
        }
    }
    __syncthreads();
    int lane = tid & 63, w = tid >> 6;
    int c15 = lane & 15, kb = lane >> 4;
    short8 af[2];
#pragma unroll
    for (int s = 0; s < 2; ++s)
        af[s] = *(const short8*)&A[(16 * w + c15) * SP + s * 32 + kb * 8];
    f32x4 acc[16];
#pragma unroll
    for (int t = 0; t < 16; ++t) acc[t] = (f32x4){0.f, 0.f, 0.f, 0.f};
#pragma unroll
    for (int t = 0; t < 16; ++t) {
#pragma unroll
        for (int s = 0; s < 2; ++s) {
            short8 bf8 = *(const short8*)&B[(16 * t + c15) * SP + s * 32 + kb * 8];
            acc[t] = __builtin_amdgcn_mfma_f32_16x16x32_bf16(af[s], bf8, acc[t], 0, 0, 0);
        }
    }
#pragma unroll
    for (int t = 0; t < 4; ++t) {
#pragma unroll
        for (int reg = 0; reg < 4; ++reg) {
            int row = kb * 4 + reg;
            int node = n0 + 16 * w + row;
            if (node < N_NODES) {
                Pi[(size_t)node * 64 + 16 * t + c15] =
                    bfr(acc[t][reg]) | (bfr(acc[t + 8][reg]) << 16);
                Pj[(size_t)node * 64 + 16 * t + c15] =
                    bfr(acc[t + 4][reg]) | (bfr(acc[t + 12][reg]) << 16);
            }
        }
    }
}

// one wave per node; pair-lane (2 edges/iter, uint2 per lane), 8-slot batches
#define UN 8
__global__ __launch_bounds__(256) void k_edge_sorted(const int* __restrict__ offs,
                                                     const int2* __restrict__ sed,
                                                     const unsigned int* __restrict__ Pi,
                                                     const unsigned int* __restrict__ Pj,
                                                     const unsigned int* __restrict__ Tp,
                                                     float* __restrict__ agg) {
    int wid = (blockIdx.x * 256 + threadIdx.x) >> 6;
    int lane = threadIdx.x & 63;
    if (wid >= N_NODES) return;
    int half = lane >> 5;
    int cp = lane & 31;
    int ko = offs[wid], ke = offs[wid + 1];
    const uint2* Pi2 = (const uint2*)Pi;
    const uint2* Pj2 = (const uint2*)Pj;
    const uint2* Tp2 = (const uint2*)Tp;
    uint2 pi2 = Pi2[(size_t)wid * 32 + cp];
    float gi0 = bf_lo(pi2.x), ci0 = bf_hi(pi2.x);
    float gi1 = bf_lo(pi2.y), ci1 = bf_hi(pi2.y);
    float acc0 = 0.0f, acc1 = 0.0f;
    int k0 = ko;
    for (; k0 + 2 * UN <= ke; k0 += 2 * UN) {
        uint2 tj[UN], pj[UN];
#pragma unroll
        for (int j = 0; j < UN; ++j) {
            int kk = k0 + 2 * j;
            int2 sd0 = sed[kk];
            int2 sd1 = sed[kk + 1];
            int s0 = __builtin_amdgcn_readfirstlane(sd0.x);
            int s1 = __builtin_amdgcn_readfirstlane(sd1.x);
            float d0 = __uint_as_float((unsigned int)__builtin_amdgcn_readfirstlane(sd0.y));
            float d1 = __uint_as_float((unsigned int)__builtin_amdgcn_readfirstlane(sd1.y));
            int src = half ? s1 : s0;
            float dv = half ? d1 : d0;
            int b = (int)fminf(fmaf(dv, (float)TBINS / TMAX, 0.5f), (float)TBINS);
            tj[j] = Tp2[(size_t)b * 32 + cp];
            pj[j] = Pj2[(size_t)src * 32 + cp];
        }
#pragma unroll
        for (int j = 0; j < UN; ++j) {
            float g0 = gi0 + bf_lo(pj[j].x) + bf_lo(tj[j].x);
            float c0 = ci0 + bf_hi(pj[j].x) + bf_hi(tj[j].x);
            float g1 = gi1 + bf_lo(pj[j].y) + bf_lo(tj[j].y);
            float c1 = ci1 + bf_hi(pj[j].y) + bf_hi(tj[j].y);
            acc0 += sig_fast(g0) * sp_fast(c0);
            acc1 += sig_fast(g1) * sp_fast(c1);
        }
    }
    if (k0 < ke) {
        uint2 tj[UN], pj[UN];
#pragma unroll
        for (int j = 0; j < UN; ++j) {
            int kk = k0 + 2 * j;
            if (kk < ke) {
                int e1 = (kk + 1 < ke) ? (kk + 1) : kk;
                int2 sd0 = sed[kk];
                int2 sd1 = sed[e1];
                int s0 = __builtin_amdgcn_readfirstlane(sd0.x);
                int s1 = __builtin_amdgcn_readfirstlane(sd1.x);
                float d0 = __uint_as_float((unsigned int)__builtin_amdgcn_readfirstlane(sd0.y));
                float d1 = __uint_as_float((unsigned int)__builtin_amdgcn_readfirstlane(sd1.y));
                int src = half ? s1 : s0;
                float dv = half ? d1 : d0;
                int b = (int)fminf(fmaf(dv, (float)TBINS / TMAX, 0.5f), (float)TBINS);
                tj[j] = Tp2[(size_t)b * 32 + cp];
                pj[j] = Pj2[(size_t)src * 32 + cp];
            }
        }
#pragma unroll
        for (int j = 0; j < UN; ++j) {
            int kk = k0 + 2 * j;
            if (kk < ke) {
                float valid = (kk + half < ke) ? 1.0f : 0.0f;
                float g0 = gi0 + bf_lo(pj[j].x) + bf_lo(tj[j].x);
                float c0 = ci0 + bf_hi(pj[j].x) + bf_hi(tj[j].x);
                float g1 = gi1 + bf_lo(pj[j].y) + bf_lo(tj[j].y);
                float c1 = ci1 + bf_hi(pj[j].y) + bf_hi(tj[j].y);
                acc0 = fmaf(sig_fast(g0) * sp_fast(c0), valid, acc0);
                acc1 = fmaf(sig_fast(g1) * sp_fast(c1), valid, acc1);
            }
        }
    }
    acc0 += __shfl_xor(acc0, 32, 64);
    acc1 += __shfl_xor(acc1, 32, 64);
    if (lane < 32) {
        float2 o; o.x = acc0; o.y = acc1;
        ((float2*)agg)[(size_t)wid * 32 + cp] = o;
    }
}

// fixed-grid partials, no atomics
__global__ __launch_bounds__(256) void k_bnstats(const float* __restrict__ agg,
                                                 float* __restrict__ partial) {
    __shared__ float ls[256], ls2[256];
    int c = threadIdx.x & 63, rg = threadIdx.x >> 6;
    float s = 0.0f, s2 = 0.0f;
    for (int n = blockIdx.x * 4 + rg; n < N_NODES; n += NPBLK * 4) {
        float v = agg[(size_t)n * ATOM + c];
        s += v; s2 += v * v;
    }
    ls[threadIdx.x] = s; ls2[threadIdx.x] = s2;
    __syncthreads();
    if (threadIdx.x < 64) {
        s = ls[c] + ls[64 + c] + ls[128 + c] + ls[192 + c];
        s2 = ls2[c] + ls2[64 + c] + ls2[128 + c] + ls2[192 + c];
        partial[blockIdx.x * 128 + c] = s;
        partial[blockIdx.x * 128 + 64 + c] = s2;
    }
}

__global__ __launch_bounds__(128) void k_bnfinal(const float* __restrict__ partial,
                                                 const float* __restrict__ gamma,
                                                 const float* __restrict__ beta,
                                                 int l, float* __restrict__ ss) {
    __shared__ float red[128];
    int t = threadIdx.x;
    float s = 0.0f;
    for (int b = 0; b < NPBLK; ++b) s += partial[b * 128 + t];
    red[t] = s;
    __syncthreads();
    if (t < 64) {
        const float inv = 1.0f / (float)N_NODES;
        float mu = red[t] * inv;
        float var = red[64 + t] * inv - mu * mu;
        float sc = gamma[l * ATOM + t] * rsqrtf(var + 1e-5f);
        ss[t] = sc;
        ss[64 + t] = beta[l * ATOM + t] - mu * sc;
    }
}

// fused final update + pool; batch is sorted -> run-length accumulate
__global__ __launch_bounds__(256) void k_pool2(const float* __restrict__ agg,
                                               const float* __restrict__ ss,
                                               const float* __restrict__ h,
                                               const int* __restrict__ batch,
                                               float* __restrict__ g) {
    int w = threadIdx.x >> 6, lane = threadIdx.x & 63;
    int nbase = blockIdx.x * 64 + w * 16;
    float acc = 0.0f;
    int curg = -1;
    float sc = ss[lane], sh = ss[64 + lane];
    for (int i = 0; i < 16; ++i) {
        int n = nbase + i;
        if (n >= N_NODES) break;
        int gid = __builtin_amdgcn_readfirstlane(batch[n]);
        if (gid != curg) {
            if (curg >= 0) atomicAdd(&g[(size_t)curg * ATOM + lane], acc);
            curg = gid;
            acc = 0.0f;
        }
        float x = sc * agg[(size_t)n * 64 + lane] + sh + h[(size_t)n * 64 + lane];
        acc += softplus_f(x);
    }
    if (curg >= 0) atomicAdd(&g[(size_t)curg * ATOM + lane], acc);
}

__global__ __launch_bounds__(128) void k_head(const float* __restrict__ g,
                                              const float* __restrict__ W1,
                                              const float* __restrict__ b1,
                                              const float* __restrict__ W2,
                                              const float* __restrict__ b2,
                                              float* __restrict__ out) {
    __shared__ float red[128];
    int gid = blockIdx.x, j = threadIdx.x;
    float acc = b1[j];
    for (int k = 0; k < ATOM; ++k) acc += g[gid * ATOM + k] * W1[k * HFEA + j];
    red[j] = softplus_f(acc) * W2[j];
    __syncthreads();
    for (int s = 64; s > 0; s >>= 1) {
        if (j < s) red[j] += red[j + s];
        __syncthreads();
    }
    if (j == 0) out[gid] = red[0] + b2[0];
}

extern "C" void kernel_launch(void* const* d_in, const int* in_sizes, int n_in,
                              void* d_out, int out_size, void* d_ws, size_t ws_size,
                              hipStream_t stream) {
    const float* x       = (const float*)d_in[0];
    const float* ea      = (const float*)d_in[1];
    const float* W_emb   = (const float*)d_in[2];
    const float* b_emb   = (const float*)d_in[3];
    const float* Wf      = (const float*)d_in[4];
    const float* bf      = (const float*)d_in[5];
    const float* Ws      = (const float*)d_in[6];
    const float* bs      = (const float*)d_in[7];
    const float* bn_g    = (const float*)d_in[8];
    const float* bn_b    = (const float*)d_in[9];
    const float* W1      = (const float*)d_in[10];
    const float* b1      = (const float*)d_in[11];
    const float* W2      = (const float*)d_in[12];
    const float* b2      = (const float*)d_in[13];
    const int*   ei      = (const int*)d_in[14];
    const int*   batch   = (const int*)d_in[15];
    float* out = (float*)d_out;

    char* wsb = (char*)d_ws;
    size_t off = 0;
    auto alloc = [&](size_t bytes) { char* p = wsb + off; off += (bytes + 255) & ~(size_t)255; return p; };
    float*        h      = (float*)alloc((size_t)N_NODES * 64 * 4);
    float*        agg    = (float*)alloc((size_t)N_NODES * 64 * 4);
    unsigned int* Pi     = (unsigned int*)alloc((size_t)N_NODES * 64 * 4);
    unsigned int* Pj     = (unsigned int*)alloc((size_t)N_NODES * 64 * 4);
    int2*         sed    = (int2*)alloc((size_t)N_EDGES * 8);
    int*          cnt    = (int*)alloc((size_t)N_NODES * 4);
    int*          offs   = (int*)alloc((size_t)(N_NODES + 1) * 4);
    int*          cursor = (int*)alloc((size_t)N_NODES * 4);
    int*          bsum   = (int*)alloc((size_t)NTILE * 4);
    int*          bpre   = (int*)alloc((size_t)NTILE * 4);
    unsigned int* Tp     = (unsigned int*)alloc((size_t)NCONV * TS * 4);
    unsigned int* Bp     = (unsigned int*)alloc((size_t)NCONV * 8192 * 4);
    float*        partial= (float*)alloc((size_t)NPBLK * 128 * 4);
    float*        ss     = (float*)alloc(128 * 4);
    float*        g      = (float*)alloc((size_t)NGRAPH * 64 * 4);

    k_embed<<<N_NODES / 16, 256, 0, stream>>>(x, W_emb, b_emb, h);

    hipMemsetAsync(cnt, 0, (size_t)N_NODES * 4, stream);
    k_hist<<<(N_EDGES + 255) / 256, 256, 0, stream>>>(ei, cnt);
    k_tilesum<<<NTILE, SCAN_BS, 0, stream>>>(cnt, bsum);
    k_bscan<<<1, 512, 0, stream>>>(bsum, bpre, offs);
    k_tilescan<<<NTILE, SCAN_BS, 0, stream>>>(cnt, bpre, offs, cursor);
    k_scatter<<<(N_EDGES + 255) / 256, 256, 0, stream>>>(ei, ea, cursor, sed);

    k_prepW<<<NCONV, 256, 0, stream>>>(Wf, Ws, Bp);
    dim3 tg((TBINS + 32) / 32, NCONV);
    k_table2<<<tg, 256, 0, stream>>>(Wf, bf, Ws, bs, Tp);

    for (int l = 0; l < NCONV; ++l) {
        k_nodeP_mfma<<<(N_NODES + 63) / 64, 256, 0, stream>>>(h, agg, ss, Bp, l, l > 0, Pi, Pj);
        k_edge_sorted<<<(N_NODES * 64 + 255) / 256, 256, 0, stream>>>(
            offs, sed, Pi, Pj, Tp + (size_t)l * TS, agg);
        k_bnstats<<<NPBLK, 256, 0, stream>>>(agg, partial);
        k_bnfinal<<<1, 128, 0, stream>>>(partial, bn_g, bn_b, l, ss);
    }

    hipMemsetAsync(g, 0, (size_t)NGRAPH * 64 * 4, stream);
    k_pool2<<<(N_NODES + 63) / 64, 256, 0, stream>>>(agg, ss, h, batch, g);
    k_head<<<NGRAPH, 128, 0, stream>>>(g, W1, b1, W2, b2, out);
}

// Round 8
// 739.577 us; speedup vs baseline: 2.8061x; 1.2004x over previous
//
#include <hip/hip_runtime.h>
#include <hip/hip_bf16.h>
#include <math.h>

#define N_NODES 100000
#define N_EDGES 1600000
#define ORIG    92
#define NBR     41
#define ATOM    64
#define NCONV   3
#define HFEA    128
#define NGRAPH  256
#define ZD      169           // 2*ATOM + NBR
#define TBINS   5120
#define TMAX    10.0f
#define TS      ((TBINS + 1) * 64)   // per-layer table stride (uints)
#define SCAN_BS 256
#define NTILE   ((N_NODES + SCAN_BS - 1) / SCAN_BS)
#define SP      72                   // nodeP LDS row pad (shorts)
#define SPE     136                  // embed LDS row pad (shorts), K=128
#define NPBLK   128                  // bnstats partial blocks
#define LOG2E   1.4426950408889634f
#define LN2     0.6931471805599453f

typedef __attribute__((ext_vector_type(8))) short short8;
typedef __attribute__((ext_vector_type(4))) float f32x4;
typedef __attribute__((ext_vector_type(8))) int int8v;

__device__ __forceinline__ float softplus_f(float x) {
    return fmaxf(x, 0.0f) + log1pf(expf(-fabsf(x)));
}
// round fp32 -> bf16 bits (RNE)
__device__ __forceinline__ unsigned int bfr(float x) {
    unsigned int u = __float_as_uint(x);
    return (u + 0x7fffu + ((u >> 16) & 1u)) >> 16;
}
__device__ __forceinline__ float bf_lo(unsigned int p) { return __uint_as_float(p << 16); }
__device__ __forceinline__ float bf_hi(unsigned int p) { return __uint_as_float(p & 0xffff0000u); }

// ---------- one-shot preprocessing ----------

__global__ __launch_bounds__(256) void k_hist(const int* __restrict__ ei,
                                              int* __restrict__ cnt) {
    int e = blockIdx.x * 256 + threadIdx.x;
    if (e < N_EDGES) atomicAdd(&cnt[ei[N_EDGES + e]], 1);
}

__global__ __launch_bounds__(SCAN_BS) void k_tilesum(const int* __restrict__ cnt,
                                                     int* __restrict__ bsum) {
    __shared__ int s[SCAN_BS];
    int i = blockIdx.x * SCAN_BS + threadIdx.x;
    s[threadIdx.x] = (i < N_NODES) ? cnt[i] : 0;
    __syncthreads();
    for (int d = SCAN_BS / 2; d > 0; d >>= 1) {
        if (threadIdx.x < d) s[threadIdx.x] += s[threadIdx.x + d];
        __syncthreads();
    }
    if (threadIdx.x == 0) bsum[blockIdx.x] = s[0];
}

__global__ __launch_bounds__(512) void k_bscan(const int* __restrict__ bsum,
                                               int* __restrict__ bpre,
                                               int* __restrict__ offs) {
    __shared__ int s[512];
    int t = threadIdx.x;
    int v = (t < NTILE) ? bsum[t] : 0;
    s[t] = v;
    __syncthreads();
    for (int d = 1; d < 512; d <<= 1) {
        int u = (t >= d) ? s[t - d] : 0;
        __syncthreads();
        s[t] += u;
        __syncthreads();
    }
    if (t < NTILE) bpre[t] = s[t] - v;
    if (t == 511) offs[N_NODES] = s[511];
}

__global__ __launch_bounds__(SCAN_BS) void k_tilescan(const int* __restrict__ cnt,
                                                      const int* __restrict__ bpre,
                                                      int* __restrict__ offs,
                                                      int* __restrict__ cursor) {
    __shared__ int s[SCAN_BS];
    int i = blockIdx.x * SCAN_BS + threadIdx.x;
    int v = (i < N_NODES) ? cnt[i] : 0;
    s[threadIdx.x] = v;
    __syncthreads();
    for (int d = 1; d < SCAN_BS; d <<= 1) {
        int u = (threadIdx.x >= d) ? s[threadIdx.x - d] : 0;
        __syncthreads();
        s[threadIdx.x] += u;
        __syncthreads();
    }
    if (i < N_NODES) {
        int ex = bpre[blockIdx.x] + s[threadIdx.x] - v;
        offs[i] = ex;
        cursor[i] = ex;
    }
}

// SoA scatter: srcOff = src*256 (byte off in Pj), tOff = bin*256 (byte off in Tp layer)
__global__ __launch_bounds__(256) void k_scatter(const int* __restrict__ ei,
                                                 const float* __restrict__ ea,
                                                 int* __restrict__ cursor,
                                                 int* __restrict__ srcOff,
                                                 int* __restrict__ tOff) {
    int e = blockIdx.x * 256 + threadIdx.x;
    if (e >= N_EDGES) return;
    float a = ea[3 * e], b = ea[3 * e + 1], c = ea[3 * e + 2];
    float d = sqrtf(a * a + b * b + c * c);
    int bin = (int)fminf(fmaf(d, (float)TBINS / TMAX, 0.5f), (float)TBINS);
    int dst = ei[N_EDGES + e];
    int pos = atomicAdd(&cursor[dst], 1);
    srcOff[pos] = ei[e] * 256;
    tOff[pos] = bin * 256;
}

// node-part weights -> bf16, pre-scaled by log2e: Bp[l][n(0..255)][kp(0..31)]
__global__ __launch_bounds__(256) void k_prepW(const float* __restrict__ Wf,
                                               const float* __restrict__ Ws,
                                               unsigned int* __restrict__ Bp) {
    int l = blockIdx.x;
    int tid = threadIdx.x;
    int m = tid >> 6, c = tid & 63;
    const float* Wb = ((m & 2) ? Ws : Wf) + (size_t)l * ZD * ATOM + (m & 1) * ATOM * ATOM + c;
    unsigned int* dst = Bp + (size_t)l * 8192 + (size_t)tid * 32;
    for (int kp = 0; kp < 32; ++kp) {
        float w0 = Wb[(2 * kp) * ATOM] * LOG2E;
        float w1 = Wb[(2 * kp + 1) * ATOM] * LOG2E;
        dst[kp] = bfr(w0) | (bfr(w1) << 16);
    }
}

// embed weights -> bf16 [64 cols][64 k-pairs], K padded 92->128 (NOT scaled)
__global__ __launch_bounds__(256) void k_prepE(const float* __restrict__ W,
                                               unsigned int* __restrict__ BpE) {
    int n = threadIdx.x & 63, q = threadIdx.x >> 6;
    for (int kp = q * 16; kp < q * 16 + 16; ++kp) {
        int k0 = 2 * kp, k1 = 2 * kp + 1;
        float w0 = (k0 < ORIG) ? W[k0 * ATOM + n] : 0.f;
        float w1 = (k1 < ORIG) ? W[k1 * ATOM + n] : 0.f;
        BpE[(size_t)n * 64 + kp] = bfr(w0) | (bfr(w1) << 16);
    }
}

// T = R(d) @ W_e + bias, all pre-scaled by log2e
__global__ __launch_bounds__(256) void k_table2(const float* __restrict__ Wf,
                                                const float* __restrict__ bf,
                                                const float* __restrict__ Ws,
                                                const float* __restrict__ bs,
                                                unsigned int* __restrict__ Tp) {
    __shared__ float Wc[NBR * 64], Wsc[NBR * 64], R[32 * NBR];
    int tid = threadIdx.x;
    int l = blockIdx.y;
    int b0 = blockIdx.x * 32;
    const float* srcf = Wf + (size_t)l * ZD * ATOM + 2 * ATOM * ATOM;
    const float* srcs = Ws + (size_t)l * ZD * ATOM + 2 * ATOM * ATOM;
    for (int i = tid; i < NBR * 64; i += 256) {
        Wc[i] = srcf[i] * LOG2E;
        Wsc[i] = srcs[i] * LOG2E;
    }
    for (int i = tid; i < 32 * NBR; i += 256) {
        int bin = i / NBR, k = i - bin * NBR;
        float d = (b0 + bin) * (TMAX / TBINS);
        float diff = d - 0.2f * k;
        R[i] = expf(-5.0f * diff * diff);
    }
    __syncthreads();
    int c = tid & 63;
    float afb = bf[l * ATOM + c] * LOG2E, asb = bs[l * ATOM + c] * LOG2E;
#pragma unroll
    for (int it = 0; it < 8; ++it) {
        int bin = (tid >> 6) + 4 * it;
        int gb = b0 + bin;
        if (gb <= TBINS) {
            float af = afb, as = asb;
            for (int k = 0; k < NBR; ++k) {
                float r = R[bin * NBR + k];
                af += r * Wc[k * 64 + c];
                as += r * Wsc[k * 64 + c];
            }
            Tp[(size_t)l * TS + (size_t)gb * 64 + c] = bfr(af) | (bfr(as) << 16);
        }
    }
}

// h = x @ W_emb + b_emb via MFMA (bf16, K=128 padded)
__global__ __launch_bounds__(256) void k_embed_mfma(const float* __restrict__ x,
                                                    const unsigned int* __restrict__ BpE,
                                                    const float* __restrict__ be,
                                                    float* __restrict__ h) {
    __shared__ short A[64 * SPE];
    __shared__ short B[64 * SPE];
    int tid = threadIdx.x;
    int n0 = blockIdx.x * 64;
    for (int i = tid; i < 64 * 64; i += 256) {
        int r = i >> 6, kp = i & 63;
        int node = n0 + r;
        float2 v = make_float2(0.f, 0.f);
        if (node < N_NODES && kp < 46) v = ((const float2*)x)[(size_t)node * 46 + kp];
        *(unsigned int*)&A[r * SPE + kp * 2] = bfr(v.x) | (bfr(v.y) << 16);
    }
    {
        const uint4* src = (const uint4*)BpE;
        for (int i = tid; i < 64 * 16; i += 256) {
            int row = i >> 4, q = i & 15;
            *(uint4*)&B[row * SPE + q * 8] = src[i];
        }
    }
    __syncthreads();
    int lane = tid & 63, w = tid >> 6;
    int c15 = lane & 15, kb = lane >> 4;
    short8 af[4];
#pragma unroll
    for (int s = 0; s < 4; ++s)
        af[s] = *(const short8*)&A[(16 * w + c15) * SPE + s * 32 + kb * 8];
    f32x4 acc[4];
#pragma unroll
    for (int t = 0; t < 4; ++t) acc[t] = (f32x4){0.f, 0.f, 0.f, 0.f};
#pragma unroll
    for (int t = 0; t < 4; ++t) {
#pragma unroll
        for (int s = 0; s < 4; ++s) {
            short8 bf8 = *(const short8*)&B[(16 * t + c15) * SPE + s * 32 + kb * 8];
            acc[t] = __builtin_amdgcn_mfma_f32_16x16x32_bf16(af[s], bf8, acc[t], 0, 0, 0);
        }
    }
#pragma unroll
    for (int t = 0; t < 4; ++t) {
        float bias = be[16 * t + c15];
#pragma unroll
        for (int reg = 0; reg < 4; ++reg) {
            int node = n0 + 16 * w + kb * 4 + reg;
            if (node < N_NODES) h[(size_t)node * 64 + 16 * t + c15] = acc[t][reg] + bias;
        }
    }
}

// fused: (optional) BN+residual update of h, then MFMA projection -> Pi, Pj
__global__ __launch_bounds__(256) void k_nodeP_mfma(float* __restrict__ h,
                                                    const float* __restrict__ agg,
                                                    const float* __restrict__ ss,
                                                    const unsigned int* __restrict__ Bp,
                                                    int l, int upd,
                                                    unsigned int* __restrict__ Pi,
                                                    unsigned int* __restrict__ Pj) {
    __shared__ short A[64 * SP];
    __shared__ short B[256 * SP];
    int tid = threadIdx.x;
    int n0 = blockIdx.x * 64;
    for (int i = tid; i < 64 * 32; i += 256) {
        int r = i >> 5, kp = i & 31;
        int node = n0 + r;
        int gi = node * 32 + kp;
        float2 hv = make_float2(0.f, 0.f);
        if (node < N_NODES) {
            hv = ((const float2*)h)[gi];
            if (upd) {
                float2 av = ((const float2*)agg)[gi];
                int c = kp * 2;
                float x0 = ss[c] * av.x + ss[64 + c] + hv.x;
                float x1 = ss[c + 1] * av.y + ss[64 + c + 1] + hv.y;
                hv.x = softplus_f(x0);
                hv.y = softplus_f(x1);
                ((float2*)h)[gi] = hv;
            }
        }
        *(unsigned int*)&A[r * SP + kp * 2] = bfr(hv.x) | (bfr(hv.y) << 16);
    }
    {
        const uint4* src = (const uint4*)(Bp + (size_t)l * 8192);
        for (int i = tid; i < 2048; i += 256) {
            int row = i >> 3, j = i & 7;
            *(uint4*)&B[row * SP + j * 8] = src[row * 8 + j];
        }
    }
    __syncthreads();
    int lane = tid & 63, w = tid >> 6;
    int c15 = lane & 15, kb = lane >> 4;
    short8 af[2];
#pragma unroll
    for (int s = 0; s < 2; ++s)
        af[s] = *(const short8*)&A[(16 * w + c15) * SP + s * 32 + kb * 8];
    f32x4 acc[16];
#pragma unroll
    for (int t = 0; t < 16; ++t) acc[t] = (f32x4){0.f, 0.f, 0.f, 0.f};
#pragma unroll
    for (int t = 0; t < 16; ++t) {
#pragma unroll
        for (int s = 0; s < 2; ++s) {
            short8 bf8 = *(const short8*)&B[(16 * t + c15) * SP + s * 32 + kb * 8];
            acc[t] = __builtin_amdgcn_mfma_f32_16x16x32_bf16(af[s], bf8, acc[t], 0, 0, 0);
        }
    }
#pragma unroll
    for (int t = 0; t < 4; ++t) {
#pragma unroll
        for (int reg = 0; reg < 4; ++reg) {
            int row = kb * 4 + reg;
            int node = n0 + 16 * w + row;
            if (node < N_NODES) {
                Pi[(size_t)node * 64 + 16 * t + c15] =
                    bfr(acc[t][reg]) | (bfr(acc[t + 8][reg]) << 16);
                Pj[(size_t)node * 64 + 16 * t + c15] =
                    bfr(acc[t + 4][reg]) | (bfr(acc[t + 12][reg]) << 16);
            }
        }
    }
}

// one wave per node; scalar-pipe edge tiles (s_load_dwordx8), saddr gathers,
// exp2-domain gate/core math (producers pre-scaled by log2e)
__global__ __launch_bounds__(256) void k_edge_sorted(const int* __restrict__ offs,
                                                     const int* __restrict__ srcOff,
                                                     const int* __restrict__ tOff,
                                                     const unsigned int* __restrict__ Pi,
                                                     const unsigned int* __restrict__ Pj,
                                                     const unsigned int* __restrict__ Tp,
                                                     float* __restrict__ agg) {
    int wid = (blockIdx.x * 256 + threadIdx.x) >> 6;
    int lane = threadIdx.x & 63;
    if (wid >= N_NODES) return;
    int ko = __builtin_amdgcn_readfirstlane(offs[wid]);
    int ke = __builtin_amdgcn_readfirstlane(offs[wid + 1]);
    unsigned int pi = Pi[(size_t)wid * 64 + lane];
    float gi = bf_lo(pi), ci = bf_hi(pi);
    float acc = 0.0f;
    int lane4 = lane * 4;
    const char* PjB = (const char*)Pj;
    const char* TpB = (const char*)Tp;
    int k0 = ko;
    for (; k0 + 16 <= ke; k0 += 16) {
        int8v sv0, sv1, tv0, tv1;
        asm volatile(
            "s_load_dwordx8 %0, %4, 0x0\n\t"
            "s_load_dwordx8 %1, %4, 0x20\n\t"
            "s_load_dwordx8 %2, %5, 0x0\n\t"
            "s_load_dwordx8 %3, %5, 0x20\n\t"
            "s_waitcnt lgkmcnt(0)"
            : "=&s"(sv0), "=&s"(sv1), "=&s"(tv0), "=&s"(tv1)
            : "s"(srcOff + k0), "s"(tOff + k0));
        unsigned int pjv[16], tjv[16];
#pragma unroll
        for (int j = 0; j < 16; ++j) {
            int ps = (j < 8) ? sv0[j & 7] : sv1[j & 7];
            int ts = (j < 8) ? tv0[j & 7] : tv1[j & 7];
            pjv[j] = *(const unsigned int*)(PjB + ps + lane4);
            tjv[j] = *(const unsigned int*)(TpB + ts + lane4);
        }
#pragma unroll
        for (int j = 0; j < 16; ++j) {
            float g = gi + bf_lo(pjv[j]) + bf_lo(tjv[j]);
            float c = ci + bf_hi(pjv[j]) + bf_hi(tjv[j]);
            float sg = __builtin_amdgcn_rcpf(1.0f + __builtin_amdgcn_exp2f(-g));
            float sp = fmaxf(c, 0.0f) + __builtin_amdgcn_logf(1.0f + __builtin_amdgcn_exp2f(-fabsf(c)));
            acc = fmaf(sg * sp, LN2, acc);
        }
    }
    if (k0 < ke) {
        int8v sv0, sv1, tv0, tv1;
        asm volatile(
            "s_load_dwordx8 %0, %4, 0x0\n\t"
            "s_load_dwordx8 %1, %4, 0x20\n\t"
            "s_load_dwordx8 %2, %5, 0x0\n\t"
            "s_load_dwordx8 %3, %5, 0x20\n\t"
            "s_waitcnt lgkmcnt(0)"
            : "=&s"(sv0), "=&s"(sv1), "=&s"(tv0), "=&s"(tv1)
            : "s"(srcOff + k0), "s"(tOff + k0));
        unsigned int pjv[16], tjv[16];
#pragma unroll
        for (int j = 0; j < 16; ++j) {
            if (k0 + j < ke) {
                int ps = (j < 8) ? sv0[j & 7] : sv1[j & 7];
                int ts = (j < 8) ? tv0[j & 7] : tv1[j & 7];
                pjv[j] = *(const unsigned int*)(PjB + ps + lane4);
                tjv[j] = *(const unsigned int*)(TpB + ts + lane4);
            }
        }
#pragma unroll
        for (int j = 0; j < 16; ++j) {
            if (k0 + j < ke) {
                float g = gi + bf_lo(pjv[j]) + bf_lo(tjv[j]);
                float c = ci + bf_hi(pjv[j]) + bf_hi(tjv[j]);
                float sg = __builtin_amdgcn_rcpf(1.0f + __builtin_amdgcn_exp2f(-g));
                float sp = fmaxf(c, 0.0f) + __builtin_amdgcn_logf(1.0f + __builtin_amdgcn_exp2f(-fabsf(c)));
                acc = fmaf(sg * sp, LN2, acc);
            }
        }
    }
    agg[(size_t)wid * 64 + lane] = acc;
}

// fixed-grid partials, no atomics
__global__ __launch_bounds__(256) void k_bnstats(const float* __restrict__ agg,
                                                 float* __restrict__ partial) {
    __shared__ float ls[256], ls2[256];
    int c = threadIdx.x & 63, rg = threadIdx.x >> 6;
    float s = 0.0f, s2 = 0.0f;
    for (int n = blockIdx.x * 4 + rg; n < N_NODES; n += NPBLK * 4) {
        float v = agg[(size_t)n * ATOM + c];
        s += v; s2 += v * v;
    }
    ls[threadIdx.x] = s; ls2[threadIdx.x] = s2;
    __syncthreads();
    if (threadIdx.x < 64) {
        s = ls[c] + ls[64 + c] + ls[128 + c] + ls[192 + c];
        s2 = ls2[c] + ls2[64 + c] + ls2[128 + c] + ls2[192 + c];
        partial[blockIdx.x * 128 + c] = s;
        partial[blockIdx.x * 128 + 64 + c] = s2;
    }
}

__global__ __launch_bounds__(128) void k_bnfinal(const float* __restrict__ partial,
                                                 const float* __restrict__ gamma,
                                                 const float* __restrict__ beta,
                                                 int l, float* __restrict__ ss) {
    __shared__ float red[128];
    int t = threadIdx.x;
    float s = 0.0f;
    for (int b = 0; b < NPBLK; ++b) s += partial[b * 128 + t];
    red[t] = s;
    __syncthreads();
    if (t < 64) {
        const float inv = 1.0f / (float)N_NODES;
        float mu = red[t] * inv;
        float var = red[64 + t] * inv - mu * mu;
        float sc = gamma[l * ATOM + t] * rsqrtf(var + 1e-5f);
        ss[t] = sc;
        ss[64 + t] = beta[l * ATOM + t] - mu * sc;
    }
}

// fused final update + pool; batch is sorted -> run-length accumulate
__global__ __launch_bounds__(256) void k_pool2(const float* __restrict__ agg,
                                               const float* __restrict__ ss,
                                               const float* __restrict__ h,
                                               const int* __restrict__ batch,
                                               float* __restrict__ g) {
    int w = threadIdx.x >> 6, lane = threadIdx.x & 63;
    int nbase = blockIdx.x * 64 + w * 16;
    float acc = 0.0f;
    int curg = -1;
    float sc = ss[lane], sh = ss[64 + lane];
    for (int i = 0; i < 16; ++i) {
        int n = nbase + i;
        if (n >= N_NODES) break;
        int gid = __builtin_amdgcn_readfirstlane(batch[n]);
        if (gid != curg) {
            if (curg >= 0) atomicAdd(&g[(size_t)curg * ATOM + lane], acc);
            curg = gid;
            acc = 0.0f;
        }
        float x = sc * agg[(size_t)n * 64 + lane] + sh + h[(size_t)n * 64 + lane];
        acc += softplus_f(x);
    }
    if (curg >= 0) atomicAdd(&g[(size_t)curg * ATOM + lane], acc);
}

__global__ __launch_bounds__(128) void k_head(const float* __restrict__ g,
                                              const float* __restrict__ W1,
                                              const float* __restrict__ b1,
                                              const float* __restrict__ W2,
                                              const float* __restrict__ b2,
                                              float* __restrict__ out) {
    __shared__ float red[128];
    int gid = blockIdx.x, j = threadIdx.x;
    float acc = b1[j];
    for (int k = 0; k < ATOM; ++k) acc += g[gid * ATOM + k] * W1[k * HFEA + j];
    red[j] = softplus_f(acc) * W2[j];
    __syncthreads();
    for (int s = 64; s > 0; s >>= 1) {
        if (j < s) red[j] += red[j + s];
        __syncthreads();
    }
    if (j == 0) out[gid] = red[0] + b2[0];
}

extern "C" void kernel_launch(void* const* d_in, const int* in_sizes, int n_in,
                              void* d_out, int out_size, void* d_ws, size_t ws_size,
                              hipStream_t stream) {
    const float* x       = (const float*)d_in[0];
    const float* ea      = (const float*)d_in[1];
    const float* W_emb   = (const float*)d_in[2];
    const float* b_emb   = (const float*)d_in[3];
    const float* Wf      = (const float*)d_in[4];
    const float* bf      = (const float*)d_in[5];
    const float* Ws      = (const float*)d_in[6];
    const float* bs      = (const float*)d_in[7];
    const float* bn_g    = (const float*)d_in[8];
    const float* bn_b    = (const float*)d_in[9];
    const float* W1      = (const float*)d_in[10];
    const float* b1      = (const float*)d_in[11];
    const float* W2      = (const float*)d_in[12];
    const float* b2      = (const float*)d_in[13];
    const int*   ei      = (const int*)d_in[14];
    const int*   batch   = (const int*)d_in[15];
    float* out = (float*)d_out;

    char* wsb = (char*)d_ws;
    size_t off = 0;
    auto alloc = [&](size_t bytes) { char* p = wsb + off; off += (bytes + 255) & ~(size_t)255; return p; };
    float*        h      = (float*)alloc((size_t)N_NODES * 64 * 4);
    float*        agg    = (float*)alloc((size_t)N_NODES * 64 * 4);
    unsigned int* Pi     = (unsigned int*)alloc((size_t)N_NODES * 64 * 4);
    unsigned int* Pj     = (unsigned int*)alloc((size_t)N_NODES * 64 * 4);
    int*          srcOff = (int*)alloc((size_t)(N_EDGES + 16) * 4);
    int*          tOff   = (int*)alloc((size_t)(N_EDGES + 16) * 4);
    int*          cnt    = (int*)alloc((size_t)N_NODES * 4);
    int*          offs   = (int*)alloc((size_t)(N_NODES + 1) * 4);
    int*          cursor = (int*)alloc((size_t)N_NODES * 4);
    int*          bsum   = (int*)alloc((size_t)NTILE * 4);
    int*          bpre   = (int*)alloc((size_t)NTILE * 4);
    unsigned int* Tp     = (unsigned int*)alloc((size_t)NCONV * TS * 4);
    unsigned int* Bp     = (unsigned int*)alloc((size_t)NCONV * 8192 * 4);
    unsigned int* BpE    = (unsigned int*)alloc((size_t)64 * 64 * 4);
    float*        partial= (float*)alloc((size_t)NPBLK * 128 * 4);
    float*        ss     = (float*)alloc(128 * 4);
    float*        g      = (float*)alloc((size_t)NGRAPH * 64 * 4);

    hipMemsetAsync(cnt, 0, (size_t)N_NODES * 4, stream);
    hipMemsetAsync(srcOff + N_EDGES, 0, 64, stream);
    hipMemsetAsync(tOff + N_EDGES, 0, 64, stream);
    k_hist<<<(N_EDGES + 255) / 256, 256, 0, stream>>>(ei, cnt);
    k_tilesum<<<NTILE, SCAN_BS, 0, stream>>>(cnt, bsum);
    k_bscan<<<1, 512, 0, stream>>>(bsum, bpre, offs);
    k_tilescan<<<NTILE, SCAN_BS, 0, stream>>>(cnt, bpre, offs, cursor);
    k_scatter<<<(N_EDGES + 255) / 256, 256, 0, stream>>>(ei, ea, cursor, srcOff, tOff);

    k_prepW<<<NCONV, 256, 0, stream>>>(Wf, Ws, Bp);
    k_prepE<<<1, 256, 0, stream>>>(W_emb, BpE);
    dim3 tg((TBINS + 32) / 32, NCONV);
    k_table2<<<tg, 256, 0, stream>>>(Wf, bf, Ws, bs, Tp);
    k_embed_mfma<<<(N_NODES + 63) / 64, 256, 0, stream>>>(x, BpE, b_emb, h);

    for (int l = 0; l < NCONV; ++l) {
        k_nodeP_mfma<<<(N_NODES + 63) / 64, 256, 0, stream>>>(h, agg, ss, Bp, l, l > 0, Pi, Pj);
        k_edge_sorted<<<(N_NODES * 64 + 255) / 256, 256, 0, stream>>>(
            offs, srcOff, tOff, Pi, Pj, Tp + (size_t)l * TS, agg);
        k_bnstats<<<NPBLK, 256, 0, stream>>>(agg, partial);
        k_bnfinal<<<1, 128, 0, stream>>>(partial, bn_g, bn_b, l, ss);
    }

    hipMemsetAsync(g, 0, (size_t)NGRAPH * 64 * 4, stream);
    k_pool2<<<(N_NODES + 63) / 64, 256, 0, stream>>>(agg, ss, h, batch, g);
    k_head<<<NGRAPH, 128, 0, stream>>>(g, W1, b1, W2, b2, out);
}

// Round 10
// 730.052 us; speedup vs baseline: 2.8427x; 1.0130x over previous
//
#include <hip/hip_runtime.h>
#include <hip/hip_bf16.h>
#include <math.h>

#define N_NODES 100000
#define N_EDGES 1600000
#define ORIG    92
#define NBR     41
#define ATOM    64
#define NCONV   3
#define HFEA    128
#define NGRAPH  256
#define ZD      169           // 2*ATOM + NBR
#define TBINS   5120
#define TMAX    10.0f
#define TS      ((TBINS + 1) * 64)   // per-layer table stride (uints)
#define SCAN_BS 256
#define NTILE   ((N_NODES + SCAN_BS - 1) / SCAN_BS)
#define SP      72                   // nodeP LDS row pad (shorts)
#define SPE     136                  // embed LDS row pad (shorts), K=128
#define NPBLK   128                  // bnstats partial blocks
#define LOG2E   1.4426950408889634f
#define LN2     0.6931471805599453f

typedef __attribute__((ext_vector_type(8))) short short8;
typedef __attribute__((ext_vector_type(4))) float f32x4;
typedef __attribute__((ext_vector_type(8))) int int8v;

__device__ __forceinline__ float softplus_f(float x) {
    return fmaxf(x, 0.0f) + log1pf(expf(-fabsf(x)));
}
// round fp32 -> bf16 bits (RNE)
__device__ __forceinline__ unsigned int bfr(float x) {
    unsigned int u = __float_as_uint(x);
    return (u + 0x7fffu + ((u >> 16) & 1u)) >> 16;
}
__device__ __forceinline__ float bf_lo(unsigned int p) { return __uint_as_float(p << 16); }
__device__ __forceinline__ float bf_hi(unsigned int p) { return __uint_as_float(p & 0xffff0000u); }

// ---------- one-shot preprocessing ----------

__global__ __launch_bounds__(256) void k_hist(const int* __restrict__ ei,
                                              int* __restrict__ cnt) {
    int e = blockIdx.x * 256 + threadIdx.x;
    if (e < N_EDGES) atomicAdd(&cnt[ei[N_EDGES + e]], 1);
}

__global__ __launch_bounds__(SCAN_BS) void k_tilesum(const int* __restrict__ cnt,
                                                     int* __restrict__ bsum) {
    __shared__ int s[SCAN_BS];
    int i = blockIdx.x * SCAN_BS + threadIdx.x;
    s[threadIdx.x] = (i < N_NODES) ? cnt[i] : 0;
    __syncthreads();
    for (int d = SCAN_BS / 2; d > 0; d >>= 1) {
        if (threadIdx.x < d) s[threadIdx.x] += s[threadIdx.x + d];
        __syncthreads();
    }
    if (threadIdx.x == 0) bsum[blockIdx.x] = s[0];
}

__global__ __launch_bounds__(512) void k_bscan(const int* __restrict__ bsum,
                                               int* __restrict__ bpre,
                                               int* __restrict__ offs) {
    __shared__ int s[512];
    int t = threadIdx.x;
    int v = (t < NTILE) ? bsum[t] : 0;
    s[t] = v;
    __syncthreads();
    for (int d = 1; d < 512; d <<= 1) {
        int u = (t >= d) ? s[t - d] : 0;
        __syncthreads();
        s[t] += u;
        __syncthreads();
    }
    if (t < NTILE) bpre[t] = s[t] - v;
    if (t == 511) offs[N_NODES] = s[511];
}

__global__ __launch_bounds__(SCAN_BS) void k_tilescan(const int* __restrict__ cnt,
                                                      const int* __restrict__ bpre,
                                                      int* __restrict__ offs,
                                                      int* __restrict__ cursor) {
    __shared__ int s[SCAN_BS];
    int i = blockIdx.x * SCAN_BS + threadIdx.x;
    int v = (i < N_NODES) ? cnt[i] : 0;
    s[threadIdx.x] = v;
    __syncthreads();
    for (int d = 1; d < SCAN_BS; d <<= 1) {
        int u = (threadIdx.x >= d) ? s[threadIdx.x - d] : 0;
        __syncthreads();
        s[threadIdx.x] += u;
        __syncthreads();
    }
    if (i < N_NODES) {
        int ex = bpre[blockIdx.x] + s[threadIdx.x] - v;
        offs[i] = ex;
        cursor[i] = ex;
    }
}

// scatter packed descriptor (bin<<17)|src per edge, sorted by dst
__global__ __launch_bounds__(256) void k_scatter(const int* __restrict__ ei,
                                                 const float* __restrict__ ea,
                                                 int* __restrict__ cursor,
                                                 int* __restrict__ edesc) {
    int e = blockIdx.x * 256 + threadIdx.x;
    if (e >= N_EDGES) return;
    float a = ea[3 * e], b = ea[3 * e + 1], c = ea[3 * e + 2];
    float d = sqrtf(a * a + b * b + c * c);
    int bin = (int)fminf(fmaf(d, (float)TBINS / TMAX, 0.5f), (float)TBINS);
    int dst = ei[N_EDGES + e];
    int pos = atomicAdd(&cursor[dst], 1);
    edesc[pos] = (bin << 17) | ei[e];
}

// blocks 0..2: node-part weights -> bf16 scaled by log2e; block 3: embed weights
__global__ __launch_bounds__(256) void k_prep(const float* __restrict__ Wf,
                                              const float* __restrict__ Ws,
                                              const float* __restrict__ We,
                                              unsigned int* __restrict__ Bp,
                                              unsigned int* __restrict__ BpE) {
    int tid = threadIdx.x;
    if (blockIdx.x < NCONV) {
        int l = blockIdx.x;
        int m = tid >> 6, c = tid & 63;
        const float* Wb = ((m & 2) ? Ws : Wf) + (size_t)l * ZD * ATOM + (m & 1) * ATOM * ATOM + c;
        unsigned int* dst = Bp + (size_t)l * 8192 + (size_t)tid * 32;
        for (int kp = 0; kp < 32; ++kp) {
            float w0 = Wb[(2 * kp) * ATOM] * LOG2E;
            float w1 = Wb[(2 * kp + 1) * ATOM] * LOG2E;
            dst[kp] = bfr(w0) | (bfr(w1) << 16);
        }
    } else {
        int n = tid & 63, q = tid >> 6;
        for (int kp = q * 16; kp < q * 16 + 16; ++kp) {
            int k0 = 2 * kp, k1 = 2 * kp + 1;
            float w0 = (k0 < ORIG) ? We[k0 * ATOM + n] : 0.f;
            float w1 = (k1 < ORIG) ? We[k1 * ATOM + n] : 0.f;
            BpE[(size_t)n * 64 + kp] = bfr(w0) | (bfr(w1) << 16);
        }
    }
}

// T = R(d) @ W_e + bias, all pre-scaled by log2e
__global__ __launch_bounds__(256) void k_table2(const float* __restrict__ Wf,
                                                const float* __restrict__ bf,
                                                const float* __restrict__ Ws,
                                                const float* __restrict__ bs,
                                                unsigned int* __restrict__ Tp) {
    __shared__ float Wc[NBR * 64], Wsc[NBR * 64], R[32 * NBR];
    int tid = threadIdx.x;
    int l = blockIdx.y;
    int b0 = blockIdx.x * 32;
    const float* srcf = Wf + (size_t)l * ZD * ATOM + 2 * ATOM * ATOM;
    const float* srcs = Ws + (size_t)l * ZD * ATOM + 2 * ATOM * ATOM;
    for (int i = tid; i < NBR * 64; i += 256) {
        Wc[i] = srcf[i] * LOG2E;
        Wsc[i] = srcs[i] * LOG2E;
    }
    for (int i = tid; i < 32 * NBR; i += 256) {
        int bin = i / NBR, k = i - bin * NBR;
        float d = (b0 + bin) * (TMAX / TBINS);
        float diff = d - 0.2f * k;
        R[i] = expf(-5.0f * diff * diff);
    }
    __syncthreads();
    int c = tid & 63;
    float afb = bf[l * ATOM + c] * LOG2E, asb = bs[l * ATOM + c] * LOG2E;
#pragma unroll
    for (int it = 0; it < 8; ++it) {
        int bin = (tid >> 6) + 4 * it;
        int gb = b0 + bin;
        if (gb <= TBINS) {
            float af = afb, as = asb;
            for (int k = 0; k < NBR; ++k) {
                float r = R[bin * NBR + k];
                af += r * Wc[k * 64 + c];
                as += r * Wsc[k * 64 + c];
            }
            Tp[(size_t)l * TS + (size_t)gb * 64 + c] = bfr(af) | (bfr(as) << 16);
        }
    }
}

// h = x @ W_emb + b_emb via MFMA (bf16, K=128 padded)
__global__ __launch_bounds__(256) void k_embed_mfma(const float* __restrict__ x,
                                                    const unsigned int* __restrict__ BpE,
                                                    const float* __restrict__ be,
                                                    float* __restrict__ h) {
    __shared__ short A[64 * SPE];
    __shared__ short B[64 * SPE];
    int tid = threadIdx.x;
    int n0 = blockIdx.x * 64;
    for (int i = tid; i < 64 * 64; i += 256) {
        int r = i >> 6, kp = i & 63;
        int node = n0 + r;
        float2 v = make_float2(0.f, 0.f);
        if (node < N_NODES && kp < 46) v = ((const float2*)x)[(size_t)node * 46 + kp];
        *(unsigned int*)&A[r * SPE + kp * 2] = bfr(v.x) | (bfr(v.y) << 16);
    }
    {
        const uint4* src = (const uint4*)BpE;
        for (int i = tid; i < 64 * 16; i += 256) {
            int row = i >> 4, q = i & 15;
            *(uint4*)&B[row * SPE + q * 8] = src[i];
        }
    }
    __syncthreads();
    int lane = tid & 63, w = tid >> 6;
    int c15 = lane & 15, kb = lane >> 4;
    short8 af[4];
#pragma unroll
    for (int s = 0; s < 4; ++s)
        af[s] = *(const short8*)&A[(16 * w + c15) * SPE + s * 32 + kb * 8];
    f32x4 acc[4];
#pragma unroll
    for (int t = 0; t < 4; ++t) acc[t] = (f32x4){0.f, 0.f, 0.f, 0.f};
#pragma unroll
    for (int t = 0; t < 4; ++t) {
#pragma unroll
        for (int s = 0; s < 4; ++s) {
            short8 bf8 = *(const short8*)&B[(16 * t + c15) * SPE + s * 32 + kb * 8];
            acc[t] = __builtin_amdgcn_mfma_f32_16x16x32_bf16(af[s], bf8, acc[t], 0, 0, 0);
        }
    }
#pragma unroll
    for (int t = 0; t < 4; ++t) {
        float bias = be[16 * t + c15];
#pragma unroll
        for (int reg = 0; reg < 4; ++reg) {
            int node = n0 + 16 * w + kb * 4 + reg;
            if (node < N_NODES) h[(size_t)node * 64 + 16 * t + c15] = acc[t][reg] + bias;
        }
    }
}

// fused: (optional) BN+residual update of h, then MFMA projection -> Pi, Pj
__global__ __launch_bounds__(256) void k_nodeP_mfma(float* __restrict__ h,
                                                    const float* __restrict__ agg,
                                                    const float* __restrict__ ss,
                                                    const unsigned int* __restrict__ Bp,
                                                    int l, int upd,
                                                    unsigned int* __restrict__ Pi,
                                                    unsigned int* __restrict__ Pj) {
    __shared__ short A[64 * SP];
    __shared__ short B[256 * SP];
    int tid = threadIdx.x;
    int n0 = blockIdx.x * 64;
    for (int i = tid; i < 64 * 32; i += 256) {
        int r = i >> 5, kp = i & 31;
        int node = n0 + r;
        int gi = node * 32 + kp;
        float2 hv = make_float2(0.f, 0.f);
        if (node < N_NODES) {
            hv = ((const float2*)h)[gi];
            if (upd) {
                float2 av = ((const float2*)agg)[gi];
                int c = kp * 2;
                float x0 = ss[c] * av.x + ss[64 + c] + hv.x;
                float x1 = ss[c + 1] * av.y + ss[64 + c + 1] + hv.y;
                hv.x = softplus_f(x0);
                hv.y = softplus_f(x1);
                ((float2*)h)[gi] = hv;
            }
        }
        *(unsigned int*)&A[r * SP + kp * 2] = bfr(hv.x) | (bfr(hv.y) << 16);
    }
    {
        const uint4* src = (const uint4*)(Bp + (size_t)l * 8192);
        for (int i = tid; i < 2048; i += 256) {
            int row = i >> 3, j = i & 7;
            *(uint4*)&B[row * SP + j * 8] = src[row * 8 + j];
        }
    }
    __syncthreads();
    int lane = tid & 63, w = tid >> 6;
    int c15 = lane & 15, kb = lane >> 4;
    short8 af[2];
#pragma unroll
    for (int s = 0; s < 2; ++s)
        af[s] = *(const short8*)&A[(16 * w + c15) * SP + s * 32 + kb * 8];
    f32x4 acc[16];
#pragma unroll
    for (int t = 0; t < 16; ++t) acc[t] = (f32x4){0.f, 0.f, 0.f, 0.f};
#pragma unroll
    for (int t = 0; t < 16; ++t) {
#pragma unroll
        for (int s = 0; s < 2; ++s) {
            short8 bf8 = *(const short8*)&B[(16 * t + c15) * SP + s * 32 + kb * 8];
            acc[t] = __builtin_amdgcn_mfma_f32_16x16x32_bf16(af[s], bf8, acc[t], 0, 0, 0);
        }
    }
#pragma unroll
    for (int t = 0; t < 4; ++t) {
#pragma unroll
        for (int reg = 0; reg < 4; ++reg) {
            int row = kb * 4 + reg;
            int node = n0 + 16 * w + row;
            if (node < N_NODES) {
                Pi[(size_t)node * 64 + 16 * t + c15] =
                    bfr(acc[t][reg]) | (bfr(acc[t + 8][reg]) << 16);
                Pj[(size_t)node * 64 + 16 * t + c15] =
                    bfr(acc[t + 4][reg]) | (bfr(acc[t + 12][reg]) << 16);
            }
        }
    }
}

// one wave per node; packed scalar descriptors, saddr gathers, exp2-domain math
__global__ __launch_bounds__(256) void k_edge_sorted(const int* __restrict__ offs,
                                                     const int* __restrict__ edesc,
                                                     const unsigned int* __restrict__ Pi,
                                                     const unsigned int* __restrict__ Pj,
                                                     const unsigned int* __restrict__ Tp,
                                                     float* __restrict__ agg) {
    int wid = (blockIdx.x * 256 + threadIdx.x) >> 6;
    int lane = threadIdx.x & 63;
    if (wid >= N_NODES) return;
    int uwid = __builtin_amdgcn_readfirstlane(wid);
    int2 kk;
    asm volatile("s_load_dwordx2 %0, %1, 0x0\n\ts_waitcnt lgkmcnt(0)"
                 : "=s"(kk) : "s"(offs + uwid));
    int ko = kk.x, ke = kk.y;
    unsigned int pi = Pi[(size_t)uwid * 64 + lane];
    float gi = bf_lo(pi), ci = bf_hi(pi);
    float acc = 0.0f;
    int lane4 = lane * 4;
    const char* PjB = (const char*)Pj;
    const char* TpB = (const char*)Tp;
    int k0 = ko;
    for (; k0 + 16 <= ke; k0 += 16) {
        int8v e0, e1;
        asm volatile(
            "s_load_dwordx8 %0, %2, 0x0\n\t"
            "s_load_dwordx8 %1, %2, 0x20\n\t"
            "s_waitcnt lgkmcnt(0)"
            : "=&s"(e0), "=&s"(e1)
            : "s"(edesc + k0));
        unsigned int pjv[16], tjv[16];
#pragma unroll
        for (int j = 0; j < 16; ++j) {
            int v = (j < 8) ? e0[j & 7] : e1[j & 7];
            int sb = (v & 0x1FFFF) << 8;
            int tb = (v >> 17) << 8;
            pjv[j] = *(const unsigned int*)(PjB + sb + lane4);
            tjv[j] = *(const unsigned int*)(TpB + tb + lane4);
        }
#pragma unroll
        for (int j = 0; j < 16; ++j) {
            float g = gi + bf_lo(pjv[j]) + bf_lo(tjv[j]);
            float c = ci + bf_hi(pjv[j]) + bf_hi(tjv[j]);
            float sg = __builtin_amdgcn_rcpf(1.0f + __builtin_amdgcn_exp2f(-g));
            float sp = fmaxf(c, 0.0f) + __builtin_amdgcn_logf(1.0f + __builtin_amdgcn_exp2f(-fabsf(c)));
            acc = fmaf(sg * sp, LN2, acc);
        }
    }
    if (k0 < ke) {
        int8v e0, e1;
        asm volatile(
            "s_load_dwordx8 %0, %2, 0x0\n\t"
            "s_load_dwordx8 %1, %2, 0x20\n\t"
            "s_waitcnt lgkmcnt(0)"
            : "=&s"(e0), "=&s"(e1)
            : "s"(edesc + k0));
        unsigned int pjv[16], tjv[16];
#pragma unroll
        for (int j = 0; j < 16; ++j) {
            if (k0 + j < ke) {
                int v = (j < 8) ? e0[j & 7] : e1[j & 7];
                int sb = (v & 0x1FFFF) << 8;
                int tb = (v >> 17) << 8;
                pjv[j] = *(const unsigned int*)(PjB + sb + lane4);
                tjv[j] = *(const unsigned int*)(TpB + tb + lane4);
            }
        }
#pragma unroll
        for (int j = 0; j < 16; ++j) {
            if (k0 + j < ke) {
                float g = gi + bf_lo(pjv[j]) + bf_lo(tjv[j]);
                float c = ci + bf_hi(pjv[j]) + bf_hi(tjv[j]);
                float sg = __builtin_amdgcn_rcpf(1.0f + __builtin_amdgcn_exp2f(-g));
                float sp = fmaxf(c, 0.0f) + __builtin_amdgcn_logf(1.0f + __builtin_amdgcn_exp2f(-fabsf(c)));
                acc = fmaf(sg * sp, LN2, acc);
            }
        }
    }
    agg[(size_t)uwid * 64 + lane] = acc;
}

// bnstats + bnfinal merged via last-block pattern
__global__ __launch_bounds__(256) void k_bnstats2(const float* __restrict__ agg,
                                                  float* __restrict__ partial,
                                                  int* __restrict__ lcnt,
                                                  const float* __restrict__ gamma,
                                                  const float* __restrict__ beta,
                                                  int l, float* __restrict__ ss) {
    __shared__ float ls[256], ls2[256];
    __shared__ int lastFlag;
    int c = threadIdx.x & 63, rg = threadIdx.x >> 6;
    float s = 0.0f, s2 = 0.0f;
    for (int n = blockIdx.x * 4 + rg; n < N_NODES; n += NPBLK * 4) {
        float v = agg[(size_t)n * ATOM + c];
        s += v; s2 += v * v;
    }
    ls[threadIdx.x] = s; ls2[threadIdx.x] = s2;
    __syncthreads();
    if (threadIdx.x < 64) {
        s = ls[c] + ls[64 + c] + ls[128 + c] + ls[192 + c];
        s2 = ls2[c] + ls2[64 + c] + ls2[128 + c] + ls2[192 + c];
        partial[blockIdx.x * 128 + c] = s;
        partial[blockIdx.x * 128 + 64 + c] = s2;
    }
    __syncthreads();
    if (threadIdx.x == 0) {
        __threadfence();
        lastFlag = (atomicAdd(lcnt, 1) == NPBLK - 1) ? 1 : 0;
    }
    __syncthreads();
    if (lastFlag) {
        __threadfence();
        int t = threadIdx.x;
        if (t < 128) {
            float sum = 0.0f;
            for (int b = 0; b < NPBLK; ++b) sum += partial[b * 128 + t];
            ls[t] = sum;
        }
        __syncthreads();
        if (t < 64) {
            const float inv = 1.0f / (float)N_NODES;
            float mu = ls[t] * inv;
            float var = ls[64 + t] * inv - mu * mu;
            float sc = gamma[l * ATOM + t] * rsqrtf(var + 1e-5f);
            ss[t] = sc;
            ss[64 + t] = beta[l * ATOM + t] - mu * sc;
        }
    }
}

// fused final update + pool; batch is sorted -> run-length accumulate
__global__ __launch_bounds__(256) void k_pool2(const float* __restrict__ agg,
                                               const float* __restrict__ ss,
                                               const float* __restrict__ h,
                                               const int* __restrict__ batch,
                                               float* __restrict__ g) {
    int w = threadIdx.x >> 6, lane = threadIdx.x & 63;
    int nbase = blockIdx.x * 64 + w * 16;
    float acc = 0.0f;
    int curg = -1;
    float sc = ss[lane], sh = ss[64 + lane];
    for (int i = 0; i < 16; ++i) {
        int n = nbase + i;
        if (n >= N_NODES) break;
        int gid = __builtin_amdgcn_readfirstlane(batch[n]);
        if (gid != curg) {
            if (curg >= 0) atomicAdd(&g[(size_t)curg * ATOM + lane], acc);
            curg = gid;
            acc = 0.0f;
        }
        float x = sc * agg[(size_t)n * 64 + lane] + sh + h[(size_t)n * 64 + lane];
        acc += softplus_f(x);
    }
    if (curg >= 0) atomicAdd(&g[(size_t)curg * ATOM + lane], acc);
}

__global__ __launch_bounds__(128) void k_head(const float* __restrict__ g,
                                              const float* __restrict__ W1,
                                              const float* __restrict__ b1,
                                              const float* __restrict__ W2,
                                              const float* __restrict__ b2,
                                              float* __restrict__ out) {
    __shared__ float red[128];
    int gid = blockIdx.x, j = threadIdx.x;
    float acc = b1[j];
    for (int k = 0; k < ATOM; ++k) acc += g[gid * ATOM + k] * W1[k * HFEA + j];
    red[j] = softplus_f(acc) * W2[j];
    __syncthreads();
    for (int s = 64; s > 0; s >>= 1) {
        if (j < s) red[j] += red[j + s];
        __syncthreads();
    }
    if (j == 0) out[gid] = red[0] + b2[0];
}

extern "C" void kernel_launch(void* const* d_in, const int* in_sizes, int n_in,
                              void* d_out, int out_size, void* d_ws, size_t ws_size,
                              hipStream_t stream) {
    const float* x       = (const float*)d_in[0];
    const float* ea      = (const float*)d_in[1];
    const float* W_emb   = (const float*)d_in[2];
    const float* b_emb   = (const float*)d_in[3];
    const float* Wf      = (const float*)d_in[4];
    const float* bf      = (const float*)d_in[5];
    const float* Ws      = (const float*)d_in[6];
    const float* bs      = (const float*)d_in[7];
    const float* bn_g    = (const float*)d_in[8];
    const float* bn_b    = (const float*)d_in[9];
    const float* W1      = (const float*)d_in[10];
    const float* b1      = (const float*)d_in[11];
    const float* W2      = (const float*)d_in[12];
    const float* b2      = (const float*)d_in[13];
    const int*   ei      = (const int*)d_in[14];
    const int*   batch   = (const int*)d_in[15];
    float* out = (float*)d_out;

    char* wsb = (char*)d_ws;
    size_t off = 0;
    auto alloc = [&](size_t bytes) { char* p = wsb + off; off += (bytes + 255) & ~(size_t)255; return p; };
    float*        h      = (float*)alloc((size_t)N_NODES * 64 * 4);
    float*        agg    = (float*)alloc((size_t)N_NODES * 64 * 4);
    unsigned int* Pi     = (unsigned int*)alloc((size_t)N_NODES * 64 * 4);
    unsigned int* Pj     = (unsigned int*)alloc((size_t)N_NODES * 64 * 4);
    int*          edesc  = (int*)alloc((size_t)(N_EDGES + 16) * 4);
    int*          cnt    = (int*)alloc((size_t)N_NODES * 4 + 256);  // tail: lcnt[3]
    int*          lcnt   = cnt + N_NODES;
    int*          offs   = (int*)alloc((size_t)(N_NODES + 1) * 4);
    int*          cursor = (int*)alloc((size_t)N_NODES * 4);
    int*          bsum   = (int*)alloc((size_t)NTILE * 4);
    int*          bpre   = (int*)alloc((size_t)NTILE * 4);
    unsigned int* Tp     = (unsigned int*)alloc((size_t)NCONV * TS * 4);
    unsigned int* Bp     = (unsigned int*)alloc((size_t)NCONV * 8192 * 4);
    unsigned int* BpE    = (unsigned int*)alloc((size_t)64 * 64 * 4);
    float*        partial= (float*)alloc((size_t)NPBLK * 128 * 4);
    float*        ss     = (float*)alloc(128 * 4);
    float*        g      = (float*)alloc((size_t)NGRAPH * 64 * 4);

    (void)hipMemsetAsync(cnt, 0, (size_t)N_NODES * 4 + 256, stream);
    k_hist<<<(N_EDGES + 255) / 256, 256, 0, stream>>>(ei, cnt);
    k_tilesum<<<NTILE, SCAN_BS, 0, stream>>>(cnt, bsum);
    k_bscan<<<1, 512, 0, stream>>>(bsum, bpre, offs);
    k_tilescan<<<NTILE, SCAN_BS, 0, stream>>>(cnt, bpre, offs, cursor);
    k_scatter<<<(N_EDGES + 255) / 256, 256, 0, stream>>>(ei, ea, cursor, edesc);

    k_prep<<<NCONV + 1, 256, 0, stream>>>(Wf, Ws, W_emb, Bp, BpE);
    dim3 tg((TBINS + 32) / 32, NCONV);
    k_table2<<<tg, 256, 0, stream>>>(Wf, bf, Ws, bs, Tp);
    k_embed_mfma<<<(N_NODES + 63) / 64, 256, 0, stream>>>(x, BpE, b_emb, h);

    for (int l = 0; l < NCONV; ++l) {
        k_nodeP_mfma<<<(N_NODES + 63) / 64, 256, 0, stream>>>(h, agg, ss, Bp, l, l > 0, Pi, Pj);
        k_edge_sorted<<<(N_NODES * 64 + 255) / 256, 256, 0, stream>>>(
            offs, edesc, Pi, Pj, Tp + (size_t)l * TS, agg);
        k_bnstats2<<<NPBLK, 256, 0, stream>>>(agg, partial, lcnt + l, bn_g, bn_b, l, ss);
    }

    (void)hipMemsetAsync(g, 0, (size_t)NGRAPH * 64 * 4, stream);
    k_pool2<<<(N_NODES + 63) / 64, 256, 0, stream>>>(agg, ss, h, batch, g);
    k_head<<<NGRAPH, 128, 0, stream>>>(g, W1, b1, W2, b2, out);
}

// Round 11
// 601.516 us; speedup vs baseline: 3.4502x; 1.2137x over previous
//
#include <hip/hip_runtime.h>
#include <hip/hip_bf16.h>
#include <math.h>

#define N_NODES 100000
#define N_EDGES 1600000
#define ORIG    92
#define NBR     41
#define ATOM    64
#define NCONV   3
#define HFEA    128
#define NGRAPH  256
#define ZD      169           // 2*ATOM + NBR
#define TBINS   5120
#define TMAX    10.0f
#define TS      ((TBINS + 1) * 64)   // per-layer table stride (uints)
#define SP      72                   // nodeP LDS row pad (shorts)
#define SPE     136                  // embed LDS row pad (shorts), K=128
#define NPBLK   128                  // bnstats partial blocks
#define LOG2E   1.4426950408889634f
#define LN2     0.6931471805599453f
#define NBKT    391                  // ceil(N_NODES / 256)
#define S1E     6250                 // edges per k_bhist block (256 blocks exact)
#define S3CH    4096                 // edges per k_psort1 block

typedef __attribute__((ext_vector_type(8))) short short8;
typedef __attribute__((ext_vector_type(4))) float f32x4;
typedef __attribute__((ext_vector_type(8))) int int8v;

__device__ __forceinline__ float softplus_f(float x) {
    return fmaxf(x, 0.0f) + log1pf(expf(-fabsf(x)));
}
// round fp32 -> bf16 bits (RNE)
__device__ __forceinline__ unsigned int bfr(float x) {
    unsigned int u = __float_as_uint(x);
    return (u + 0x7fffu + ((u >> 16) & 1u)) >> 16;
}
__device__ __forceinline__ float bf_lo(unsigned int p) { return __uint_as_float(p << 16); }
__device__ __forceinline__ float bf_hi(unsigned int p) { return __uint_as_float(p & 0xffff0000u); }

// ---------- sort pass 0: coarse bucket histogram (LDS-staged) ----------
__global__ __launch_bounds__(256) void k_bhist(const int* __restrict__ ei,
                                               int* __restrict__ bucketCnt) {
    __shared__ int cntL[NBKT];
    int tid = threadIdx.x;
    for (int i = tid; i < NBKT; i += 256) cntL[i] = 0;
    __syncthreads();
    int base = blockIdx.x * S1E;
    for (int i = tid; i < S1E; i += 256)
        atomicAdd(&cntL[ei[N_EDGES + base + i] >> 8], 1);
    __syncthreads();
    for (int i = tid; i < NBKT; i += 256)
        if (cntL[i]) atomicAdd(&bucketCnt[i], cntL[i]);
}

// ---------- sort pass 0b: scan 391 bucket counts (1 wave) ----------
__global__ __launch_bounds__(64) void k_bscan2(const int* __restrict__ bucketCnt,
                                               int* __restrict__ bucketBase,
                                               int* __restrict__ bucketCursor,
                                               int* __restrict__ offs) {
    int tid = threadIdx.x;
    int carry = 0;
    for (int b0 = 0; b0 < NBKT; b0 += 64) {
        int idx = b0 + tid;
        int v0 = (idx < NBKT) ? bucketCnt[idx] : 0;
        int v = v0;
        for (int d = 1; d < 64; d <<= 1) {
            int u = __shfl_up(v, d, 64);
            if (tid >= d) v += u;
        }
        if (idx < NBKT) {
            int ex = carry + v - v0;
            bucketBase[idx] = ex;
            bucketCursor[idx] = ex;
        }
        carry += __shfl(v, 63, 64);
    }
    if (tid == 0) {
        bucketBase[NBKT] = N_EDGES;
        offs[N_NODES] = N_EDGES;
    }
}

// ---------- sort pass 1: bucket-binned staging, coalesced burst writes ----------
__global__ __launch_bounds__(256) void k_psort1(const int* __restrict__ ei,
                                                const float* __restrict__ ea,
                                                int* __restrict__ bucketCursor,
                                                int2* __restrict__ staging) {
    __shared__ int cntL[NBKT], scanB[NBKT], curL[NBKT], gbaseL[NBKT];
    __shared__ int sortedD[S3CH], sortedN[S3CH];
    int tid = threadIdx.x;
    int base = blockIdx.x * S3CH;
    int myCount = N_EDGES - base;
    if (myCount > S3CH) myCount = S3CH;
    for (int i = tid; i < NBKT; i += 256) { cntL[i] = 0; curL[i] = 0; }
    __syncthreads();
    int descr[16], dstr[16];
#pragma unroll
    for (int j = 0; j < 16; ++j) {
        int i = j * 256 + tid;
        descr[j] = 0; dstr[j] = -1;
        if (i < myCount) {
            int e = base + i;
            int src = ei[e];
            int dst = ei[N_EDGES + e];
            float a = ea[3 * e], bb = ea[3 * e + 1], c = ea[3 * e + 2];
            float d = sqrtf(a * a + bb * bb + c * c);
            int bin = (int)fminf(fmaf(d, (float)TBINS / TMAX, 0.5f), (float)TBINS);
            descr[j] = (bin << 17) | src;
            dstr[j] = dst;
            atomicAdd(&cntL[dst >> 8], 1);
        }
    }
    __syncthreads();
    if (tid < 64) {  // wave 0 exclusive-scans cntL
        int carry = 0;
        for (int b0 = 0; b0 < NBKT; b0 += 64) {
            int idx = b0 + tid;
            int v0 = (idx < NBKT) ? cntL[idx] : 0;
            int v = v0;
            for (int d = 1; d < 64; d <<= 1) {
                int u = __shfl_up(v, d, 64);
                if (tid >= d) v += u;
            }
            if (idx < NBKT) scanB[idx] = carry + v - v0;
            carry += __shfl(v, 63, 64);
        }
    }
    __syncthreads();
#pragma unroll
    for (int j = 0; j < 16; ++j) {
        if (dstr[j] >= 0) {
            int b = dstr[j] >> 8;
            int pos = scanB[b] + atomicAdd(&curL[b], 1);
            sortedD[pos] = descr[j];
            sortedN[pos] = dstr[j];
        }
    }
    for (int i = tid; i < NBKT; i += 256)
        if (cntL[i] > 0) gbaseL[i] = atomicAdd(&bucketCursor[i], cntL[i]);
    __syncthreads();
    for (int i = tid; i < myCount; i += 256) {
        int n = sortedN[i];
        int b = n >> 8;
        int2 pr; pr.x = sortedD[i]; pr.y = n;
        staging[gbaseL[b] + (i - scanB[b])] = pr;
    }
}

// ---------- sort pass 2: per-bucket exact sort + offs ----------
__global__ __launch_bounds__(256) void k_psort2(const int* __restrict__ bucketBase,
                                                const int2* __restrict__ staging,
                                                int* __restrict__ edesc,
                                                int* __restrict__ offs) {
    __shared__ int cnt[256], sbase[256], cur[256];
    int b = blockIdx.x, tid = threadIdx.x;
    int base = bucketBase[b];
    int nb = bucketBase[b + 1] - base;
    cnt[tid] = 0; cur[tid] = 0;
    __syncthreads();
    for (int i = tid; i < nb; i += 256)
        atomicAdd(&cnt[staging[base + i].y & 255], 1);
    __syncthreads();
    int v = cnt[tid];
    sbase[tid] = v;
    __syncthreads();
    for (int d = 1; d < 256; d <<= 1) {
        int u = (tid >= d) ? sbase[tid - d] : 0;
        __syncthreads();
        sbase[tid] += u;
        __syncthreads();
    }
    int ex = sbase[tid] - v;
    int dst = (b << 8) + tid;
    if (dst < N_NODES) offs[dst] = base + ex;
    sbase[tid] = ex;
    __syncthreads();
    for (int i = tid; i < nb; i += 256) {
        int2 pr = staging[base + i];
        int local = pr.y & 255;
        int pos = base + sbase[local] + atomicAdd(&cur[local], 1);
        edesc[pos] = pr.x;
    }
}

// T = R(d) @ W_e + bias (pre-scaled by log2e); tail blocks do weight prep
__global__ __launch_bounds__(256) void k_table2(const float* __restrict__ Wf,
                                                const float* __restrict__ bf,
                                                const float* __restrict__ Ws,
                                                const float* __restrict__ bs,
                                                const float* __restrict__ We,
                                                unsigned int* __restrict__ Tp,
                                                unsigned int* __restrict__ Bp,
                                                unsigned int* __restrict__ BpE) {
    int tid = threadIdx.x;
    int l = blockIdx.y;
    if (blockIdx.x == 161) {  // node-part weight prep for layer l
        int m = tid >> 6, c = tid & 63;
        const float* Wb = ((m & 2) ? Ws : Wf) + (size_t)l * ZD * ATOM + (m & 1) * ATOM * ATOM + c;
        unsigned int* dst = Bp + (size_t)l * 8192 + (size_t)tid * 32;
        for (int kp = 0; kp < 32; ++kp) {
            float w0 = Wb[(2 * kp) * ATOM] * LOG2E;
            float w1 = Wb[(2 * kp + 1) * ATOM] * LOG2E;
            dst[kp] = bfr(w0) | (bfr(w1) << 16);
        }
        return;
    }
    if (blockIdx.x == 162) {  // embed weight prep (once)
        if (l != 0) return;
        int n = tid & 63, q = tid >> 6;
        for (int kp = q * 16; kp < q * 16 + 16; ++kp) {
            int k0 = 2 * kp, k1 = 2 * kp + 1;
            float w0 = (k0 < ORIG) ? We[k0 * ATOM + n] : 0.f;
            float w1 = (k1 < ORIG) ? We[k1 * ATOM + n] : 0.f;
            BpE[(size_t)n * 64 + kp] = bfr(w0) | (bfr(w1) << 16);
        }
        return;
    }
    __shared__ float Wc[NBR * 64], Wsc[NBR * 64], R[32 * NBR];
    int b0 = blockIdx.x * 32;
    const float* srcf = Wf + (size_t)l * ZD * ATOM + 2 * ATOM * ATOM;
    const float* srcs = Ws + (size_t)l * ZD * ATOM + 2 * ATOM * ATOM;
    for (int i = tid; i < NBR * 64; i += 256) {
        Wc[i] = srcf[i] * LOG2E;
        Wsc[i] = srcs[i] * LOG2E;
    }
    for (int i = tid; i < 32 * NBR; i += 256) {
        int bin = i / NBR, k = i - bin * NBR;
        float d = (b0 + bin) * (TMAX / TBINS);
        float diff = d - 0.2f * k;
        R[i] = expf(-5.0f * diff * diff);
    }
    __syncthreads();
    int c = tid & 63;
    float afb = bf[l * ATOM + c] * LOG2E, asb = bs[l * ATOM + c] * LOG2E;
#pragma unroll
    for (int it = 0; it < 8; ++it) {
        int bin = (tid >> 6) + 4 * it;
        int gb = b0 + bin;
        if (gb <= TBINS) {
            float af = afb, as = asb;
            for (int k = 0; k < NBR; ++k) {
                float r = R[bin * NBR + k];
                af += r * Wc[k * 64 + c];
                as += r * Wsc[k * 64 + c];
            }
            Tp[(size_t)l * TS + (size_t)gb * 64 + c] = bfr(af) | (bfr(as) << 16);
        }
    }
}

// h = x @ W_emb + b_emb via MFMA (bf16, K=128 padded)
__global__ __launch_bounds__(256) void k_embed_mfma(const float* __restrict__ x,
                                                    const unsigned int* __restrict__ BpE,
                                                    const float* __restrict__ be,
                                                    float* __restrict__ h) {
    __shared__ short A[64 * SPE];
    __shared__ short B[64 * SPE];
    int tid = threadIdx.x;
    int n0 = blockIdx.x * 64;
    for (int i = tid; i < 64 * 64; i += 256) {
        int r = i >> 6, kp = i & 63;
        int node = n0 + r;
        float2 v = make_float2(0.f, 0.f);
        if (node < N_NODES && kp < 46) v = ((const float2*)x)[(size_t)node * 46 + kp];
        *(unsigned int*)&A[r * SPE + kp * 2] = bfr(v.x) | (bfr(v.y) << 16);
    }
    {
        const uint4* src = (const uint4*)BpE;
        for (int i = tid; i < 64 * 16; i += 256) {
            int row = i >> 4, q = i & 15;
            *(uint4*)&B[row * SPE + q * 8] = src[i];
        }
    }
    __syncthreads();
    int lane = tid & 63, w = tid >> 6;
    int c15 = lane & 15, kb = lane >> 4;
    short8 af[4];
#pragma unroll
    for (int s = 0; s < 4; ++s)
        af[s] = *(const short8*)&A[(16 * w + c15) * SPE + s * 32 + kb * 8];
    f32x4 acc[4];
#pragma unroll
    for (int t = 0; t < 4; ++t) acc[t] = (f32x4){0.f, 0.f, 0.f, 0.f};
#pragma unroll
    for (int t = 0; t < 4; ++t) {
#pragma unroll
        for (int s = 0; s < 4; ++s) {
            short8 bf8 = *(const short8*)&B[(16 * t + c15) * SPE + s * 32 + kb * 8];
            acc[t] = __builtin_amdgcn_mfma_f32_16x16x32_bf16(af[s], bf8, acc[t], 0, 0, 0);
        }
    }
#pragma unroll
    for (int t = 0; t < 4; ++t) {
        float bias = be[16 * t + c15];
#pragma unroll
        for (int reg = 0; reg < 4; ++reg) {
            int node = n0 + 16 * w + kb * 4 + reg;
            if (node < N_NODES) h[(size_t)node * 64 + 16 * t + c15] = acc[t][reg] + bias;
        }
    }
}

// fused: (optional) BN+residual update of h, then MFMA projection -> Pi, Pj
__global__ __launch_bounds__(256) void k_nodeP_mfma(float* __restrict__ h,
                                                    const float* __restrict__ agg,
                                                    const float* __restrict__ ss,
                                                    const unsigned int* __restrict__ Bp,
                                                    int l, int upd,
                                                    unsigned int* __restrict__ Pi,
                                                    unsigned int* __restrict__ Pj) {
    __shared__ short A[64 * SP];
    __shared__ short B[256 * SP];
    int tid = threadIdx.x;
    int n0 = blockIdx.x * 64;
    for (int i = tid; i < 64 * 32; i += 256) {
        int r = i >> 5, kp = i & 31;
        int node = n0 + r;
        int gi = node * 32 + kp;
        float2 hv = make_float2(0.f, 0.f);
        if (node < N_NODES) {
            hv = ((const float2*)h)[gi];
            if (upd) {
                float2 av = ((const float2*)agg)[gi];
                int c = kp * 2;
                float x0 = ss[c] * av.x + ss[64 + c] + hv.x;
                float x1 = ss[c + 1] * av.y + ss[64 + c + 1] + hv.y;
                hv.x = softplus_f(x0);
                hv.y = softplus_f(x1);
                ((float2*)h)[gi] = hv;
            }
        }
        *(unsigned int*)&A[r * SP + kp * 2] = bfr(hv.x) | (bfr(hv.y) << 16);
    }
    {
        const uint4* src = (const uint4*)(Bp + (size_t)l * 8192);
        for (int i = tid; i < 2048; i += 256) {
            int row = i >> 3, j = i & 7;
            *(uint4*)&B[row * SP + j * 8] = src[row * 8 + j];
        }
    }
    __syncthreads();
    int lane = tid & 63, w = tid >> 6;
    int c15 = lane & 15, kb = lane >> 4;
    short8 af[2];
#pragma unroll
    for (int s = 0; s < 2; ++s)
        af[s] = *(const short8*)&A[(16 * w + c15) * SP + s * 32 + kb * 8];
    f32x4 acc[16];
#pragma unroll
    for (int t = 0; t < 16; ++t) acc[t] = (f32x4){0.f, 0.f, 0.f, 0.f};
#pragma unroll
    for (int t = 0; t < 16; ++t) {
#pragma unroll
        for (int s = 0; s < 2; ++s) {
            short8 bf8 = *(const short8*)&B[(16 * t + c15) * SP + s * 32 + kb * 8];
            acc[t] = __builtin_amdgcn_mfma_f32_16x16x32_bf16(af[s], bf8, acc[t], 0, 0, 0);
        }
    }
#pragma unroll
    for (int t = 0; t < 4; ++t) {
#pragma unroll
        for (int reg = 0; reg < 4; ++reg) {
            int row = kb * 4 + reg;
            int node = n0 + 16 * w + row;
            if (node < N_NODES) {
                Pi[(size_t)node * 64 + 16 * t + c15] =
                    bfr(acc[t][reg]) | (bfr(acc[t + 8][reg]) << 16);
                Pj[(size_t)node * 64 + 16 * t + c15] =
                    bfr(acc[t + 4][reg]) | (bfr(acc[t + 12][reg]) << 16);
            }
        }
    }
}

// one wave per node; packed scalar descriptors, saddr gathers, exp2-domain math
__global__ __launch_bounds__(256) void k_edge_sorted(const int* __restrict__ offs,
                                                     const int* __restrict__ edesc,
                                                     const unsigned int* __restrict__ Pi,
                                                     const unsigned int* __restrict__ Pj,
                                                     const unsigned int* __restrict__ Tp,
                                                     float* __restrict__ agg) {
    int wid = (blockIdx.x * 256 + threadIdx.x) >> 6;
    int lane = threadIdx.x & 63;
    if (wid >= N_NODES) return;
    int uwid = __builtin_amdgcn_readfirstlane(wid);
    int2 kk;
    asm volatile("s_load_dwordx2 %0, %1, 0x0\n\ts_waitcnt lgkmcnt(0)"
                 : "=s"(kk) : "s"(offs + uwid));
    int ko = kk.x, ke = kk.y;
    unsigned int pi = Pi[(size_t)uwid * 64 + lane];
    float gi = bf_lo(pi), ci = bf_hi(pi);
    float acc = 0.0f;
    int lane4 = lane * 4;
    const char* PjB = (const char*)Pj;
    const char* TpB = (const char*)Tp;
    int k0 = ko;
    for (; k0 + 16 <= ke; k0 += 16) {
        int8v e0, e1;
        asm volatile(
            "s_load_dwordx8 %0, %2, 0x0\n\t"
            "s_load_dwordx8 %1, %2, 0x20\n\t"
            "s_waitcnt lgkmcnt(0)"
            : "=&s"(e0), "=&s"(e1)
            : "s"(edesc + k0));
        unsigned int pjv[16], tjv[16];
#pragma unroll
        for (int j = 0; j < 16; ++j) {
            int v = (j < 8) ? e0[j & 7] : e1[j & 7];
            int sb = (v & 0x1FFFF) << 8;
            int tb = (v >> 17) << 8;
            pjv[j] = *(const unsigned int*)(PjB + sb + lane4);
            tjv[j] = *(const unsigned int*)(TpB + tb + lane4);
        }
#pragma unroll
        for (int j = 0; j < 16; ++j) {
            float g = gi + bf_lo(pjv[j]) + bf_lo(tjv[j]);
            float c = ci + bf_hi(pjv[j]) + bf_hi(tjv[j]);
            float sg = __builtin_amdgcn_rcpf(1.0f + __builtin_amdgcn_exp2f(-g));
            float sp = fmaxf(c, 0.0f) + __builtin_amdgcn_logf(1.0f + __builtin_amdgcn_exp2f(-fabsf(c)));
            acc = fmaf(sg * sp, LN2, acc);
        }
    }
    if (k0 < ke) {
        int8v e0, e1;
        asm volatile(
            "s_load_dwordx8 %0, %2, 0x0\n\t"
            "s_load_dwordx8 %1, %2, 0x20\n\t"
            "s_waitcnt lgkmcnt(0)"
            : "=&s"(e0), "=&s"(e1)
            : "s"(edesc + k0));
        unsigned int pjv[16], tjv[16];
#pragma unroll
        for (int j = 0; j < 16; ++j) {
            if (k0 + j < ke) {
                int v = (j < 8) ? e0[j & 7] : e1[j & 7];
                int sb = (v & 0x1FFFF) << 8;
                int tb = (v >> 17) << 8;
                pjv[j] = *(const unsigned int*)(PjB + sb + lane4);
                tjv[j] = *(const unsigned int*)(TpB + tb + lane4);
            }
        }
#pragma unroll
        for (int j = 0; j < 16; ++j) {
            if (k0 + j < ke) {
                float g = gi + bf_lo(pjv[j]) + bf_lo(tjv[j]);
                float c = ci + bf_hi(pjv[j]) + bf_hi(tjv[j]);
                float sg = __builtin_amdgcn_rcpf(1.0f + __builtin_amdgcn_exp2f(-g));
                float sp = fmaxf(c, 0.0f) + __builtin_amdgcn_logf(1.0f + __builtin_amdgcn_exp2f(-fabsf(c)));
                acc = fmaf(sg * sp, LN2, acc);
            }
        }
    }
    agg[(size_t)uwid * 64 + lane] = acc;
}

// bnstats + bnfinal merged via last-block pattern
__global__ __launch_bounds__(256) void k_bnstats2(const float* __restrict__ agg,
                                                  float* __restrict__ partial,
                                                  int* __restrict__ lcnt,
                                                  const float* __restrict__ gamma,
                                                  const float* __restrict__ beta,
                                                  int l, float* __restrict__ ss) {
    __shared__ float ls[256], ls2[256];
    __shared__ int lastFlag;
    int c = threadIdx.x & 63, rg = threadIdx.x >> 6;
    float s = 0.0f, s2 = 0.0f;
    for (int n = blockIdx.x * 4 + rg; n < N_NODES; n += NPBLK * 4) {
        float v = agg[(size_t)n * ATOM + c];
        s += v; s2 += v * v;
    }
    ls[threadIdx.x] = s; ls2[threadIdx.x] = s2;
    __syncthreads();
    if (threadIdx.x < 64) {
        s = ls[c] + ls[64 + c] + ls[128 + c] + ls[192 + c];
        s2 = ls2[c] + ls2[64 + c] + ls2[128 + c] + ls2[192 + c];
        partial[blockIdx.x * 128 + c] = s;
        partial[blockIdx.x * 128 + 64 + c] = s2;
    }
    __syncthreads();
    if (threadIdx.x == 0) {
        __threadfence();
        lastFlag = (atomicAdd(lcnt, 1) == NPBLK - 1) ? 1 : 0;
    }
    __syncthreads();
    if (lastFlag) {
        __threadfence();
        int t = threadIdx.x;
        if (t < 128) {
            float sum = 0.0f;
            for (int b = 0; b < NPBLK; ++b) sum += partial[b * 128 + t];
            ls[t] = sum;
        }
        __syncthreads();
        if (t < 64) {
            const float inv = 1.0f / (float)N_NODES;
            float mu = ls[t] * inv;
            float var = ls[64 + t] * inv - mu * mu;
            float sc = gamma[l * ATOM + t] * rsqrtf(var + 1e-5f);
            ss[t] = sc;
            ss[64 + t] = beta[l * ATOM + t] - mu * sc;
        }
    }
}

// fused final update + pool; batch is sorted -> run-length accumulate
__global__ __launch_bounds__(256) void k_pool2(const float* __restrict__ agg,
                                               const float* __restrict__ ss,
                                               const float* __restrict__ h,
                                               const int* __restrict__ batch,
                                               float* __restrict__ g) {
    int w = threadIdx.x >> 6, lane = threadIdx.x & 63;
    int nbase = blockIdx.x * 64 + w * 16;
    float acc = 0.0f;
    int curg = -1;
    float sc = ss[lane], sh = ss[64 + lane];
    for (int i = 0; i < 16; ++i) {
        int n = nbase + i;
        if (n >= N_NODES) break;
        int gid = __builtin_amdgcn_readfirstlane(batch[n]);
        if (gid != curg) {
            if (curg >= 0) atomicAdd(&g[(size_t)curg * ATOM + lane], acc);
            curg = gid;
            acc = 0.0f;
        }
        float x = sc * agg[(size_t)n * 64 + lane] + sh + h[(size_t)n * 64 + lane];
        acc += softplus_f(x);
    }
    if (curg >= 0) atomicAdd(&g[(size_t)curg * ATOM + lane], acc);
}

__global__ __launch_bounds__(128) void k_head(const float* __restrict__ g,
                                              const float* __restrict__ W1,
                                              const float* __restrict__ b1,
                                              const float* __restrict__ W2,
                                              const float* __restrict__ b2,
                                              float* __restrict__ out) {
    __shared__ float red[128];
    int gid = blockIdx.x, j = threadIdx.x;
    float acc = b1[j];
    for (int k = 0; k < ATOM; ++k) acc += g[gid * ATOM + k] * W1[k * HFEA + j];
    red[j] = softplus_f(acc) * W2[j];
    __syncthreads();
    for (int s = 64; s > 0; s >>= 1) {
        if (j < s) red[j] += red[j + s];
        __syncthreads();
    }
    if (j == 0) out[gid] = red[0] + b2[0];
}

extern "C" void kernel_launch(void* const* d_in, const int* in_sizes, int n_in,
                              void* d_out, int out_size, void* d_ws, size_t ws_size,
                              hipStream_t stream) {
    const float* x       = (const float*)d_in[0];
    const float* ea      = (const float*)d_in[1];
    const float* W_emb   = (const float*)d_in[2];
    const float* b_emb   = (const float*)d_in[3];
    const float* Wf      = (const float*)d_in[4];
    const float* bf      = (const float*)d_in[5];
    const float* Ws      = (const float*)d_in[6];
    const float* bs      = (const float*)d_in[7];
    const float* bn_g    = (const float*)d_in[8];
    const float* bn_b    = (const float*)d_in[9];
    const float* W1      = (const float*)d_in[10];
    const float* b1      = (const float*)d_in[11];
    const float* W2      = (const float*)d_in[12];
    const float* b2      = (const float*)d_in[13];
    const int*   ei      = (const int*)d_in[14];
    const int*   batch   = (const int*)d_in[15];
    float* out = (float*)d_out;

    char* wsb = (char*)d_ws;
    size_t off = 0;
    auto alloc = [&](size_t bytes) { char* p = wsb + off; off += (bytes + 255) & ~(size_t)255; return p; };
    float*        h        = (float*)alloc((size_t)N_NODES * 64 * 4);
    float*        agg      = (float*)alloc((size_t)N_NODES * 64 * 4);
    unsigned int* Pi       = (unsigned int*)alloc((size_t)N_NODES * 64 * 4);
    unsigned int* Pj       = (unsigned int*)alloc((size_t)N_NODES * 64 * 4);
    int*          edesc    = (int*)alloc((size_t)(N_EDGES + 16) * 4);
    int2*         staging  = (int2*)alloc((size_t)N_EDGES * 8);
    int*          meta     = (int*)alloc(1024 * 4);   // [0..511] bucketCnt, [512..519] lcnt
    int*          bucketCnt    = meta;
    int*          lcnt         = meta + 512;
    int*          bucketBase   = (int*)alloc(520 * 4);
    int*          bucketCursor = (int*)alloc(512 * 4);
    int*          offs     = (int*)alloc((size_t)(N_NODES + 1) * 4);
    unsigned int* Tp       = (unsigned int*)alloc((size_t)NCONV * TS * 4);
    unsigned int* Bp       = (unsigned int*)alloc((size_t)NCONV * 8192 * 4);
    unsigned int* BpE      = (unsigned int*)alloc((size_t)64 * 64 * 4);
    float*        partial  = (float*)alloc((size_t)NPBLK * 128 * 4);
    float*        ss       = (float*)alloc(128 * 4);
    float*        g        = (float*)alloc((size_t)NGRAPH * 64 * 4);

    (void)hipMemsetAsync(meta, 0, 1024 * 4, stream);
    k_bhist<<<256, 256, 0, stream>>>(ei, bucketCnt);
    k_bscan2<<<1, 64, 0, stream>>>(bucketCnt, bucketBase, bucketCursor, offs);
    k_psort1<<<(N_EDGES + S3CH - 1) / S3CH, 256, 0, stream>>>(ei, ea, bucketCursor, staging);
    k_psort2<<<NBKT, 256, 0, stream>>>(bucketBase, staging, edesc, offs);

    dim3 tg(163, NCONV);
    k_table2<<<tg, 256, 0, stream>>>(Wf, bf, Ws, bs, W_emb, Tp, Bp, BpE);
    k_embed_mfma<<<(N_NODES + 63) / 64, 256, 0, stream>>>(x, BpE, b_emb, h);

    for (int l = 0; l < NCONV; ++l) {
        k_nodeP_mfma<<<(N_NODES + 63) / 64, 256, 0, stream>>>(h, agg, ss, Bp, l, l > 0, Pi, Pj);
        k_edge_sorted<<<(N_NODES * 64 + 255) / 256, 256, 0, stream>>>(
            offs, edesc, Pi, Pj, Tp + (size_t)l * TS, agg);
        k_bnstats2<<<NPBLK, 256, 0, stream>>>(agg, partial, lcnt + l, bn_g, bn_b, l, ss);
    }

    (void)hipMemsetAsync(g, 0, (size_t)NGRAPH * 64 * 4, stream);
    k_pool2<<<(N_NODES + 63) / 64, 256, 0, stream>>>(agg, ss, h, batch, g);
    k_head<<<NGRAPH, 128, 0, stream>>>(g, W1, b1, W2, b2, out);
}

// Round 12
// 561.579 us; speedup vs baseline: 3.6955x; 1.0711x over previous
//
#include <hip/hip_runtime.h>
#include <hip/hip_bf16.h>
#include <math.h>

#define N_NODES 100000
#define N_EDGES 1600000
#define ORIG    92
#define NBR     41
#define ATOM    64
#define NCONV   3
#define HFEA    128
#define NGRAPH  256
#define ZD      169           // 2*ATOM + NBR
#define TBINS   5120
#define TMAX    10.0f
#define TS      ((TBINS + 1) * 64)   // per-layer table stride (uints)
#define SP      72                   // nodeP LDS row pad (shorts)
#define SPE     136                  // embed LDS row pad (shorts), K=128
#define NPBLK   128                  // bnstats partial blocks
#define LOG2E   1.4426950408889634f
#define LN2     0.6931471805599453f
#define NBKT    391                  // ceil(N_NODES / 256)
#define S1E     6250                 // edges per k_bhist block (256 blocks exact)
#define S3CH    4096                 // edges per k_psort1 block

typedef __attribute__((ext_vector_type(8))) short short8;
typedef __attribute__((ext_vector_type(4))) float f32x4;
typedef __attribute__((ext_vector_type(8))) int int8v;

__device__ __forceinline__ float softplus_f(float x) {
    return fmaxf(x, 0.0f) + log1pf(expf(-fabsf(x)));
}
// fast softplus via exp2/log2 HW ops
__device__ __forceinline__ float sp_fast2(float x) {
    float t = x * LOG2E;
    return LN2 * (fmaxf(t, 0.0f) +
                  __builtin_amdgcn_logf(1.0f + __builtin_amdgcn_exp2f(-fabsf(t))));
}
// pack 2 fp32 -> 2 bf16 in one uint (lo in low 16, hi in high 16)
__device__ __forceinline__ unsigned int pk_bf16(float lo, float hi) {
    unsigned int r;
    asm("v_cvt_pk_bf16_f32 %0, %1, %2" : "=v"(r) : "v"(lo), "v"(hi));
    return r;
}
__device__ __forceinline__ float bf_lo(unsigned int p) { return __uint_as_float(p << 16); }
__device__ __forceinline__ float bf_hi(unsigned int p) { return __uint_as_float(p & 0xffff0000u); }

// ---------- sort pass 0: coarse bucket histogram + last-block scan ----------
__global__ __launch_bounds__(256) void k_bhist(const int* __restrict__ ei,
                                               int* __restrict__ bucketCnt,
                                               int* __restrict__ flag,
                                               int* __restrict__ bucketBase,
                                               int* __restrict__ bucketCursor,
                                               int* __restrict__ offs) {
    __shared__ int cntL[NBKT];
    __shared__ int lastFlag;
    int tid = threadIdx.x;
    for (int i = tid; i < NBKT; i += 256) cntL[i] = 0;
    __syncthreads();
    int base = blockIdx.x * S1E;
    for (int i = tid; i < S1E; i += 256)
        atomicAdd(&cntL[ei[N_EDGES + base + i] >> 8], 1);
    __syncthreads();
    for (int i = tid; i < NBKT; i += 256)
        if (cntL[i]) atomicAdd(&bucketCnt[i], cntL[i]);
    if (tid == 0) {
        __threadfence();
        lastFlag = (atomicAdd(flag, 1) == 255) ? 1 : 0;
    }
    __syncthreads();
    if (lastFlag && tid < 64) {
        __threadfence();
        int carry = 0;
        for (int b0 = 0; b0 < NBKT; b0 += 64) {
            int idx = b0 + tid;
            int v0 = (idx < NBKT) ? bucketCnt[idx] : 0;
            int v = v0;
            for (int d = 1; d < 64; d <<= 1) {
                int u = __shfl_up(v, d, 64);
                if (tid >= d) v += u;
            }
            if (idx < NBKT) {
                int ex = carry + v - v0;
                bucketBase[idx] = ex;
                bucketCursor[idx] = ex;
            }
            carry += __shfl(v, 63, 64);
        }
        if (tid == 0) {
            bucketBase[NBKT] = N_EDGES;
            offs[N_NODES] = N_EDGES;
        }
    }
}

// ---------- sort pass 1: bucket-binned staging, coalesced burst writes ----------
__global__ __launch_bounds__(256) void k_psort1(const int* __restrict__ ei,
                                                const float* __restrict__ ea,
                                                int* __restrict__ bucketCursor,
                                                int2* __restrict__ staging) {
    __shared__ int cntL[NBKT], scanB[NBKT], curL[NBKT], gbaseL[NBKT];
    __shared__ int sortedD[S3CH], sortedN[S3CH];
    int tid = threadIdx.x;
    int base = blockIdx.x * S3CH;
    int myCount = N_EDGES - base;
    if (myCount > S3CH) myCount = S3CH;
    for (int i = tid; i < NBKT; i += 256) { cntL[i] = 0; curL[i] = 0; }
    __syncthreads();
    int descr[16], dstr[16];
#pragma unroll
    for (int j = 0; j < 16; ++j) {
        int i = j * 256 + tid;
        descr[j] = 0; dstr[j] = -1;
        if (i < myCount) {
            int e = base + i;
            int src = ei[e];
            int dst = ei[N_EDGES + e];
            float a = ea[3 * e], bb = ea[3 * e + 1], c = ea[3 * e + 2];
            float d = sqrtf(a * a + bb * bb + c * c);
            int bin = (int)fminf(fmaf(d, (float)TBINS / TMAX, 0.5f), (float)TBINS);
            descr[j] = (bin << 17) | src;
            dstr[j] = dst;
            atomicAdd(&cntL[dst >> 8], 1);
        }
    }
    __syncthreads();
    if (tid < 64) {  // wave 0 exclusive-scans cntL
        int carry = 0;
        for (int b0 = 0; b0 < NBKT; b0 += 64) {
            int idx = b0 + tid;
            int v0 = (idx < NBKT) ? cntL[idx] : 0;
            int v = v0;
            for (int d = 1; d < 64; d <<= 1) {
                int u = __shfl_up(v, d, 64);
                if (tid >= d) v += u;
            }
            if (idx < NBKT) scanB[idx] = carry + v - v0;
            carry += __shfl(v, 63, 64);
        }
    }
    __syncthreads();
#pragma unroll
    for (int j = 0; j < 16; ++j) {
        if (dstr[j] >= 0) {
            int b = dstr[j] >> 8;
            int pos = scanB[b] + atomicAdd(&curL[b], 1);
            sortedD[pos] = descr[j];
            sortedN[pos] = dstr[j];
        }
    }
    for (int i = tid; i < NBKT; i += 256)
        if (cntL[i] > 0) gbaseL[i] = atomicAdd(&bucketCursor[i], cntL[i]);
    __syncthreads();
    for (int i = tid; i < myCount; i += 256) {
        int n = sortedN[i];
        int b = n >> 8;
        int2 pr; pr.x = sortedD[i]; pr.y = n;
        staging[gbaseL[b] + (i - scanB[b])] = pr;
    }
}

// ---------- sort pass 2: per-bucket exact sort + offs ----------
__global__ __launch_bounds__(256) void k_psort2(const int* __restrict__ bucketBase,
                                                const int2* __restrict__ staging,
                                                int* __restrict__ edesc,
                                                int* __restrict__ offs) {
    __shared__ int cnt[256], sbase[256], cur[256];
    int b = blockIdx.x, tid = threadIdx.x;
    int base = bucketBase[b];
    int nb = bucketBase[b + 1] - base;
    cnt[tid] = 0; cur[tid] = 0;
    __syncthreads();
    for (int i = tid; i < nb; i += 256)
        atomicAdd(&cnt[staging[base + i].y & 255], 1);
    __syncthreads();
    int v = cnt[tid];
    sbase[tid] = v;
    __syncthreads();
    for (int d = 1; d < 256; d <<= 1) {
        int u = (tid >= d) ? sbase[tid - d] : 0;
        __syncthreads();
        sbase[tid] += u;
        __syncthreads();
    }
    int ex = sbase[tid] - v;
    int dst = (b << 8) + tid;
    if (dst < N_NODES) offs[dst] = base + ex;
    sbase[tid] = ex;
    __syncthreads();
    for (int i = tid; i < nb; i += 256) {
        int2 pr = staging[base + i];
        int local = pr.y & 255;
        int pos = base + sbase[local] + atomicAdd(&cur[local], 1);
        edesc[pos] = pr.x;
    }
}

// T = R(d) @ W_e + bias (pre-scaled by log2e); tail blocks do weight prep
__global__ __launch_bounds__(256) void k_table2(const float* __restrict__ Wf,
                                                const float* __restrict__ bf,
                                                const float* __restrict__ Ws,
                                                const float* __restrict__ bs,
                                                const float* __restrict__ We,
                                                unsigned int* __restrict__ Tp,
                                                unsigned int* __restrict__ Bp,
                                                unsigned int* __restrict__ BpE) {
    int tid = threadIdx.x;
    int l = blockIdx.y;
    if (blockIdx.x == 161) {  // node-part weight prep for layer l
        int m = tid >> 6, c = tid & 63;
        const float* Wb = ((m & 2) ? Ws : Wf) + (size_t)l * ZD * ATOM + (m & 1) * ATOM * ATOM + c;
        unsigned int* dst = Bp + (size_t)l * 8192 + (size_t)tid * 32;
        for (int kp = 0; kp < 32; ++kp) {
            float w0 = Wb[(2 * kp) * ATOM] * LOG2E;
            float w1 = Wb[(2 * kp + 1) * ATOM] * LOG2E;
            dst[kp] = pk_bf16(w0, w1);
        }
        return;
    }
    if (blockIdx.x == 162) {  // embed weight prep (once)
        if (l != 0) return;
        int n = tid & 63, q = tid >> 6;
        for (int kp = q * 16; kp < q * 16 + 16; ++kp) {
            int k0 = 2 * kp, k1 = 2 * kp + 1;
            float w0 = (k0 < ORIG) ? We[k0 * ATOM + n] : 0.f;
            float w1 = (k1 < ORIG) ? We[k1 * ATOM + n] : 0.f;
            BpE[(size_t)n * 64 + kp] = pk_bf16(w0, w1);
        }
        return;
    }
    __shared__ float Wc[NBR * 64], Wsc[NBR * 64], R[32 * NBR];
    int b0 = blockIdx.x * 32;
    const float* srcf = Wf + (size_t)l * ZD * ATOM + 2 * ATOM * ATOM;
    const float* srcs = Ws + (size_t)l * ZD * ATOM + 2 * ATOM * ATOM;
    for (int i = tid; i < NBR * 64; i += 256) {
        Wc[i] = srcf[i] * LOG2E;
        Wsc[i] = srcs[i] * LOG2E;
    }
    for (int i = tid; i < 32 * NBR; i += 256) {
        int bin = i / NBR, k = i - bin * NBR;
        float d = (b0 + bin) * (TMAX / TBINS);
        float diff = d - 0.2f * k;
        R[i] = expf(-5.0f * diff * diff);
    }
    __syncthreads();
    int c = tid & 63;
    float afb = bf[l * ATOM + c] * LOG2E, asb = bs[l * ATOM + c] * LOG2E;
#pragma unroll
    for (int it = 0; it < 8; ++it) {
        int bin = (tid >> 6) + 4 * it;
        int gb = b0 + bin;
        if (gb <= TBINS) {
            float af = afb, as = asb;
            for (int k = 0; k < NBR; ++k) {
                float r = R[bin * NBR + k];
                af += r * Wc[k * 64 + c];
                as += r * Wsc[k * 64 + c];
            }
            Tp[(size_t)l * TS + (size_t)gb * 64 + c] = pk_bf16(af, as);
        }
    }
}

// h = x @ W_emb + b_emb via MFMA (bf16, K=128 padded)
__global__ __launch_bounds__(256) void k_embed_mfma(const float* __restrict__ x,
                                                    const unsigned int* __restrict__ BpE,
                                                    const float* __restrict__ be,
                                                    float* __restrict__ h) {
    __shared__ short A[64 * SPE];
    __shared__ short B[64 * SPE];
    int tid = threadIdx.x;
    int n0 = blockIdx.x * 64;
    for (int i = tid; i < 64 * 64; i += 256) {
        int r = i >> 6, kp = i & 63;
        int node = n0 + r;
        float2 v = make_float2(0.f, 0.f);
        if (node < N_NODES && kp < 46) v = ((const float2*)x)[(size_t)node * 46 + kp];
        *(unsigned int*)&A[r * SPE + kp * 2] = pk_bf16(v.x, v.y);
    }
    {
        const uint4* src = (const uint4*)BpE;
        for (int i = tid; i < 64 * 16; i += 256) {
            int row = i >> 4, q = i & 15;
            *(uint4*)&B[row * SPE + q * 8] = src[i];
        }
    }
    __syncthreads();
    int lane = tid & 63, w = tid >> 6;
    int c15 = lane & 15, kb = lane >> 4;
    short8 af[4];
#pragma unroll
    for (int s = 0; s < 4; ++s)
        af[s] = *(const short8*)&A[(16 * w + c15) * SPE + s * 32 + kb * 8];
    f32x4 acc[4];
#pragma unroll
    for (int t = 0; t < 4; ++t) acc[t] = (f32x4){0.f, 0.f, 0.f, 0.f};
#pragma unroll
    for (int t = 0; t < 4; ++t) {
#pragma unroll
        for (int s = 0; s < 4; ++s) {
            short8 bf8 = *(const short8*)&B[(16 * t + c15) * SPE + s * 32 + kb * 8];
            acc[t] = __builtin_amdgcn_mfma_f32_16x16x32_bf16(af[s], bf8, acc[t], 0, 0, 0);
        }
    }
#pragma unroll
    for (int t = 0; t < 4; ++t) {
        float bias = be[16 * t + c15];
#pragma unroll
        for (int reg = 0; reg < 4; ++reg) {
            int node = n0 + 16 * w + kb * 4 + reg;
            if (node < N_NODES) h[(size_t)node * 64 + 16 * t + c15] = acc[t][reg] + bias;
        }
    }
}

// fused: (optional) BN+residual update of h, then MFMA projection -> Pi, Pj
__global__ __launch_bounds__(256) void k_nodeP_mfma(float* __restrict__ h,
                                                    const float* __restrict__ agg,
                                                    const float* __restrict__ ss,
                                                    const unsigned int* __restrict__ Bp,
                                                    int l, int upd,
                                                    unsigned int* __restrict__ Pi,
                                                    unsigned int* __restrict__ Pj) {
    __shared__ short A[64 * SP];
    __shared__ short B[256 * SP];
    int tid = threadIdx.x;
    int n0 = blockIdx.x * 64;
    for (int i = tid; i < 64 * 32; i += 256) {
        int r = i >> 5, kp = i & 31;
        int node = n0 + r;
        int gi = node * 32 + kp;
        float2 hv = make_float2(0.f, 0.f);
        if (node < N_NODES) {
            hv = ((const float2*)h)[gi];
            if (upd) {
                float2 av = ((const float2*)agg)[gi];
                int c = kp * 2;
                float x0 = ss[c] * av.x + ss[64 + c] + hv.x;
                float x1 = ss[c + 1] * av.y + ss[64 + c + 1] + hv.y;
                hv.x = sp_fast2(x0);
                hv.y = sp_fast2(x1);
                ((float2*)h)[gi] = hv;
            }
        }
        *(unsigned int*)&A[r * SP + kp * 2] = pk_bf16(hv.x, hv.y);
    }
    {
        const uint4* src = (const uint4*)(Bp + (size_t)l * 8192);
        for (int i = tid; i < 2048; i += 256) {
            int row = i >> 3, j = i & 7;
            *(uint4*)&B[row * SP + j * 8] = src[row * 8 + j];
        }
    }
    __syncthreads();
    int lane = tid & 63, w = tid >> 6;
    int c15 = lane & 15, kb = lane >> 4;
    short8 af[2];
#pragma unroll
    for (int s = 0; s < 2; ++s)
        af[s] = *(const short8*)&A[(16 * w + c15) * SP + s * 32 + kb * 8];
    f32x4 acc[16];
#pragma unroll
    for (int t = 0; t < 16; ++t) acc[t] = (f32x4){0.f, 0.f, 0.f, 0.f};
#pragma unroll
    for (int t = 0; t < 16; ++t) {
#pragma unroll
        for (int s = 0; s < 2; ++s) {
            short8 bf8 = *(const short8*)&B[(16 * t + c15) * SP + s * 32 + kb * 8];
            acc[t] = __builtin_amdgcn_mfma_f32_16x16x32_bf16(af[s], bf8, acc[t], 0, 0, 0);
        }
    }
#pragma unroll
    for (int t = 0; t < 4; ++t) {
#pragma unroll
        for (int reg = 0; reg < 4; ++reg) {
            int row = kb * 4 + reg;
            int node = n0 + 16 * w + row;
            if (node < N_NODES) {
                Pi[(size_t)node * 64 + 16 * t + c15] = pk_bf16(acc[t][reg], acc[t + 8][reg]);
                Pj[(size_t)node * 64 + 16 * t + c15] = pk_bf16(acc[t + 4][reg], acc[t + 12][reg]);
            }
        }
    }
}

// one wave per node; packed scalar descriptors, saddr gathers, exp2-domain math
__global__ __launch_bounds__(256) void k_edge_sorted(const int* __restrict__ offs,
                                                     const int* __restrict__ edesc,
                                                     const unsigned int* __restrict__ Pi,
                                                     const unsigned int* __restrict__ Pj,
                                                     const unsigned int* __restrict__ Tp,
                                                     float* __restrict__ agg) {
    int wid = (blockIdx.x * 256 + threadIdx.x) >> 6;
    int lane = threadIdx.x & 63;
    if (wid >= N_NODES) return;
    int uwid = __builtin_amdgcn_readfirstlane(wid);
    int2 kk;
    asm volatile("s_load_dwordx2 %0, %1, 0x0\n\ts_waitcnt lgkmcnt(0)"
                 : "=s"(kk) : "s"(offs + uwid));
    int ko = kk.x, ke = kk.y;
    unsigned int pi = Pi[(size_t)uwid * 64 + lane];
    float gi = bf_lo(pi), ci = bf_hi(pi);
    float acc = 0.0f;
    int lane4 = lane * 4;
    const char* PjB = (const char*)Pj;
    const char* TpB = (const char*)Tp;
    int k0 = ko;
    for (; k0 + 16 <= ke; k0 += 16) {
        int8v e0, e1;
        asm volatile(
            "s_load_dwordx8 %0, %2, 0x0\n\t"
            "s_load_dwordx8 %1, %2, 0x20\n\t"
            "s_waitcnt lgkmcnt(0)"
            : "=&s"(e0), "=&s"(e1)
            : "s"(edesc + k0));
        unsigned int pjv[16], tjv[16];
#pragma unroll
        for (int j = 0; j < 16; ++j) {
            int v = (j < 8) ? e0[j & 7] : e1[j & 7];
            int sb = (v & 0x1FFFF) << 8;
            int tb = (v >> 17) << 8;
            pjv[j] = *(const unsigned int*)(PjB + sb + lane4);
            tjv[j] = *(const unsigned int*)(TpB + tb + lane4);
        }
#pragma unroll
        for (int j = 0; j < 16; ++j) {
            float g = gi + bf_lo(pjv[j]) + bf_lo(tjv[j]);
            float c = ci + bf_hi(pjv[j]) + bf_hi(tjv[j]);
            float sg = __builtin_amdgcn_rcpf(1.0f + __builtin_amdgcn_exp2f(-g));
            float sp = fmaxf(c, 0.0f) + __builtin_amdgcn_logf(1.0f + __builtin_amdgcn_exp2f(-fabsf(c)));
            acc = fmaf(sg, sp, acc);
        }
    }
    if (k0 < ke) {
        int8v e0, e1;
        asm volatile(
            "s_load_dwordx8 %0, %2, 0x0\n\t"
            "s_load_dwordx8 %1, %2, 0x20\n\t"
            "s_waitcnt lgkmcnt(0)"
            : "=&s"(e0), "=&s"(e1)
            : "s"(edesc + k0));
        unsigned int pjv[16], tjv[16];
#pragma unroll
        for (int j = 0; j < 16; ++j) {
            if (k0 + j < ke) {
                int v = (j < 8) ? e0[j & 7] : e1[j & 7];
                int sb = (v & 0x1FFFF) << 8;
                int tb = (v >> 17) << 8;
                pjv[j] = *(const unsigned int*)(PjB + sb + lane4);
                tjv[j] = *(const unsigned int*)(TpB + tb + lane4);
            }
        }
#pragma unroll
        for (int j = 0; j < 16; ++j) {
            if (k0 + j < ke) {
                float g = gi + bf_lo(pjv[j]) + bf_lo(tjv[j]);
                float c = ci + bf_hi(pjv[j]) + bf_hi(tjv[j]);
                float sg = __builtin_amdgcn_rcpf(1.0f + __builtin_amdgcn_exp2f(-g));
                float sp = fmaxf(c, 0.0f) + __builtin_amdgcn_logf(1.0f + __builtin_amdgcn_exp2f(-fabsf(c)));
                acc = fmaf(sg, sp, acc);
            }
        }
    }
    agg[(size_t)uwid * 64 + lane] = acc * LN2;
}

// bnstats + bnfinal merged via last-block pattern
__global__ __launch_bounds__(256) void k_bnstats2(const float* __restrict__ agg,
                                                  float* __restrict__ partial,
                                                  int* __restrict__ lcnt,
                                                  const float* __restrict__ gamma,
                                                  const float* __restrict__ beta,
                                                  int l, float* __restrict__ ss) {
    __shared__ float ls[256], ls2[256];
    __shared__ int lastFlag;
    int c = threadIdx.x & 63, rg = threadIdx.x >> 6;
    float s = 0.0f, s2 = 0.0f;
    for (int n = blockIdx.x * 4 + rg; n < N_NODES; n += NPBLK * 4) {
        float v = agg[(size_t)n * ATOM + c];
        s += v; s2 += v * v;
    }
    ls[threadIdx.x] = s; ls2[threadIdx.x] = s2;
    __syncthreads();
    if (threadIdx.x < 64) {
        s = ls[c] + ls[64 + c] + ls[128 + c] + ls[192 + c];
        s2 = ls2[c] + ls2[64 + c] + ls2[128 + c] + ls2[192 + c];
        partial[blockIdx.x * 128 + c] = s;
        partial[blockIdx.x * 128 + 64 + c] = s2;
    }
    __syncthreads();
    if (threadIdx.x == 0) {
        __threadfence();
        lastFlag = (atomicAdd(lcnt, 1) == NPBLK - 1) ? 1 : 0;
    }
    __syncthreads();
    if (lastFlag) {
        __threadfence();
        int t = threadIdx.x;
        if (t < 128) {
            float sum = 0.0f;
            for (int b = 0; b < NPBLK; ++b) sum += partial[b * 128 + t];
            ls[t] = sum;
        }
        __syncthreads();
        if (t < 64) {
            const float inv = 1.0f / (float)N_NODES;
            float mu = ls[t] * inv;
            float var = ls[64 + t] * inv - mu * mu;
            float sc = gamma[l * ATOM + t] * rsqrtf(var + 1e-5f);
            ss[t] = sc;
            ss[64 + t] = beta[l * ATOM + t] - mu * sc;
        }
    }
}

// fused final update + pool; batch is sorted -> run-length accumulate
__global__ __launch_bounds__(256) void k_pool2(const float* __restrict__ agg,
                                               const float* __restrict__ ss,
                                               const float* __restrict__ h,
                                               const int* __restrict__ batch,
                                               float* __restrict__ g) {
    int w = threadIdx.x >> 6, lane = threadIdx.x & 63;
    int nbase = blockIdx.x * 64 + w * 16;
    float acc = 0.0f;
    int curg = -1;
    float sc = ss[lane], sh = ss[64 + lane];
    for (int i = 0; i < 16; ++i) {
        int n = nbase + i;
        if (n >= N_NODES) break;
        int gid = __builtin_amdgcn_readfirstlane(batch[n]);
        if (gid != curg) {
            if (curg >= 0) atomicAdd(&g[(size_t)curg * ATOM + lane], acc);
            curg = gid;
            acc = 0.0f;
        }
        float x = sc * agg[(size_t)n * 64 + lane] + sh + h[(size_t)n * 64 + lane];
        acc += sp_fast2(x);
    }
    if (curg >= 0) atomicAdd(&g[(size_t)curg * ATOM + lane], acc);
}

__global__ __launch_bounds__(128) void k_head(const float* __restrict__ g,
                                              const float* __restrict__ W1,
                                              const float* __restrict__ b1,
                                              const float* __restrict__ W2,
                                              const float* __restrict__ b2,
                                              float* __restrict__ out) {
    __shared__ float red[128];
    int gid = blockIdx.x, j = threadIdx.x;
    float acc = b1[j];
    for (int k = 0; k < ATOM; ++k) acc += g[gid * ATOM + k] * W1[k * HFEA + j];
    red[j] = softplus_f(acc) * W2[j];
    __syncthreads();
    for (int s = 64; s > 0; s >>= 1) {
        if (j < s) red[j] += red[j + s];
        __syncthreads();
    }
    if (j == 0) out[gid] = red[0] + b2[0];
}

extern "C" void kernel_launch(void* const* d_in, const int* in_sizes, int n_in,
                              void* d_out, int out_size, void* d_ws, size_t ws_size,
                              hipStream_t stream) {
    const float* x       = (const float*)d_in[0];
    const float* ea      = (const float*)d_in[1];
    const float* W_emb   = (const float*)d_in[2];
    const float* b_emb   = (const float*)d_in[3];
    const float* Wf      = (const float*)d_in[4];
    const float* bf      = (const float*)d_in[5];
    const float* Ws      = (const float*)d_in[6];
    const float* bs      = (const float*)d_in[7];
    const float* bn_g    = (const float*)d_in[8];
    const float* bn_b    = (const float*)d_in[9];
    const float* W1      = (const float*)d_in[10];
    const float* b1      = (const float*)d_in[11];
    const float* W2      = (const float*)d_in[12];
    const float* b2      = (const float*)d_in[13];
    const int*   ei      = (const int*)d_in[14];
    const int*   batch   = (const int*)d_in[15];
    float* out = (float*)d_out;

    char* wsb = (char*)d_ws;
    size_t off = 0;
    auto alloc = [&](size_t bytes) { char* p = wsb + off; off += (bytes + 255) & ~(size_t)255; return p; };
    float*        h        = (float*)alloc((size_t)N_NODES * 64 * 4);
    float*        agg      = (float*)alloc((size_t)N_NODES * 64 * 4);
    unsigned int* Pi       = (unsigned int*)alloc((size_t)N_NODES * 64 * 4);
    unsigned int* Pj       = (unsigned int*)alloc((size_t)N_NODES * 64 * 4);
    int*          edesc    = (int*)alloc((size_t)(N_EDGES + 16) * 4);
    int2*         staging  = (int2*)alloc((size_t)N_EDGES * 8);
    int*          meta     = (int*)alloc(1024 * 4);   // [0..511] bucketCnt, [512..] lcnt/flags
    int*          bucketCnt    = meta;
    int*          lcnt         = meta + 512;          // [0..2] bn layers, [3] bhist flag
    int*          bucketBase   = (int*)alloc(520 * 4);
    int*          bucketCursor = (int*)alloc(512 * 4);
    int*          offs     = (int*)alloc((size_t)(N_NODES + 1) * 4);
    unsigned int* Tp       = (unsigned int*)alloc((size_t)NCONV * TS * 4);
    unsigned int* Bp       = (unsigned int*)alloc((size_t)NCONV * 8192 * 4);
    unsigned int* BpE      = (unsigned int*)alloc((size_t)64 * 64 * 4);
    float*        partial  = (float*)alloc((size_t)NPBLK * 128 * 4);
    float*        ss       = (float*)alloc(128 * 4);
    float*        g        = (float*)alloc((size_t)NGRAPH * 64 * 4);

    (void)hipMemsetAsync(meta, 0, 1024 * 4, stream);
    k_bhist<<<256, 256, 0, stream>>>(ei, bucketCnt, lcnt + 3, bucketBase, bucketCursor, offs);
    k_psort1<<<(N_EDGES + S3CH - 1) / S3CH, 256, 0, stream>>>(ei, ea, bucketCursor, staging);
    k_psort2<<<NBKT, 256, 0, stream>>>(bucketBase, staging, edesc, offs);

    dim3 tg(163, NCONV);
    k_table2<<<tg, 256, 0, stream>>>(Wf, bf, Ws, bs, W_emb, Tp, Bp, BpE);
    k_embed_mfma<<<(N_NODES + 63) / 64, 256, 0, stream>>>(x, BpE, b_emb, h);

    for (int l = 0; l < NCONV; ++l) {
        k_nodeP_mfma<<<(N_NODES + 63) / 64, 256, 0, stream>>>(h, agg, ss, Bp, l, l > 0, Pi, Pj);
        k_edge_sorted<<<(N_NODES * 64 + 255) / 256, 256, 0, stream>>>(
            offs, edesc, Pi, Pj, Tp + (size_t)l * TS, agg);
        k_bnstats2<<<NPBLK, 256, 0, stream>>>(agg, partial, lcnt + l, bn_g, bn_b, l, ss);
    }

    (void)hipMemsetAsync(g, 0, (size_t)NGRAPH * 64 * 4, stream);
    k_pool2<<<(N_NODES + 63) / 64, 256, 0, stream>>>(agg, ss, h, batch, g);
    k_head<<<NGRAPH, 128, 0, stream>>>(g, W1, b1, W2, b2, out);
}

// Round 13
// 501.545 us; speedup vs baseline: 4.1379x; 1.1197x over previous
//
#include <hip/hip_runtime.h>
#include <hip/hip_bf16.h>
#include <math.h>

#define N_NODES 100000
#define N_EDGES 1600000
#define ORIG    92
#define NBR     41
#define ATOM    64
#define NCONV   3
#define HFEA    128
#define NGRAPH  256
#define ZD      169           // 2*ATOM + NBR
#define TBINS   5120
#define TMAX    10.0f
#define TS      ((TBINS + 1) * 64)   // per-layer table stride (uints)
#define SP      72                   // nodeP LDS row pad (shorts)
#define SPE     136                  // embed LDS row pad (shorts), K=128
#define NPBLK   128                  // bnstats partial blocks
#define LOG2E   1.4426950408889634f
#define LN2     0.6931471805599453f
#define NBKT    391                  // ceil(N_NODES / 256)
#define S1E     6250                 // edges per k_bhist block (256 blocks exact)
#define S3CH    4096                 // edges per k_psort1 block

typedef __attribute__((ext_vector_type(8))) short short8;
typedef __attribute__((ext_vector_type(4))) float f32x4;
typedef __attribute__((ext_vector_type(8))) int int8v;

__device__ __forceinline__ float softplus_f(float x) {
    return fmaxf(x, 0.0f) + log1pf(expf(-fabsf(x)));
}
// fast softplus via exp2/log2 HW ops
__device__ __forceinline__ float sp_fast2(float x) {
    float t = x * LOG2E;
    return LN2 * (fmaxf(t, 0.0f) +
                  __builtin_amdgcn_logf(1.0f + __builtin_amdgcn_exp2f(-fabsf(t))));
}
// pack 2 fp32 -> 2 bf16 in one uint (lo in low 16, hi in high 16)
__device__ __forceinline__ unsigned int pk_bf16(float lo, float hi) {
    unsigned int r;
    asm("v_cvt_pk_bf16_f32 %0, %1, %2" : "=v"(r) : "v"(lo), "v"(hi));
    return r;
}
__device__ __forceinline__ float bf_lo(unsigned int p) { return __uint_as_float(p << 16); }
__device__ __forceinline__ float bf_hi(unsigned int p) { return __uint_as_float(p & 0xffff0000u); }

__device__ __forceinline__ int lower_bound_i(const int* __restrict__ a, int n, int key) {
    int lo = 0, hi = n;
    while (lo < hi) {
        int mid = (lo + hi) >> 1;
        if (a[mid] < key) lo = mid + 1; else hi = mid;
    }
    return lo;
}

// ---------- sort pass 0: coarse bucket histogram + last-block scan ----------
__global__ __launch_bounds__(256) void k_bhist(const int* __restrict__ ei,
                                               int* __restrict__ bucketCnt,
                                               int* __restrict__ flag,
                                               int* __restrict__ bucketBase,
                                               int* __restrict__ bucketCursor,
                                               int* __restrict__ offs) {
    __shared__ int cntL[NBKT];
    __shared__ int lastFlag;
    int tid = threadIdx.x;
    for (int i = tid; i < NBKT; i += 256) cntL[i] = 0;
    __syncthreads();
    int base = blockIdx.x * S1E;
    for (int i = tid; i < S1E; i += 256)
        atomicAdd(&cntL[ei[N_EDGES + base + i] >> 8], 1);
    __syncthreads();
    for (int i = tid; i < NBKT; i += 256)
        if (cntL[i]) atomicAdd(&bucketCnt[i], cntL[i]);
    if (tid == 0) {
        __threadfence();
        lastFlag = (atomicAdd(flag, 1) == 255) ? 1 : 0;
    }
    __syncthreads();
    if (lastFlag && tid < 64) {
        __threadfence();
        int carry = 0;
        for (int b0 = 0; b0 < NBKT; b0 += 64) {
            int idx = b0 + tid;
            int v0 = (idx < NBKT) ? bucketCnt[idx] : 0;
            int v = v0;
            for (int d = 1; d < 64; d <<= 1) {
                int u = __shfl_up(v, d, 64);
                if (tid >= d) v += u;
            }
            if (idx < NBKT) {
                int ex = carry + v - v0;
                bucketBase[idx] = ex;
                bucketCursor[idx] = ex;
            }
            carry += __shfl(v, 63, 64);
        }
        if (tid == 0) {
            bucketBase[NBKT] = N_EDGES;
            offs[N_NODES] = N_EDGES;
        }
    }
}

// ---------- sort pass 1: bucket-binned staging, coalesced burst writes ----------
__global__ __launch_bounds__(256) void k_psort1(const int* __restrict__ ei,
                                                const float* __restrict__ ea,
                                                int* __restrict__ bucketCursor,
                                                int2* __restrict__ staging) {
    __shared__ int cntL[NBKT], scanB[NBKT], curL[NBKT], gbaseL[NBKT];
    __shared__ int sortedD[S3CH], sortedN[S3CH];
    int tid = threadIdx.x;
    int base = blockIdx.x * S3CH;
    int myCount = N_EDGES - base;
    if (myCount > S3CH) myCount = S3CH;
    for (int i = tid; i < NBKT; i += 256) { cntL[i] = 0; curL[i] = 0; }
    __syncthreads();
    int descr[16], dstr[16];
#pragma unroll
    for (int j = 0; j < 16; ++j) {
        int i = j * 256 + tid;
        descr[j] = 0; dstr[j] = -1;
        if (i < myCount) {
            int e = base + i;
            int src = ei[e];
            int dst = ei[N_EDGES + e];
            float a = ea[3 * e], bb = ea[3 * e + 1], c = ea[3 * e + 2];
            float d = sqrtf(a * a + bb * bb + c * c);
            int bin = (int)fminf(fmaf(d, (float)TBINS / TMAX, 0.5f), (float)TBINS);
            descr[j] = (bin << 17) | src;
            dstr[j] = dst;
            atomicAdd(&cntL[dst >> 8], 1);
        }
    }
    __syncthreads();
    if (tid < 64) {  // wave 0 exclusive-scans cntL
        int carry = 0;
        for (int b0 = 0; b0 < NBKT; b0 += 64) {
            int idx = b0 + tid;
            int v0 = (idx < NBKT) ? cntL[idx] : 0;
            int v = v0;
            for (int d = 1; d < 64; d <<= 1) {
                int u = __shfl_up(v, d, 64);
                if (tid >= d) v += u;
            }
            if (idx < NBKT) scanB[idx] = carry + v - v0;
            carry += __shfl(v, 63, 64);
        }
    }
    __syncthreads();
#pragma unroll
    for (int j = 0; j < 16; ++j) {
        if (dstr[j] >= 0) {
            int b = dstr[j] >> 8;
            int pos = scanB[b] + atomicAdd(&curL[b], 1);
            sortedD[pos] = descr[j];
            sortedN[pos] = dstr[j];
        }
    }
    for (int i = tid; i < NBKT; i += 256)
        if (cntL[i] > 0) gbaseL[i] = atomicAdd(&bucketCursor[i], cntL[i]);
    __syncthreads();
    for (int i = tid; i < myCount; i += 256) {
        int n = sortedN[i];
        int b = n >> 8;
        int2 pr; pr.x = sortedD[i]; pr.y = n;
        staging[gbaseL[b] + (i - scanB[b])] = pr;
    }
}

// ---------- sort pass 2: per-bucket exact sort + offs ----------
__global__ __launch_bounds__(256) void k_psort2(const int* __restrict__ bucketBase,
                                                const int2* __restrict__ staging,
                                                int* __restrict__ edesc,
                                                int* __restrict__ offs) {
    __shared__ int cnt[256], sbase[256], cur[256];
    int b = blockIdx.x, tid = threadIdx.x;
    int base = bucketBase[b];
    int nb = bucketBase[b + 1] - base;
    cnt[tid] = 0; cur[tid] = 0;
    __syncthreads();
    for (int i = tid; i < nb; i += 256)
        atomicAdd(&cnt[staging[base + i].y & 255], 1);
    __syncthreads();
    int v = cnt[tid];
    sbase[tid] = v;
    __syncthreads();
    for (int d = 1; d < 256; d <<= 1) {
        int u = (tid >= d) ? sbase[tid - d] : 0;
        __syncthreads();
        sbase[tid] += u;
        __syncthreads();
    }
    int ex = sbase[tid] - v;
    int dst = (b << 8) + tid;
    if (dst < N_NODES) offs[dst] = base + ex;
    sbase[tid] = ex;
    __syncthreads();
    for (int i = tid; i < nb; i += 256) {
        int2 pr = staging[base + i];
        int local = pr.y & 255;
        int pos = base + sbase[local] + atomicAdd(&cur[local], 1);
        edesc[pos] = pr.x;
    }
}

// T = R(d) @ W_e + bias (pre-scaled by log2e); tail blocks do weight prep
__global__ __launch_bounds__(256) void k_table2(const float* __restrict__ Wf,
                                                const float* __restrict__ bf,
                                                const float* __restrict__ Ws,
                                                const float* __restrict__ bs,
                                                const float* __restrict__ We,
                                                unsigned int* __restrict__ Tp,
                                                unsigned int* __restrict__ Bp,
                                                unsigned int* __restrict__ BpE) {
    int tid = threadIdx.x;
    int l = blockIdx.y;
    if (blockIdx.x == 161) {  // node-part weight prep for layer l
        int m = tid >> 6, c = tid & 63;
        const float* Wb = ((m & 2) ? Ws : Wf) + (size_t)l * ZD * ATOM + (m & 1) * ATOM * ATOM + c;
        unsigned int* dst = Bp + (size_t)l * 8192 + (size_t)tid * 32;
        for (int kp = 0; kp < 32; ++kp) {
            float w0 = Wb[(2 * kp) * ATOM] * LOG2E;
            float w1 = Wb[(2 * kp + 1) * ATOM] * LOG2E;
            dst[kp] = pk_bf16(w0, w1);
        }
        return;
    }
    if (blockIdx.x == 162) {  // embed weight prep (once)
        if (l != 0) return;
        int n = tid & 63, q = tid >> 6;
        for (int kp = q * 16; kp < q * 16 + 16; ++kp) {
            int k0 = 2 * kp, k1 = 2 * kp + 1;
            float w0 = (k0 < ORIG) ? We[k0 * ATOM + n] : 0.f;
            float w1 = (k1 < ORIG) ? We[k1 * ATOM + n] : 0.f;
            BpE[(size_t)n * 64 + kp] = pk_bf16(w0, w1);
        }
        return;
    }
    __shared__ float Wc[NBR * 64], Wsc[NBR * 64], R[32 * NBR];
    int b0 = blockIdx.x * 32;
    const float* srcf = Wf + (size_t)l * ZD * ATOM + 2 * ATOM * ATOM;
    const float* srcs = Ws + (size_t)l * ZD * ATOM + 2 * ATOM * ATOM;
    for (int i = tid; i < NBR * 64; i += 256) {
        Wc[i] = srcf[i] * LOG2E;
        Wsc[i] = srcs[i] * LOG2E;
    }
    for (int i = tid; i < 32 * NBR; i += 256) {
        int bin = i / NBR, k = i - bin * NBR;
        float d = (b0 + bin) * (TMAX / TBINS);
        float diff = d - 0.2f * k;
        R[i] = expf(-5.0f * diff * diff);
    }
    __syncthreads();
    int c = tid & 63;
    float afb = bf[l * ATOM + c] * LOG2E, asb = bs[l * ATOM + c] * LOG2E;
#pragma unroll
    for (int it = 0; it < 8; ++it) {
        int bin = (tid >> 6) + 4 * it;
        int gb = b0 + bin;
        if (gb <= TBINS) {
            float af = afb, as = asb;
            for (int k = 0; k < NBR; ++k) {
                float r = R[bin * NBR + k];
                af += r * Wc[k * 64 + c];
                as += r * Wsc[k * 64 + c];
            }
            Tp[(size_t)l * TS + (size_t)gb * 64 + c] = pk_bf16(af, as);
        }
    }
}

// fused: embed MFMA (K=128) -> h, then layer-0 projection MFMA -> Pi, Pj
__global__ __launch_bounds__(256) void k_embed_nodeP(const float* __restrict__ x,
                                                     const unsigned int* __restrict__ BpE,
                                                     const float* __restrict__ be,
                                                     const unsigned int* __restrict__ Bp,
                                                     float* __restrict__ h,
                                                     unsigned int* __restrict__ Pi,
                                                     unsigned int* __restrict__ Pj) {
    __shared__ char smem[46080];
    short* Ae = (short*)smem;              // [64][SPE]  0..17407
    short* Be = (short*)(smem + 17408);    // [64][SPE]  17408..34815
    short* Bn = (short*)smem;              // [256][SP]  aliases Ae/Be (after sync)
    short* An = (short*)(smem + 36864);    // [64][SP]   36864..46079
    int tid = threadIdx.x;
    int n0 = blockIdx.x * 64;
    for (int i = tid; i < 64 * 64; i += 256) {
        int r = i >> 6, kp = i & 63;
        int node = n0 + r;
        float2 v = make_float2(0.f, 0.f);
        if (node < N_NODES && kp < 46) v = ((const float2*)x)[(size_t)node * 46 + kp];
        *(unsigned int*)&Ae[r * SPE + kp * 2] = pk_bf16(v.x, v.y);
    }
    {
        const uint4* src = (const uint4*)BpE;
        for (int i = tid; i < 64 * 16; i += 256) {
            int row = i >> 4, q = i & 15;
            *(uint4*)&Be[row * SPE + q * 8] = src[i];
        }
    }
    __syncthreads();
    int lane = tid & 63, w = tid >> 6;
    int c15 = lane & 15, kb = lane >> 4;
    {
        short8 af[4];
#pragma unroll
        for (int s = 0; s < 4; ++s)
            af[s] = *(const short8*)&Ae[(16 * w + c15) * SPE + s * 32 + kb * 8];
        f32x4 acc[4];
#pragma unroll
        for (int t = 0; t < 4; ++t) acc[t] = (f32x4){0.f, 0.f, 0.f, 0.f};
#pragma unroll
        for (int t = 0; t < 4; ++t) {
#pragma unroll
            for (int s = 0; s < 4; ++s) {
                short8 bf8 = *(const short8*)&Be[(16 * t + c15) * SPE + s * 32 + kb * 8];
                acc[t] = __builtin_amdgcn_mfma_f32_16x16x32_bf16(af[s], bf8, acc[t], 0, 0, 0);
            }
        }
#pragma unroll
        for (int t = 0; t < 4; ++t) {
            float bias = be[16 * t + c15];
#pragma unroll
            for (int reg = 0; reg < 4; ++reg) {
                int row = 16 * w + kb * 4 + reg;
                int node = n0 + row;
                float v = acc[t][reg] + bias;
                if (node < N_NODES) h[(size_t)node * 64 + 16 * t + c15] = v;
                An[row * SP + 16 * t + c15] = (short)pk_bf16(v, v);
            }
        }
    }
    __syncthreads();   // all embed-LDS reads done; An written
    {
        const uint4* src = (const uint4*)Bp;   // layer 0
        for (int i = tid; i < 2048; i += 256) {
            int row = i >> 3, j = i & 7;
            *(uint4*)&Bn[row * SP + j * 8] = src[row * 8 + j];
        }
    }
    __syncthreads();
    short8 af2[2];
#pragma unroll
    for (int s = 0; s < 2; ++s)
        af2[s] = *(const short8*)&An[(16 * w + c15) * SP + s * 32 + kb * 8];
    f32x4 acc2[16];
#pragma unroll
    for (int t = 0; t < 16; ++t) acc2[t] = (f32x4){0.f, 0.f, 0.f, 0.f};
#pragma unroll
    for (int t = 0; t < 16; ++t) {
#pragma unroll
        for (int s = 0; s < 2; ++s) {
            short8 bf8 = *(const short8*)&Bn[(16 * t + c15) * SP + s * 32 + kb * 8];
            acc2[t] = __builtin_amdgcn_mfma_f32_16x16x32_bf16(af2[s], bf8, acc2[t], 0, 0, 0);
        }
    }
#pragma unroll
    for (int t = 0; t < 4; ++t) {
#pragma unroll
        for (int reg = 0; reg < 4; ++reg) {
            int row = kb * 4 + reg;
            int node = n0 + 16 * w + row;
            if (node < N_NODES) {
                Pi[(size_t)node * 64 + 16 * t + c15] = pk_bf16(acc2[t][reg], acc2[t + 8][reg]);
                Pj[(size_t)node * 64 + 16 * t + c15] = pk_bf16(acc2[t + 4][reg], acc2[t + 12][reg]);
            }
        }
    }
}

// fused: BN+residual update of h, then MFMA projection -> Pi, Pj (layers 1,2)
__global__ __launch_bounds__(256) void k_nodeP_mfma(float* __restrict__ h,
                                                    const float* __restrict__ agg,
                                                    const float* __restrict__ ss,
                                                    const unsigned int* __restrict__ Bp,
                                                    int l,
                                                    unsigned int* __restrict__ Pi,
                                                    unsigned int* __restrict__ Pj) {
    __shared__ short A[64 * SP];
    __shared__ short B[256 * SP];
    int tid = threadIdx.x;
    int n0 = blockIdx.x * 64;
    for (int i = tid; i < 64 * 32; i += 256) {
        int r = i >> 5, kp = i & 31;
        int node = n0 + r;
        int gi = node * 32 + kp;
        float2 hv = make_float2(0.f, 0.f);
        if (node < N_NODES) {
            hv = ((const float2*)h)[gi];
            float2 av = ((const float2*)agg)[gi];
            int c = kp * 2;
            float x0 = ss[c] * av.x + ss[64 + c] + hv.x;
            float x1 = ss[c + 1] * av.y + ss[64 + c + 1] + hv.y;
            hv.x = sp_fast2(x0);
            hv.y = sp_fast2(x1);
            ((float2*)h)[gi] = hv;
        }
        *(unsigned int*)&A[r * SP + kp * 2] = pk_bf16(hv.x, hv.y);
    }
    {
        const uint4* src = (const uint4*)(Bp + (size_t)l * 8192);
        for (int i = tid; i < 2048; i += 256) {
            int row = i >> 3, j = i & 7;
            *(uint4*)&B[row * SP + j * 8] = src[row * 8 + j];
        }
    }
    __syncthreads();
    int lane = tid & 63, w = tid >> 6;
    int c15 = lane & 15, kb = lane >> 4;
    short8 af[2];
#pragma unroll
    for (int s = 0; s < 2; ++s)
        af[s] = *(const short8*)&A[(16 * w + c15) * SP + s * 32 + kb * 8];
    f32x4 acc[16];
#pragma unroll
    for (int t = 0; t < 16; ++t) acc[t] = (f32x4){0.f, 0.f, 0.f, 0.f};
#pragma unroll
    for (int t = 0; t < 16; ++t) {
#pragma unroll
        for (int s = 0; s < 2; ++s) {
            short8 bf8 = *(const short8*)&B[(16 * t + c15) * SP + s * 32 + kb * 8];
            acc[t] = __builtin_amdgcn_mfma_f32_16x16x32_bf16(af[s], bf8, acc[t], 0, 0, 0);
        }
    }
#pragma unroll
    for (int t = 0; t < 4; ++t) {
#pragma unroll
        for (int reg = 0; reg < 4; ++reg) {
            int row = kb * 4 + reg;
            int node = n0 + 16 * w + row;
            if (node < N_NODES) {
                Pi[(size_t)node * 64 + 16 * t + c15] = pk_bf16(acc[t][reg], acc[t + 8][reg]);
                Pj[(size_t)node * 64 + 16 * t + c15] = pk_bf16(acc[t + 4][reg], acc[t + 12][reg]);
            }
        }
    }
}

// one wave per node; packed scalar descriptors, saddr gathers, exp2-domain math
__global__ __launch_bounds__(256, 4) void k_edge_sorted(const int* __restrict__ offs,
                                                        const int* __restrict__ edesc,
                                                        const unsigned int* __restrict__ Pi,
                                                        const unsigned int* __restrict__ Pj,
                                                        const unsigned int* __restrict__ Tp,
                                                        float* __restrict__ agg) {
    int wid = (blockIdx.x * 256 + threadIdx.x) >> 6;
    int lane = threadIdx.x & 63;
    if (wid >= N_NODES) return;
    int uwid = __builtin_amdgcn_readfirstlane(wid);
    int2 kk;
    asm volatile("s_load_dwordx2 %0, %1, 0x0\n\ts_waitcnt lgkmcnt(0)"
                 : "=s"(kk) : "s"(offs + uwid));
    int ko = kk.x, ke = kk.y;
    unsigned int pi = Pi[(size_t)uwid * 64 + lane];
    float gi = bf_lo(pi), ci = bf_hi(pi);
    float acc = 0.0f;
    int lane4 = lane * 4;
    const char* PjB = (const char*)Pj;
    const char* TpB = (const char*)Tp;
    int k0 = ko;
    for (; k0 + 16 <= ke; k0 += 16) {
        int8v e0, e1;
        asm volatile(
            "s_load_dwordx8 %0, %2, 0x0\n\t"
            "s_load_dwordx8 %1, %2, 0x20\n\t"
            "s_waitcnt lgkmcnt(0)"
            : "=&s"(e0), "=&s"(e1)
            : "s"(edesc + k0));
        unsigned int pjv[16], tjv[16];
#pragma unroll
        for (int j = 0; j < 16; ++j) {
            int v = (j < 8) ? e0[j & 7] : e1[j & 7];
            int sb = (v & 0x1FFFF) << 8;
            int tb = (v >> 17) << 8;
            pjv[j] = *(const unsigned int*)(PjB + sb + lane4);
            tjv[j] = *(const unsigned int*)(TpB + tb + lane4);
        }
#pragma unroll
        for (int j = 0; j < 16; ++j) {
            float g = gi + bf_lo(pjv[j]) + bf_lo(tjv[j]);
            float c = ci + bf_hi(pjv[j]) + bf_hi(tjv[j]);
            float sg = __builtin_amdgcn_rcpf(1.0f + __builtin_amdgcn_exp2f(-g));
            float sp = fmaxf(c, 0.0f) + __builtin_amdgcn_logf(1.0f + __builtin_amdgcn_exp2f(-fabsf(c)));
            acc = fmaf(sg, sp, acc);
        }
    }
    if (k0 < ke) {
        int8v e0, e1;
        asm volatile(
            "s_load_dwordx8 %0, %2, 0x0\n\t"
            "s_load_dwordx8 %1, %2, 0x20\n\t"
            "s_waitcnt lgkmcnt(0)"
            : "=&s"(e0), "=&s"(e1)
            : "s"(edesc + k0));
        unsigned int pjv[16], tjv[16];
#pragma unroll
        for (int j = 0; j < 16; ++j) {
            if (k0 + j < ke) {
                int v = (j < 8) ? e0[j & 7] : e1[j & 7];
                int sb = (v & 0x1FFFF) << 8;
                int tb = (v >> 17) << 8;
                pjv[j] = *(const unsigned int*)(PjB + sb + lane4);
                tjv[j] = *(const unsigned int*)(TpB + tb + lane4);
            }
        }
#pragma unroll
        for (int j = 0; j < 16; ++j) {
            if (k0 + j < ke) {
                float g = gi + bf_lo(pjv[j]) + bf_lo(tjv[j]);
                float c = ci + bf_hi(pjv[j]) + bf_hi(tjv[j]);
                float sg = __builtin_amdgcn_rcpf(1.0f + __builtin_amdgcn_exp2f(-g));
                float sp = fmaxf(c, 0.0f) + __builtin_amdgcn_logf(1.0f + __builtin_amdgcn_exp2f(-fabsf(c)));
                acc = fmaf(sg, sp, acc);
            }
        }
    }
    agg[(size_t)uwid * 64 + lane] = acc * LN2;
}

// bnstats + bnfinal merged via last-block pattern; float4 reads
__global__ __launch_bounds__(256) void k_bnstats2(const float* __restrict__ agg,
                                                  float* __restrict__ partial,
                                                  int* __restrict__ lcnt,
                                                  const float* __restrict__ gamma,
                                                  const float* __restrict__ beta,
                                                  int l, float* __restrict__ ss) {
    __shared__ f32x4 ls4[256], ls24[256];
    __shared__ float ls[128];
    __shared__ int lastFlag;
    int tid = threadIdx.x;
    const f32x4* agg4 = (const f32x4*)agg;
    f32x4 s = (f32x4){0.f, 0.f, 0.f, 0.f};
    f32x4 s2 = (f32x4){0.f, 0.f, 0.f, 0.f};
    for (int i = blockIdx.x * 256 + tid; i < N_NODES * 16; i += NPBLK * 256) {
        f32x4 v = agg4[i];
        s += v;
        s2 += v * v;
    }
    ls4[tid] = s; ls24[tid] = s2;
    __syncthreads();
    // reduce the 16 threads sharing each col-group (tid & 15 invariant under +16k)
    for (int d = 128; d >= 16; d >>= 1) {
        if (tid < d) { ls4[tid] += ls4[tid + d]; ls24[tid] += ls24[tid + d]; }
        __syncthreads();
    }
    if (tid < 16) {
#pragma unroll
        for (int j = 0; j < 4; ++j) {
            partial[blockIdx.x * 128 + tid * 4 + j] = ls4[tid][j];
            partial[blockIdx.x * 128 + 64 + tid * 4 + j] = ls24[tid][j];
        }
    }
    __syncthreads();
    if (tid == 0) {
        __threadfence();
        lastFlag = (atomicAdd(lcnt, 1) == NPBLK - 1) ? 1 : 0;
    }
    __syncthreads();
    if (lastFlag) {
        __threadfence();
        if (tid < 128) {
            float sum = 0.0f;
            for (int b = 0; b < NPBLK; ++b) sum += partial[b * 128 + tid];
            ls[tid] = sum;
        }
        __syncthreads();
        if (tid < 64) {
            const float inv = 1.0f / (float)N_NODES;
            float mu = ls[tid] * inv;
            float var = ls[64 + tid] * inv - mu * mu;
            float sc = gamma[l * ATOM + tid] * rsqrtf(var + 1e-5f);
            ss[tid] = sc;
            ss[64 + tid] = beta[l * ATOM + tid] - mu * sc;
        }
    }
}

// fused final update + pool + MLP head; one block per graph, batch sorted
__global__ __launch_bounds__(128) void k_head2(const float* __restrict__ agg,
                                               const float* __restrict__ ss,
                                               const float* __restrict__ h,
                                               const int* __restrict__ batch,
                                               const float* __restrict__ W1,
                                               const float* __restrict__ b1,
                                               const float* __restrict__ W2,
                                               const float* __restrict__ b2,
                                               float* __restrict__ out) {
    __shared__ float gvec[64];
    __shared__ float red[128];
    int gid = blockIdx.x, tid = threadIdx.x;
    int lo = lower_bound_i(batch, N_NODES, gid);
    int hi = lower_bound_i(batch, N_NODES, gid + 1);
    int c = tid & 63, half = tid >> 6;
    float sc = ss[c], sh = ss[64 + c];
    float acc = 0.0f;
    for (int n = lo + half; n < hi; n += 2) {
        float xv = sc * agg[(size_t)n * 64 + c] + sh + h[(size_t)n * 64 + c];
        acc += sp_fast2(xv);
    }
    red[tid] = acc;
    __syncthreads();
    if (tid < 64) gvec[tid] = red[tid] + red[tid + 64];
    __syncthreads();
    float a2 = b1[tid];
    for (int k = 0; k < ATOM; ++k) a2 += gvec[k] * W1[k * HFEA + tid];
    red[tid] = softplus_f(a2) * W2[tid];
    __syncthreads();
    for (int s = 64; s > 0; s >>= 1) {
        if (tid < s) red[tid] += red[tid + s];
        __syncthreads();
    }
    if (tid == 0) out[gid] = red[0] + b2[0];
}

extern "C" void kernel_launch(void* const* d_in, const int* in_sizes, int n_in,
                              void* d_out, int out_size, void* d_ws, size_t ws_size,
                              hipStream_t stream) {
    const float* x       = (const float*)d_in[0];
    const float* ea      = (const float*)d_in[1];
    const float* W_emb   = (const float*)d_in[2];
    const float* b_emb   = (const float*)d_in[3];
    const float* Wf      = (const float*)d_in[4];
    const float* bf      = (const float*)d_in[5];
    const float* Ws      = (const float*)d_in[6];
    const float* bs      = (const float*)d_in[7];
    const float* bn_g    = (const float*)d_in[8];
    const float* bn_b    = (const float*)d_in[9];
    const float* W1      = (const float*)d_in[10];
    const float* b1      = (const float*)d_in[11];
    const float* W2      = (const float*)d_in[12];
    const float* b2      = (const float*)d_in[13];
    const int*   ei      = (const int*)d_in[14];
    const int*   batch   = (const int*)d_in[15];
    float* out = (float*)d_out;

    char* wsb = (char*)d_ws;
    size_t off = 0;
    auto alloc = [&](size_t bytes) { char* p = wsb + off; off += (bytes + 255) & ~(size_t)255; return p; };
    float*        h        = (float*)alloc((size_t)N_NODES * 64 * 4);
    float*        agg      = (float*)alloc((size_t)N_NODES * 64 * 4);
    unsigned int* Pi       = (unsigned int*)alloc((size_t)N_NODES * 64 * 4);
    unsigned int* Pj       = (unsigned int*)alloc((size_t)N_NODES * 64 * 4);
    int*          edesc    = (int*)alloc((size_t)(N_EDGES + 16) * 4);
    int2*         staging  = (int2*)alloc((size_t)N_EDGES * 8);
    int*          meta     = (int*)alloc(1024 * 4);   // [0..511] bucketCnt, [512..] lcnt/flags
    int*          bucketCnt    = meta;
    int*          lcnt         = meta + 512;          // [0..2] bn layers, [3] bhist flag
    int*          bucketBase   = (int*)alloc(520 * 4);
    int*          bucketCursor = (int*)alloc(512 * 4);
    int*          offs     = (int*)alloc((size_t)(N_NODES + 1) * 4);
    unsigned int* Tp       = (unsigned int*)alloc((size_t)NCONV * TS * 4);
    unsigned int* Bp       = (unsigned int*)alloc((size_t)NCONV * 8192 * 4);
    unsigned int* BpE      = (unsigned int*)alloc((size_t)64 * 64 * 4);
    float*        partial  = (float*)alloc((size_t)NPBLK * 128 * 4);
    float*        ss       = (float*)alloc(128 * 4);

    (void)hipMemsetAsync(meta, 0, 1024 * 4, stream);
    k_bhist<<<256, 256, 0, stream>>>(ei, bucketCnt, lcnt + 3, bucketBase, bucketCursor, offs);
    k_psort1<<<(N_EDGES + S3CH - 1) / S3CH, 256, 0, stream>>>(ei, ea, bucketCursor, staging);
    k_psort2<<<NBKT, 256, 0, stream>>>(bucketBase, staging, edesc, offs);

    dim3 tg(163, NCONV);
    k_table2<<<tg, 256, 0, stream>>>(Wf, bf, Ws, bs, W_emb, Tp, Bp, BpE);
    k_embed_nodeP<<<(N_NODES + 63) / 64, 256, 0, stream>>>(x, BpE, b_emb, Bp, h, Pi, Pj);

    for (int l = 0; l < NCONV; ++l) {
        if (l > 0)
            k_nodeP_mfma<<<(N_NODES + 63) / 64, 256, 0, stream>>>(h, agg, ss, Bp, l, Pi, Pj);
        k_edge_sorted<<<(N_NODES * 64 + 255) / 256, 256, 0, stream>>>(
            offs, edesc, Pi, Pj, Tp + (size_t)l * TS, agg);
        k_bnstats2<<<NPBLK, 256, 0, stream>>>(agg, partial, lcnt + l, bn_g, bn_b, l, ss);
    }

    k_head2<<<NGRAPH, 128, 0, stream>>>(agg, ss, h, batch, W1, b1, W2, b2, out);
}

// Round 14
// 445.402 us; speedup vs baseline: 4.6594x; 1.1260x over previous
//
#include <hip/hip_runtime.h>
#include <hip/hip_bf16.h>
#include <math.h>

#define N_NODES 100000
#define N_EDGES 1600000
#define ORIG    92
#define NBR     41
#define ATOM    64
#define NCONV   3
#define HFEA    128
#define NGRAPH  256
#define ZD      169           // 2*ATOM + NBR
#define TBINS   5120
#define TMAX    10.0f
#define TS      ((TBINS + 1) * 64)   // per-layer table stride (uints)
#define SP      72                   // nodeP LDS row pad (shorts)
#define SPE     136                  // embed LDS row pad (shorts), K=128
#define NPBLK   128                  // bnstats partial blocks
#define LOG2E   1.4426950408889634f
#define LN2     0.6931471805599453f
#define NBKT    391                  // ceil(N_NODES / 256)
#define S1E     6250                 // edges per k_bhist block (256 blocks exact)
#define S3CH    4096                 // edges per k_psort1 block

typedef __attribute__((ext_vector_type(8))) short short8;
typedef __attribute__((ext_vector_type(4))) float f32x4;
typedef __attribute__((ext_vector_type(8))) int int8v;

__device__ __forceinline__ float softplus_f(float x) {
    return fmaxf(x, 0.0f) + log1pf(expf(-fabsf(x)));
}
// fast softplus via exp2/log2 HW ops
__device__ __forceinline__ float sp_fast2(float x) {
    float t = x * LOG2E;
    return LN2 * (fmaxf(t, 0.0f) +
                  __builtin_amdgcn_logf(1.0f + __builtin_amdgcn_exp2f(-fabsf(t))));
}
// pack 2 fp32 -> 2 bf16 in one uint (lo in low 16, hi in high 16)
__device__ __forceinline__ unsigned int pk_bf16(float lo, float hi) {
    unsigned int r;
    asm("v_cvt_pk_bf16_f32 %0, %1, %2" : "=v"(r) : "v"(lo), "v"(hi));
    return r;
}
__device__ __forceinline__ float bf_lo(unsigned int p) { return __uint_as_float(p << 16); }
__device__ __forceinline__ float bf_hi(unsigned int p) { return __uint_as_float(p & 0xffff0000u); }

// ---------- sort pass 0: coarse bucket histogram + last-block scan ----------
__global__ __launch_bounds__(256) void k_bhist(const int* __restrict__ ei,
                                               int* __restrict__ bucketCnt,
                                               int* __restrict__ flag,
                                               int* __restrict__ bucketBase,
                                               int* __restrict__ bucketCursor,
                                               int* __restrict__ offs) {
    __shared__ int cntL[NBKT];
    __shared__ int lastFlag;
    int tid = threadIdx.x;
    for (int i = tid; i < NBKT; i += 256) cntL[i] = 0;
    __syncthreads();
    int base = blockIdx.x * S1E;
    for (int i = tid; i < S1E; i += 256)
        atomicAdd(&cntL[ei[N_EDGES + base + i] >> 8], 1);
    __syncthreads();
    for (int i = tid; i < NBKT; i += 256)
        if (cntL[i]) atomicAdd(&bucketCnt[i], cntL[i]);
    if (tid == 0) {
        __threadfence();
        lastFlag = (atomicAdd(flag, 1) == 255) ? 1 : 0;
    }
    __syncthreads();
    if (lastFlag && tid < 64) {
        __threadfence();
        int carry = 0;
        for (int b0 = 0; b0 < NBKT; b0 += 64) {
            int idx = b0 + tid;
            int v0 = (idx < NBKT) ? bucketCnt[idx] : 0;
            int v = v0;
            for (int d = 1; d < 64; d <<= 1) {
                int u = __shfl_up(v, d, 64);
                if (tid >= d) v += u;
            }
            if (idx < NBKT) {
                int ex = carry + v - v0;
                bucketBase[idx] = ex;
                bucketCursor[idx] = ex;
            }
            carry += __shfl(v, 63, 64);
        }
        if (tid == 0) {
            bucketBase[NBKT] = N_EDGES;
            offs[N_NODES] = N_EDGES;
        }
    }
}

// ---------- sort pass 1: bucket-binned staging, coalesced burst writes ----------
__global__ __launch_bounds__(256) void k_psort1(const int* __restrict__ ei,
                                                const float* __restrict__ ea,
                                                int* __restrict__ bucketCursor,
                                                int2* __restrict__ staging) {
    __shared__ int cntL[NBKT], scanB[NBKT], curL[NBKT], gbaseL[NBKT];
    __shared__ int sortedD[S3CH], sortedN[S3CH];
    int tid = threadIdx.x;
    int base = blockIdx.x * S3CH;
    int myCount = N_EDGES - base;
    if (myCount > S3CH) myCount = S3CH;
    for (int i = tid; i < NBKT; i += 256) { cntL[i] = 0; curL[i] = 0; }
    __syncthreads();
    int descr[16], dstr[16];
#pragma unroll
    for (int j = 0; j < 16; ++j) {
        int i = j * 256 + tid;
        descr[j] = 0; dstr[j] = -1;
        if (i < myCount) {
            int e = base + i;
            int src = ei[e];
            int dst = ei[N_EDGES + e];
            float a = ea[3 * e], bb = ea[3 * e + 1], c = ea[3 * e + 2];
            float d = sqrtf(a * a + bb * bb + c * c);
            int bin = (int)fminf(fmaf(d, (float)TBINS / TMAX, 0.5f), (float)TBINS);
            descr[j] = (bin << 17) | src;
            dstr[j] = dst;
            atomicAdd(&cntL[dst >> 8], 1);
        }
    }
    __syncthreads();
    if (tid < 64) {  // wave 0 exclusive-scans cntL
        int carry = 0;
        for (int b0 = 0; b0 < NBKT; b0 += 64) {
            int idx = b0 + tid;
            int v0 = (idx < NBKT) ? cntL[idx] : 0;
            int v = v0;
            for (int d = 1; d < 64; d <<= 1) {
                int u = __shfl_up(v, d, 64);
                if (tid >= d) v += u;
            }
            if (idx < NBKT) scanB[idx] = carry + v - v0;
            carry += __shfl(v, 63, 64);
        }
    }
    __syncthreads();
#pragma unroll
    for (int j = 0; j < 16; ++j) {
        if (dstr[j] >= 0) {
            int b = dstr[j] >> 8;
            int pos = scanB[b] + atomicAdd(&curL[b], 1);
            sortedD[pos] = descr[j];
            sortedN[pos] = dstr[j];
        }
    }
    for (int i = tid; i < NBKT; i += 256)
        if (cntL[i] > 0) gbaseL[i] = atomicAdd(&bucketCursor[i], cntL[i]);
    __syncthreads();
    for (int i = tid; i < myCount; i += 256) {
        int n = sortedN[i];
        int b = n >> 8;
        int2 pr; pr.x = sortedD[i]; pr.y = n;
        staging[gbaseL[b] + (i - scanB[b])] = pr;
    }
}

// ---------- sort pass 2: per-bucket exact sort + offs ----------
__global__ __launch_bounds__(256) void k_psort2(const int* __restrict__ bucketBase,
                                                const int2* __restrict__ staging,
                                                int* __restrict__ edesc,
                                                int* __restrict__ offs) {
    __shared__ int cnt[256], sbase[256], cur[256];
    int b = blockIdx.x, tid = threadIdx.x;
    int base = bucketBase[b];
    int nb = bucketBase[b + 1] - base;
    cnt[tid] = 0; cur[tid] = 0;
    __syncthreads();
    for (int i = tid; i < nb; i += 256)
        atomicAdd(&cnt[staging[base + i].y & 255], 1);
    __syncthreads();
    int v = cnt[tid];
    sbase[tid] = v;
    __syncthreads();
    for (int d = 1; d < 256; d <<= 1) {
        int u = (tid >= d) ? sbase[tid - d] : 0;
        __syncthreads();
        sbase[tid] += u;
        __syncthreads();
    }
    int ex = sbase[tid] - v;
    int dst = (b << 8) + tid;
    if (dst < N_NODES) offs[dst] = base + ex;
    sbase[tid] = ex;
    __syncthreads();
    for (int i = tid; i < nb; i += 256) {
        int2 pr = staging[base + i];
        int local = pr.y & 255;
        int pos = base + sbase[local] + atomicAdd(&cur[local], 1);
        edesc[pos] = pr.x;
    }
}

// T = R(d) @ W_e + bias (pre-scaled by log2e); tail blocks do weight prep
__global__ __launch_bounds__(256) void k_table2(const float* __restrict__ Wf,
                                                const float* __restrict__ bf,
                                                const float* __restrict__ Ws,
                                                const float* __restrict__ bs,
                                                const float* __restrict__ We,
                                                unsigned int* __restrict__ Tp,
                                                unsigned int* __restrict__ Bp,
                                                unsigned int* __restrict__ BpE) {
    int tid = threadIdx.x;
    int l = blockIdx.y;
    if (blockIdx.x == 161) {  // node-part weight prep for layer l
        int m = tid >> 6, c = tid & 63;
        const float* Wb = ((m & 2) ? Ws : Wf) + (size_t)l * ZD * ATOM + (m & 1) * ATOM * ATOM + c;
        unsigned int* dst = Bp + (size_t)l * 8192 + (size_t)tid * 32;
        for (int kp = 0; kp < 32; ++kp) {
            float w0 = Wb[(2 * kp) * ATOM] * LOG2E;
            float w1 = Wb[(2 * kp + 1) * ATOM] * LOG2E;
            dst[kp] = pk_bf16(w0, w1);
        }
        return;
    }
    if (blockIdx.x == 162) {  // embed weight prep (once)
        if (l != 0) return;
        int n = tid & 63, q = tid >> 6;
        for (int kp = q * 16; kp < q * 16 + 16; ++kp) {
            int k0 = 2 * kp, k1 = 2 * kp + 1;
            float w0 = (k0 < ORIG) ? We[k0 * ATOM + n] : 0.f;
            float w1 = (k1 < ORIG) ? We[k1 * ATOM + n] : 0.f;
            BpE[(size_t)n * 64 + kp] = pk_bf16(w0, w1);
        }
        return;
    }
    __shared__ float Wc[NBR * 64], Wsc[NBR * 64], R[32 * NBR];
    int b0 = blockIdx.x * 32;
    const float* srcf = Wf + (size_t)l * ZD * ATOM + 2 * ATOM * ATOM;
    const float* srcs = Ws + (size_t)l * ZD * ATOM + 2 * ATOM * ATOM;
    for (int i = tid; i < NBR * 64; i += 256) {
        Wc[i] = srcf[i] * LOG2E;
        Wsc[i] = srcs[i] * LOG2E;
    }
    for (int i = tid; i < 32 * NBR; i += 256) {
        int bin = i / NBR, k = i - bin * NBR;
        float d = (b0 + bin) * (TMAX / TBINS);
        float diff = d - 0.2f * k;
        R[i] = expf(-5.0f * diff * diff);
    }
    __syncthreads();
    int c = tid & 63;
    float afb = bf[l * ATOM + c] * LOG2E, asb = bs[l * ATOM + c] * LOG2E;
#pragma unroll
    for (int it = 0; it < 8; ++it) {
        int bin = (tid >> 6) + 4 * it;
        int gb = b0 + bin;
        if (gb <= TBINS) {
            float af = afb, as = asb;
            for (int k = 0; k < NBR; ++k) {
                float r = R[bin * NBR + k];
                af += r * Wc[k * 64 + c];
                as += r * Wsc[k * 64 + c];
            }
            Tp[(size_t)l * TS + (size_t)gb * 64 + c] = pk_bf16(af, as);
        }
    }
}

// fused: embed MFMA (K=128) -> h, then layer-0 projection MFMA -> Pi, Pj
__global__ __launch_bounds__(256) void k_embed_nodeP(const float* __restrict__ x,
                                                     const unsigned int* __restrict__ BpE,
                                                     const float* __restrict__ be,
                                                     const unsigned int* __restrict__ Bp,
                                                     float* __restrict__ h,
                                                     unsigned int* __restrict__ Pi,
                                                     unsigned int* __restrict__ Pj) {
    __shared__ char smem[46080];
    short* Ae = (short*)smem;              // [64][SPE]  0..17407
    short* Be = (short*)(smem + 17408);    // [64][SPE]  17408..34815
    short* Bn = (short*)smem;              // [256][SP]  aliases Ae/Be (after sync)
    short* An = (short*)(smem + 36864);    // [64][SP]   36864..46079
    int tid = threadIdx.x;
    int n0 = blockIdx.x * 64;
    for (int i = tid; i < 64 * 64; i += 256) {
        int r = i >> 6, kp = i & 63;
        int node = n0 + r;
        float2 v = make_float2(0.f, 0.f);
        if (node < N_NODES && kp < 46) v = ((const float2*)x)[(size_t)node * 46 + kp];
        *(unsigned int*)&Ae[r * SPE + kp * 2] = pk_bf16(v.x, v.y);
    }
    {
        const uint4* src = (const uint4*)BpE;
        for (int i = tid; i < 64 * 16; i += 256) {
            int row = i >> 4, q = i & 15;
            *(uint4*)&Be[row * SPE + q * 8] = src[i];
        }
    }
    __syncthreads();
    int lane = tid & 63, w = tid >> 6;
    int c15 = lane & 15, kb = lane >> 4;
    {
        short8 af[4];
#pragma unroll
        for (int s = 0; s < 4; ++s)
            af[s] = *(const short8*)&Ae[(16 * w + c15) * SPE + s * 32 + kb * 8];
        f32x4 acc[4];
#pragma unroll
        for (int t = 0; t < 4; ++t) acc[t] = (f32x4){0.f, 0.f, 0.f, 0.f};
#pragma unroll
        for (int t = 0; t < 4; ++t) {
#pragma unroll
            for (int s = 0; s < 4; ++s) {
                short8 bf8 = *(const short8*)&Be[(16 * t + c15) * SPE + s * 32 + kb * 8];
                acc[t] = __builtin_amdgcn_mfma_f32_16x16x32_bf16(af[s], bf8, acc[t], 0, 0, 0);
            }
        }
#pragma unroll
        for (int t = 0; t < 4; ++t) {
            float bias = be[16 * t + c15];
#pragma unroll
            for (int reg = 0; reg < 4; ++reg) {
                int row = 16 * w + kb * 4 + reg;
                int node = n0 + row;
                float v = acc[t][reg] + bias;
                if (node < N_NODES) h[(size_t)node * 64 + 16 * t + c15] = v;
                An[row * SP + 16 * t + c15] = (short)pk_bf16(v, v);
            }
        }
    }
    __syncthreads();   // all embed-LDS reads done; An written
    {
        const uint4* src = (const uint4*)Bp;   // layer 0
        for (int i = tid; i < 2048; i += 256) {
            int row = i >> 3, j = i & 7;
            *(uint4*)&Bn[row * SP + j * 8] = src[row * 8 + j];
        }
    }
    __syncthreads();
    short8 af2[2];
#pragma unroll
    for (int s = 0; s < 2; ++s)
        af2[s] = *(const short8*)&An[(16 * w + c15) * SP + s * 32 + kb * 8];
    f32x4 acc2[16];
#pragma unroll
    for (int t = 0; t < 16; ++t) acc2[t] = (f32x4){0.f, 0.f, 0.f, 0.f};
#pragma unroll
    for (int t = 0; t < 16; ++t) {
#pragma unroll
        for (int s = 0; s < 2; ++s) {
            short8 bf8 = *(const short8*)&Bn[(16 * t + c15) * SP + s * 32 + kb * 8];
            acc2[t] = __builtin_amdgcn_mfma_f32_16x16x32_bf16(af2[s], bf8, acc2[t], 0, 0, 0);
        }
    }
#pragma unroll
    for (int t = 0; t < 4; ++t) {
#pragma unroll
        for (int reg = 0; reg < 4; ++reg) {
            int row = kb * 4 + reg;
            int node = n0 + 16 * w + row;
            if (node < N_NODES) {
                Pi[(size_t)node * 64 + 16 * t + c15] = pk_bf16(acc2[t][reg], acc2[t + 8][reg]);
                Pj[(size_t)node * 64 + 16 * t + c15] = pk_bf16(acc2[t + 4][reg], acc2[t + 12][reg]);
            }
        }
    }
}

// fused: BN+residual update of h, then MFMA projection -> Pi, Pj (layers 1,2)
__global__ __launch_bounds__(256) void k_nodeP_mfma(float* __restrict__ h,
                                                    const float* __restrict__ agg,
                                                    const float* __restrict__ ss,
                                                    const unsigned int* __restrict__ Bp,
                                                    int l,
                                                    unsigned int* __restrict__ Pi,
                                                    unsigned int* __restrict__ Pj) {
    __shared__ short A[64 * SP];
    __shared__ short B[256 * SP];
    int tid = threadIdx.x;
    int n0 = blockIdx.x * 64;
    for (int i = tid; i < 64 * 32; i += 256) {
        int r = i >> 5, kp = i & 31;
        int node = n0 + r;
        int gi = node * 32 + kp;
        float2 hv = make_float2(0.f, 0.f);
        if (node < N_NODES) {
            hv = ((const float2*)h)[gi];
            float2 av = ((const float2*)agg)[gi];
            int c = kp * 2;
            float x0 = ss[c] * av.x + ss[64 + c] + hv.x;
            float x1 = ss[c + 1] * av.y + ss[64 + c + 1] + hv.y;
            hv.x = sp_fast2(x0);
            hv.y = sp_fast2(x1);
            ((float2*)h)[gi] = hv;
        }
        *(unsigned int*)&A[r * SP + kp * 2] = pk_bf16(hv.x, hv.y);
    }
    {
        const uint4* src = (const uint4*)(Bp + (size_t)l * 8192);
        for (int i = tid; i < 2048; i += 256) {
            int row = i >> 3, j = i & 7;
            *(uint4*)&B[row * SP + j * 8] = src[row * 8 + j];
        }
    }
    __syncthreads();
    int lane = tid & 63, w = tid >> 6;
    int c15 = lane & 15, kb = lane >> 4;
    short8 af[2];
#pragma unroll
    for (int s = 0; s < 2; ++s)
        af[s] = *(const short8*)&A[(16 * w + c15) * SP + s * 32 + kb * 8];
    f32x4 acc[16];
#pragma unroll
    for (int t = 0; t < 16; ++t) acc[t] = (f32x4){0.f, 0.f, 0.f, 0.f};
#pragma unroll
    for (int t = 0; t < 16; ++t) {
#pragma unroll
        for (int s = 0; s < 2; ++s) {
            short8 bf8 = *(const short8*)&B[(16 * t + c15) * SP + s * 32 + kb * 8];
            acc[t] = __builtin_amdgcn_mfma_f32_16x16x32_bf16(af[s], bf8, acc[t], 0, 0, 0);
        }
    }
#pragma unroll
    for (int t = 0; t < 4; ++t) {
#pragma unroll
        for (int reg = 0; reg < 4; ++reg) {
            int row = kb * 4 + reg;
            int node = n0 + 16 * w + row;
            if (node < N_NODES) {
                Pi[(size_t)node * 64 + 16 * t + c15] = pk_bf16(acc[t][reg], acc[t + 8][reg]);
                Pj[(size_t)node * 64 + 16 * t + c15] = pk_bf16(acc[t + 4][reg], acc[t + 12][reg]);
            }
        }
    }
}

// one wave per node; packed scalar descriptors, saddr gathers, exp2-domain math
__global__ __launch_bounds__(256, 4) void k_edge_sorted(const int* __restrict__ offs,
                                                        const int* __restrict__ edesc,
                                                        const unsigned int* __restrict__ Pi,
                                                        const unsigned int* __restrict__ Pj,
                                                        const unsigned int* __restrict__ Tp,
                                                        float* __restrict__ agg) {
    int wid = (blockIdx.x * 256 + threadIdx.x) >> 6;
    int lane = threadIdx.x & 63;
    if (wid >= N_NODES) return;
    int uwid = __builtin_amdgcn_readfirstlane(wid);
    int2 kk;
    asm volatile("s_load_dwordx2 %0, %1, 0x0\n\ts_waitcnt lgkmcnt(0)"
                 : "=s"(kk) : "s"(offs + uwid));
    int ko = kk.x, ke = kk.y;
    unsigned int pi = Pi[(size_t)uwid * 64 + lane];
    float gi = bf_lo(pi), ci = bf_hi(pi);
    float acc = 0.0f;
    int lane4 = lane * 4;
    const char* PjB = (const char*)Pj;
    const char* TpB = (const char*)Tp;
    int k0 = ko;
    for (; k0 + 16 <= ke; k0 += 16) {
        int8v e0, e1;
        asm volatile(
            "s_load_dwordx8 %0, %2, 0x0\n\t"
            "s_load_dwordx8 %1, %2, 0x20\n\t"
            "s_waitcnt lgkmcnt(0)"
            : "=&s"(e0), "=&s"(e1)
            : "s"(edesc + k0));
        unsigned int pjv[16], tjv[16];
#pragma unroll
        for (int j = 0; j < 16; ++j) {
            int v = (j < 8) ? e0[j & 7] : e1[j & 7];
            int sb = (v & 0x1FFFF) << 8;
            int tb = (v >> 17) << 8;
            pjv[j] = *(const unsigned int*)(PjB + sb + lane4);
            tjv[j] = *(const unsigned int*)(TpB + tb + lane4);
        }
#pragma unroll
        for (int j = 0; j < 16; ++j) {
            float g = gi + bf_lo(pjv[j]) + bf_lo(tjv[j]);
            float c = ci + bf_hi(pjv[j]) + bf_hi(tjv[j]);
            float sg = __builtin_amdgcn_rcpf(1.0f + __builtin_amdgcn_exp2f(-g));
            float sp = fmaxf(c, 0.0f) + __builtin_amdgcn_logf(1.0f + __builtin_amdgcn_exp2f(-fabsf(c)));
            acc = fmaf(sg, sp, acc);
        }
    }
    if (k0 < ke) {
        int8v e0, e1;
        asm volatile(
            "s_load_dwordx8 %0, %2, 0x0\n\t"
            "s_load_dwordx8 %1, %2, 0x20\n\t"
            "s_waitcnt lgkmcnt(0)"
            : "=&s"(e0), "=&s"(e1)
            : "s"(edesc + k0));
        unsigned int pjv[16], tjv[16];
#pragma unroll
        for (int j = 0; j < 16; ++j) {
            if (k0 + j < ke) {
                int v = (j < 8) ? e0[j & 7] : e1[j & 7];
                int sb = (v & 0x1FFFF) << 8;
                int tb = (v >> 17) << 8;
                pjv[j] = *(const unsigned int*)(PjB + sb + lane4);
                tjv[j] = *(const unsigned int*)(TpB + tb + lane4);
            }
        }
#pragma unroll
        for (int j = 0; j < 16; ++j) {
            if (k0 + j < ke) {
                float g = gi + bf_lo(pjv[j]) + bf_lo(tjv[j]);
                float c = ci + bf_hi(pjv[j]) + bf_hi(tjv[j]);
                float sg = __builtin_amdgcn_rcpf(1.0f + __builtin_amdgcn_exp2f(-g));
                float sp = fmaxf(c, 0.0f) + __builtin_amdgcn_logf(1.0f + __builtin_amdgcn_exp2f(-fabsf(c)));
                acc = fmaf(sg, sp, acc);
            }
        }
    }
    agg[(size_t)uwid * 64 + lane] = acc * LN2;
}

// bnstats + bnfinal merged via last-block pattern; float4 reads
__global__ __launch_bounds__(256) void k_bnstats2(const float* __restrict__ agg,
                                                  float* __restrict__ partial,
                                                  int* __restrict__ lcnt,
                                                  const float* __restrict__ gamma,
                                                  const float* __restrict__ beta,
                                                  int l, float* __restrict__ ss) {
    __shared__ f32x4 ls4[256], ls24[256];
    __shared__ float ls[128];
    __shared__ int lastFlag;
    int tid = threadIdx.x;
    const f32x4* agg4 = (const f32x4*)agg;
    f32x4 s = (f32x4){0.f, 0.f, 0.f, 0.f};
    f32x4 s2 = (f32x4){0.f, 0.f, 0.f, 0.f};
    for (int i = blockIdx.x * 256 + tid; i < N_NODES * 16; i += NPBLK * 256) {
        f32x4 v = agg4[i];
        s += v;
        s2 += v * v;
    }
    ls4[tid] = s; ls24[tid] = s2;
    __syncthreads();
    for (int d = 128; d >= 16; d >>= 1) {
        if (tid < d) { ls4[tid] += ls4[tid + d]; ls24[tid] += ls24[tid + d]; }
        __syncthreads();
    }
    if (tid < 16) {
#pragma unroll
        for (int j = 0; j < 4; ++j) {
            partial[blockIdx.x * 128 + tid * 4 + j] = ls4[tid][j];
            partial[blockIdx.x * 128 + 64 + tid * 4 + j] = ls24[tid][j];
        }
    }
    __syncthreads();
    if (tid == 0) {
        __threadfence();
        lastFlag = (atomicAdd(lcnt, 1) == NPBLK - 1) ? 1 : 0;
    }
    __syncthreads();
    if (lastFlag) {
        __threadfence();
        if (tid < 128) {
            float sum = 0.0f;
            for (int b = 0; b < NPBLK; ++b) sum += partial[b * 128 + tid];
            ls[tid] = sum;
        }
        __syncthreads();
        if (tid < 64) {
            const float inv = 1.0f / (float)N_NODES;
            float mu = ls[tid] * inv;
            float var = ls[64 + tid] * inv - mu * mu;
            float sc = gamma[l * ATOM + tid] * rsqrtf(var + 1e-5f);
            ss[tid] = sc;
            ss[64 + tid] = beta[l * ATOM + tid] - mu * sc;
        }
    }
}

// fused final update + pool; batch is sorted -> run-length accumulate (high-occupancy)
__global__ __launch_bounds__(256) void k_pool2(const float* __restrict__ agg,
                                               const float* __restrict__ ss,
                                               const float* __restrict__ h,
                                               const int* __restrict__ batch,
                                               float* __restrict__ g) {
    int w = threadIdx.x >> 6, lane = threadIdx.x & 63;
    int nbase = blockIdx.x * 64 + w * 16;
    float acc = 0.0f;
    int curg = -1;
    float sc = ss[lane], sh = ss[64 + lane];
    for (int i = 0; i < 16; ++i) {
        int n = nbase + i;
        if (n >= N_NODES) break;
        int gid = __builtin_amdgcn_readfirstlane(batch[n]);
        if (gid != curg) {
            if (curg >= 0) atomicAdd(&g[(size_t)curg * ATOM + lane], acc);
            curg = gid;
            acc = 0.0f;
        }
        float x = sc * agg[(size_t)n * 64 + lane] + sh + h[(size_t)n * 64 + lane];
        acc += sp_fast2(x);
    }
    if (curg >= 0) atomicAdd(&g[(size_t)curg * ATOM + lane], acc);
}

__global__ __launch_bounds__(128) void k_head(const float* __restrict__ g,
                                              const float* __restrict__ W1,
                                              const float* __restrict__ b1,
                                              const float* __restrict__ W2,
                                              const float* __restrict__ b2,
                                              float* __restrict__ out) {
    __shared__ float red[128];
    int gid = blockIdx.x, j = threadIdx.x;
    float acc = b1[j];
    for (int k = 0; k < ATOM; ++k) acc += g[gid * ATOM + k] * W1[k * HFEA + j];
    red[j] = softplus_f(acc) * W2[j];
    __syncthreads();
    for (int s = 64; s > 0; s >>= 1) {
        if (j < s) red[j] += red[j + s];
        __syncthreads();
    }
    if (j == 0) out[gid] = red[0] + b2[0];
}

extern "C" void kernel_launch(void* const* d_in, const int* in_sizes, int n_in,
                              void* d_out, int out_size, void* d_ws, size_t ws_size,
                              hipStream_t stream) {
    const float* x       = (const float*)d_in[0];
    const float* ea      = (const float*)d_in[1];
    const float* W_emb   = (const float*)d_in[2];
    const float* b_emb   = (const float*)d_in[3];
    const float* Wf      = (const float*)d_in[4];
    const float* bf      = (const float*)d_in[5];
    const float* Ws      = (const float*)d_in[6];
    const float* bs      = (const float*)d_in[7];
    const float* bn_g    = (const float*)d_in[8];
    const float* bn_b    = (const float*)d_in[9];
    const float* W1      = (const float*)d_in[10];
    const float* b1      = (const float*)d_in[11];
    const float* W2      = (const float*)d_in[12];
    const float* b2      = (const float*)d_in[13];
    const int*   ei      = (const int*)d_in[14];
    const int*   batch   = (const int*)d_in[15];
    float* out = (float*)d_out;

    char* wsb = (char*)d_ws;
    size_t off = 0;
    auto alloc = [&](size_t bytes) { char* p = wsb + off; off += (bytes + 255) & ~(size_t)255; return p; };
    float*        h        = (float*)alloc((size_t)N_NODES * 64 * 4);
    float*        agg      = (float*)alloc((size_t)N_NODES * 64 * 4);
    unsigned int* Pi       = (unsigned int*)alloc((size_t)N_NODES * 64 * 4);
    unsigned int* Pj       = (unsigned int*)alloc((size_t)N_NODES * 64 * 4);
    int*          edesc    = (int*)alloc((size_t)(N_EDGES + 16) * 4);
    int2*         staging  = (int2*)alloc((size_t)N_EDGES * 8);
    int*          meta     = (int*)alloc(1024 * 4);   // [0..511] bucketCnt, [512..] lcnt/flags
    int*          bucketCnt    = meta;
    int*          lcnt         = meta + 512;          // [0..2] bn layers, [3] bhist flag
    int*          bucketBase   = (int*)alloc(520 * 4);
    int*          bucketCursor = (int*)alloc(512 * 4);
    int*          offs     = (int*)alloc((size_t)(N_NODES + 1) * 4);
    unsigned int* Tp       = (unsigned int*)alloc((size_t)NCONV * TS * 4);
    unsigned int* Bp       = (unsigned int*)alloc((size_t)NCONV * 8192 * 4);
    unsigned int* BpE      = (unsigned int*)alloc((size_t)64 * 64 * 4);
    float*        partial  = (float*)alloc((size_t)NPBLK * 128 * 4);
    float*        ss       = (float*)alloc(128 * 4);
    float*        g        = (float*)alloc((size_t)NGRAPH * 64 * 4);

    (void)hipMemsetAsync(meta, 0, 1024 * 4, stream);
    k_bhist<<<256, 256, 0, stream>>>(ei, bucketCnt, lcnt + 3, bucketBase, bucketCursor, offs);
    k_psort1<<<(N_EDGES + S3CH - 1) / S3CH, 256, 0, stream>>>(ei, ea, bucketCursor, staging);
    k_psort2<<<NBKT, 256, 0, stream>>>(bucketBase, staging, edesc, offs);

    dim3 tg(163, NCONV);
    k_table2<<<tg, 256, 0, stream>>>(Wf, bf, Ws, bs, W_emb, Tp, Bp, BpE);
    k_embed_nodeP<<<(N_NODES + 63) / 64, 256, 0, stream>>>(x, BpE, b_emb, Bp, h, Pi, Pj);

    for (int l = 0; l < NCONV; ++l) {
        if (l > 0)
            k_nodeP_mfma<<<(N_NODES + 63) / 64, 256, 0, stream>>>(h, agg, ss, Bp, l, Pi, Pj);
        k_edge_sorted<<<(N_NODES * 64 + 255) / 256, 256, 0, stream>>>(
            offs, edesc, Pi, Pj, Tp + (size_t)l * TS, agg);
        k_bnstats2<<<NPBLK, 256, 0, stream>>>(agg, partial, lcnt + l, bn_g, bn_b, l, ss);
    }

    (void)hipMemsetAsync(g, 0, (size_t)NGRAPH * 64 * 4, stream);
    k_pool2<<<(N_NODES + 63) / 64, 256, 0, stream>>>(agg, ss, h, batch, g);
    k_head<<<NGRAPH, 128, 0, stream>>>(g, W1, b1, W2, b2, out);
}

// Round 15
// 404.527 us; speedup vs baseline: 5.1302x; 1.1010x over previous
//
#include <hip/hip_runtime.h>
#include <hip/hip_bf16.h>
#include <math.h>

#define N_NODES 100000
#define N_EDGES 1600000
#define ORIG    92
#define NBR     41
#define ATOM    64
#define NCONV   3
#define HFEA    128
#define NGRAPH  256
#define ZD      169           // 2*ATOM + NBR
#define TBINS   5120
#define TMAX    10.0f
#define TS      ((TBINS + 1) * 64)   // per-layer table stride (uints)
#define SP      72                   // nodeP LDS row pad (shorts)
#define SPE     136                  // embed LDS row pad (shorts), K=128
#define LOG2E   1.4426950408889634f
#define LN2     0.6931471805599453f
#define EPS2    (1e-5f / (LN2 * LN2))   // BN eps compensated for un-scaled agg
#define NBKT    391                  // ceil(N_NODES / 256)
#define S1E     6250                 // edges per k_bhist block (256 blocks exact)
#define S3CH    4096                 // edges per k_psort1 block
#define PSLOT   128                  // pstats slots

typedef __attribute__((ext_vector_type(8))) short short8;
typedef __attribute__((ext_vector_type(4))) float f32x4;
typedef __attribute__((ext_vector_type(8))) int int8v;

__device__ __forceinline__ float softplus_f(float x) {
    return fmaxf(x, 0.0f) + log1pf(expf(-fabsf(x)));
}
// fast softplus via exp2/log2 HW ops
__device__ __forceinline__ float sp_fast2(float x) {
    float t = x * LOG2E;
    return LN2 * (fmaxf(t, 0.0f) +
                  __builtin_amdgcn_logf(1.0f + __builtin_amdgcn_exp2f(-fabsf(t))));
}
// pack 2 fp32 -> 2 bf16 in one uint
__device__ __forceinline__ unsigned int pk_bf16(float lo, float hi) {
    unsigned int r;
    asm("v_cvt_pk_bf16_f32 %0, %1, %2" : "=v"(r) : "v"(lo), "v"(hi));
    return r;
}
__device__ __forceinline__ float bf_lo(unsigned int p) { return __uint_as_float(p << 16); }
__device__ __forceinline__ float bf_hi(unsigned int p) { return __uint_as_float(p & 0xffff0000u); }

// ---------- sort pass 0: coarse bucket histogram + last-block scan ----------
__global__ __launch_bounds__(256) void k_bhist(const int* __restrict__ ei,
                                               int* __restrict__ bucketCnt,
                                               int* __restrict__ flag,
                                               int* __restrict__ bucketBase,
                                               int* __restrict__ bucketCursor,
                                               int* __restrict__ offs) {
    __shared__ int cntL[NBKT];
    __shared__ int lastFlag;
    int tid = threadIdx.x;
    for (int i = tid; i < NBKT; i += 256) cntL[i] = 0;
    __syncthreads();
    int base = blockIdx.x * S1E;
    for (int i = tid; i < S1E; i += 256)
        atomicAdd(&cntL[ei[N_EDGES + base + i] >> 8], 1);
    __syncthreads();
    for (int i = tid; i < NBKT; i += 256)
        if (cntL[i]) atomicAdd(&bucketCnt[i], cntL[i]);
    if (tid == 0) {
        __threadfence();
        lastFlag = (atomicAdd(flag, 1) == 255) ? 1 : 0;
    }
    __syncthreads();
    if (lastFlag && tid < 64) {
        __threadfence();
        int carry = 0;
        for (int b0 = 0; b0 < NBKT; b0 += 64) {
            int idx = b0 + tid;
            int v0 = (idx < NBKT) ? bucketCnt[idx] : 0;
            int v = v0;
            for (int d = 1; d < 64; d <<= 1) {
                int u = __shfl_up(v, d, 64);
                if (tid >= d) v += u;
            }
            if (idx < NBKT) {
                int ex = carry + v - v0;
                bucketBase[idx] = ex;
                bucketCursor[idx] = ex;
            }
            carry += __shfl(v, 63, 64);
        }
        if (tid == 0) {
            bucketBase[NBKT] = N_EDGES;
            offs[N_NODES] = N_EDGES;
        }
    }
}

// ---------- sort pass 1: bucket-binned staging, coalesced burst writes ----------
__global__ __launch_bounds__(256) void k_psort1(const int* __restrict__ ei,
                                                const float* __restrict__ ea,
                                                int* __restrict__ bucketCursor,
                                                int2* __restrict__ staging) {
    __shared__ int cntL[NBKT], scanB[NBKT], curL[NBKT], gbaseL[NBKT];
    __shared__ int sortedD[S3CH], sortedN[S3CH];
    int tid = threadIdx.x;
    int base = blockIdx.x * S3CH;
    int myCount = N_EDGES - base;
    if (myCount > S3CH) myCount = S3CH;
    for (int i = tid; i < NBKT; i += 256) { cntL[i] = 0; curL[i] = 0; }
    __syncthreads();
    int descr[16], dstr[16];
#pragma unroll
    for (int j = 0; j < 16; ++j) {
        int i = j * 256 + tid;
        descr[j] = 0; dstr[j] = -1;
        if (i < myCount) {
            int e = base + i;
            int src = ei[e];
            int dst = ei[N_EDGES + e];
            float a = ea[3 * e], bb = ea[3 * e + 1], c = ea[3 * e + 2];
            float d = sqrtf(a * a + bb * bb + c * c);
            int bin = (int)fminf(fmaf(d, (float)TBINS / TMAX, 0.5f), (float)TBINS);
            descr[j] = (bin << 17) | src;
            dstr[j] = dst;
            atomicAdd(&cntL[dst >> 8], 1);
        }
    }
    __syncthreads();
    if (tid < 64) {  // wave 0 exclusive-scans cntL
        int carry = 0;
        for (int b0 = 0; b0 < NBKT; b0 += 64) {
            int idx = b0 + tid;
            int v0 = (idx < NBKT) ? cntL[idx] : 0;
            int v = v0;
            for (int d = 1; d < 64; d <<= 1) {
                int u = __shfl_up(v, d, 64);
                if (tid >= d) v += u;
            }
            if (idx < NBKT) scanB[idx] = carry + v - v0;
            carry += __shfl(v, 63, 64);
        }
    }
    __syncthreads();
#pragma unroll
    for (int j = 0; j < 16; ++j) {
        if (dstr[j] >= 0) {
            int b = dstr[j] >> 8;
            int pos = scanB[b] + atomicAdd(&curL[b], 1);
            sortedD[pos] = descr[j];
            sortedN[pos] = dstr[j];
        }
    }
    for (int i = tid; i < NBKT; i += 256)
        if (cntL[i] > 0) gbaseL[i] = atomicAdd(&bucketCursor[i], cntL[i]);
    __syncthreads();
    for (int i = tid; i < myCount; i += 256) {
        int n = sortedN[i];
        int b = n >> 8;
        int2 pr; pr.x = sortedD[i]; pr.y = n;
        staging[gbaseL[b] + (i - scanB[b])] = pr;
    }
}

// ---------- sort pass 2: per-bucket exact sort + offs ----------
__global__ __launch_bounds__(256) void k_psort2(const int* __restrict__ bucketBase,
                                                const int2* __restrict__ staging,
                                                int* __restrict__ edesc,
                                                int* __restrict__ offs) {
    __shared__ int cnt[256], sbase[256], cur[256];
    int b = blockIdx.x, tid = threadIdx.x;
    int base = bucketBase[b];
    int nb = bucketBase[b + 1] - base;
    cnt[tid] = 0; cur[tid] = 0;
    __syncthreads();
    for (int i = tid; i < nb; i += 256)
        atomicAdd(&cnt[staging[base + i].y & 255], 1);
    __syncthreads();
    int v = cnt[tid];
    sbase[tid] = v;
    __syncthreads();
    for (int d = 1; d < 256; d <<= 1) {
        int u = (tid >= d) ? sbase[tid - d] : 0;
        __syncthreads();
        sbase[tid] += u;
        __syncthreads();
    }
    int ex = sbase[tid] - v;
    int dst = (b << 8) + tid;
    if (dst < N_NODES) offs[dst] = base + ex;
    sbase[tid] = ex;
    __syncthreads();
    for (int i = tid; i < nb; i += 256) {
        int2 pr = staging[base + i];
        int local = pr.y & 255;
        int pos = base + sbase[local] + atomicAdd(&cur[local], 1);
        edesc[pos] = pr.x;
    }
}

// T = R(d) @ W_e + bias (pre-scaled by log2e); tail blocks do weight prep
__global__ __launch_bounds__(256) void k_table2(const float* __restrict__ Wf,
                                                const float* __restrict__ bf,
                                                const float* __restrict__ Ws,
                                                const float* __restrict__ bs,
                                                const float* __restrict__ We,
                                                unsigned int* __restrict__ Tp,
                                                unsigned int* __restrict__ Bp,
                                                unsigned int* __restrict__ BpE) {
    int tid = threadIdx.x;
    int l = blockIdx.y;
    if (blockIdx.x == 161) {  // node-part weight prep for layer l
        int m = tid >> 6, c = tid & 63;
        const float* Wb = ((m & 2) ? Ws : Wf) + (size_t)l * ZD * ATOM + (m & 1) * ATOM * ATOM + c;
        unsigned int* dst = Bp + (size_t)l * 8192 + (size_t)tid * 32;
        for (int kp = 0; kp < 32; ++kp) {
            float w0 = Wb[(2 * kp) * ATOM] * LOG2E;
            float w1 = Wb[(2 * kp + 1) * ATOM] * LOG2E;
            dst[kp] = pk_bf16(w0, w1);
        }
        return;
    }
    if (blockIdx.x == 162) {  // embed weight prep (once)
        if (l != 0) return;
        int n = tid & 63, q = tid >> 6;
        for (int kp = q * 16; kp < q * 16 + 16; ++kp) {
            int k0 = 2 * kp, k1 = 2 * kp + 1;
            float w0 = (k0 < ORIG) ? We[k0 * ATOM + n] : 0.f;
            float w1 = (k1 < ORIG) ? We[k1 * ATOM + n] : 0.f;
            BpE[(size_t)n * 64 + kp] = pk_bf16(w0, w1);
        }
        return;
    }
    __shared__ float Wc[NBR * 64], Wsc[NBR * 64], R[32 * NBR];
    int b0 = blockIdx.x * 32;
    const float* srcf = Wf + (size_t)l * ZD * ATOM + 2 * ATOM * ATOM;
    const float* srcs = Ws + (size_t)l * ZD * ATOM + 2 * ATOM * ATOM;
    for (int i = tid; i < NBR * 64; i += 256) {
        Wc[i] = srcf[i] * LOG2E;
        Wsc[i] = srcs[i] * LOG2E;
    }
    for (int i = tid; i < 32 * NBR; i += 256) {
        int bin = i / NBR, k = i - bin * NBR;
        float d = (b0 + bin) * (TMAX / TBINS);
        float diff = d - 0.2f * k;
        R[i] = expf(-5.0f * diff * diff);
    }
    __syncthreads();
    int c = tid & 63;
    float afb = bf[l * ATOM + c] * LOG2E, asb = bs[l * ATOM + c] * LOG2E;
#pragma unroll
    for (int it = 0; it < 8; ++it) {
        int bin = (tid >> 6) + 4 * it;
        int gb = b0 + bin;
        if (gb <= TBINS) {
            float af = afb, as = asb;
            for (int k = 0; k < NBR; ++k) {
                float r = R[bin * NBR + k];
                af += r * Wc[k * 64 + c];
                as += r * Wsc[k * 64 + c];
            }
            Tp[(size_t)l * TS + (size_t)gb * 64 + c] = pk_bf16(af, as);
        }
    }
}

// fused: embed MFMA (K=128) -> h, then layer-0 projection MFMA -> Pi, Pj
__global__ __launch_bounds__(256) void k_embed_nodeP(const float* __restrict__ x,
                                                     const unsigned int* __restrict__ BpE,
                                                     const float* __restrict__ be,
                                                     const unsigned int* __restrict__ Bp,
                                                     float* __restrict__ h,
                                                     unsigned int* __restrict__ Pi,
                                                     unsigned int* __restrict__ Pj) {
    __shared__ char smem[46080];
    short* Ae = (short*)smem;              // [64][SPE]
    short* Be = (short*)(smem + 17408);    // [64][SPE]
    short* Bn = (short*)smem;              // [256][SP]  aliases Ae/Be (after sync)
    short* An = (short*)(smem + 36864);    // [64][SP]
    int tid = threadIdx.x;
    int n0 = blockIdx.x * 64;
    for (int i = tid; i < 64 * 64; i += 256) {
        int r = i >> 6, kp = i & 63;
        int node = n0 + r;
        float2 v = make_float2(0.f, 0.f);
        if (node < N_NODES && kp < 46) v = ((const float2*)x)[(size_t)node * 46 + kp];
        *(unsigned int*)&Ae[r * SPE + kp * 2] = pk_bf16(v.x, v.y);
    }
    {
        const uint4* src = (const uint4*)BpE;
        for (int i = tid; i < 64 * 16; i += 256) {
            int row = i >> 4, q = i & 15;
            *(uint4*)&Be[row * SPE + q * 8] = src[i];
        }
    }
    __syncthreads();
    int lane = tid & 63, w = tid >> 6;
    int c15 = lane & 15, kb = lane >> 4;
    {
        short8 af[4];
#pragma unroll
        for (int s = 0; s < 4; ++s)
            af[s] = *(const short8*)&Ae[(16 * w + c15) * SPE + s * 32 + kb * 8];
        f32x4 acc[4];
#pragma unroll
        for (int t = 0; t < 4; ++t) acc[t] = (f32x4){0.f, 0.f, 0.f, 0.f};
#pragma unroll
        for (int t = 0; t < 4; ++t) {
#pragma unroll
            for (int s = 0; s < 4; ++s) {
                short8 bf8 = *(const short8*)&Be[(16 * t + c15) * SPE + s * 32 + kb * 8];
                acc[t] = __builtin_amdgcn_mfma_f32_16x16x32_bf16(af[s], bf8, acc[t], 0, 0, 0);
            }
        }
#pragma unroll
        for (int t = 0; t < 4; ++t) {
            float bias = be[16 * t + c15];
#pragma unroll
            for (int reg = 0; reg < 4; ++reg) {
                int row = 16 * w + kb * 4 + reg;
                int node = n0 + row;
                float v = acc[t][reg] + bias;
                if (node < N_NODES) h[(size_t)node * 64 + 16 * t + c15] = v;
                An[row * SP + 16 * t + c15] = (short)pk_bf16(v, v);
            }
        }
    }
    __syncthreads();
    {
        const uint4* src = (const uint4*)Bp;   // layer 0
        for (int i = tid; i < 2048; i += 256) {
            int row = i >> 3, j = i & 7;
            *(uint4*)&Bn[row * SP + j * 8] = src[row * 8 + j];
        }
    }
    __syncthreads();
    short8 af2[2];
#pragma unroll
    for (int s = 0; s < 2; ++s)
        af2[s] = *(const short8*)&An[(16 * w + c15) * SP + s * 32 + kb * 8];
    f32x4 acc2[16];
#pragma unroll
    for (int t = 0; t < 16; ++t) acc2[t] = (f32x4){0.f, 0.f, 0.f, 0.f};
#pragma unroll
    for (int t = 0; t < 16; ++t) {
#pragma unroll
        for (int s = 0; s < 2; ++s) {
            short8 bf8 = *(const short8*)&Bn[(16 * t + c15) * SP + s * 32 + kb * 8];
            acc2[t] = __builtin_amdgcn_mfma_f32_16x16x32_bf16(af2[s], bf8, acc2[t], 0, 0, 0);
        }
    }
#pragma unroll
    for (int t = 0; t < 4; ++t) {
#pragma unroll
        for (int reg = 0; reg < 4; ++reg) {
            int row = kb * 4 + reg;
            int node = n0 + 16 * w + row;
            if (node < N_NODES) {
                Pi[(size_t)node * 64 + 16 * t + c15] = pk_bf16(acc2[t][reg], acc2[t + 8][reg]);
                Pj[(size_t)node * 64 + 16 * t + c15] = pk_bf16(acc2[t + 4][reg], acc2[t + 12][reg]);
            }
        }
    }
}

// fused: BN+residual update of h, then MFMA projection -> Pi, Pj (layers 1,2)
__global__ __launch_bounds__(256) void k_nodeP_mfma(float* __restrict__ h,
                                                    const float* __restrict__ agg,
                                                    const float* __restrict__ ss,
                                                    const unsigned int* __restrict__ Bp,
                                                    int l,
                                                    unsigned int* __restrict__ Pi,
                                                    unsigned int* __restrict__ Pj) {
    __shared__ short A[64 * SP];
    __shared__ short B[256 * SP];
    int tid = threadIdx.x;
    int n0 = blockIdx.x * 64;
    for (int i = tid; i < 64 * 16; i += 256) {
        int r = i >> 4, kq = i & 15;
        int node = n0 + r;
        float4 hv = make_float4(0.f, 0.f, 0.f, 0.f);
        if (node < N_NODES) {
            hv = ((const float4*)h)[(size_t)node * 16 + kq];
            float4 av = ((const float4*)agg)[(size_t)node * 16 + kq];
            int c = kq * 4;
            hv.x = sp_fast2(ss[c] * av.x + ss[64 + c] + hv.x);
            hv.y = sp_fast2(ss[c + 1] * av.y + ss[64 + c + 1] + hv.y);
            hv.z = sp_fast2(ss[c + 2] * av.z + ss[64 + c + 2] + hv.z);
            hv.w = sp_fast2(ss[c + 3] * av.w + ss[64 + c + 3] + hv.w);
            ((float4*)h)[(size_t)node * 16 + kq] = hv;
        }
        uint2 pk2;
        pk2.x = pk_bf16(hv.x, hv.y);
        pk2.y = pk_bf16(hv.z, hv.w);
        *(uint2*)&A[r * SP + kq * 4] = pk2;
    }
    {
        const uint4* src = (const uint4*)(Bp + (size_t)l * 8192);
        for (int i = tid; i < 2048; i += 256) {
            int row = i >> 3, j = i & 7;
            *(uint4*)&B[row * SP + j * 8] = src[row * 8 + j];
        }
    }
    __syncthreads();
    int lane = tid & 63, w = tid >> 6;
    int c15 = lane & 15, kb = lane >> 4;
    short8 af[2];
#pragma unroll
    for (int s = 0; s < 2; ++s)
        af[s] = *(const short8*)&A[(16 * w + c15) * SP + s * 32 + kb * 8];
    f32x4 acc[16];
#pragma unroll
    for (int t = 0; t < 16; ++t) acc[t] = (f32x4){0.f, 0.f, 0.f, 0.f};
#pragma unroll
    for (int t = 0; t < 16; ++t) {
#pragma unroll
        for (int s = 0; s < 2; ++s) {
            short8 bf8 = *(const short8*)&B[(16 * t + c15) * SP + s * 32 + kb * 8];
            acc[t] = __builtin_amdgcn_mfma_f32_16x16x32_bf16(af[s], bf8, acc[t], 0, 0, 0);
        }
    }
#pragma unroll
    for (int t = 0; t < 4; ++t) {
#pragma unroll
        for (int reg = 0; reg < 4; ++reg) {
            int row = kb * 4 + reg;
            int node = n0 + 16 * w + row;
            if (node < N_NODES) {
                Pi[(size_t)node * 64 + 16 * t + c15] = pk_bf16(acc[t][reg], acc[t + 8][reg]);
                Pj[(size_t)node * 64 + 16 * t + c15] = pk_bf16(acc[t + 4][reg], acc[t + 12][reg]);
            }
        }
    }
}

// one wave per node (exact grid: 25000 blocks x 4 nodes); fused BN-stats epilogue
__global__ __launch_bounds__(256, 4) void k_edge_sorted(const int* __restrict__ offs,
                                                        const int* __restrict__ edesc,
                                                        const unsigned int* __restrict__ Pi,
                                                        const unsigned int* __restrict__ Pj,
                                                        const unsigned int* __restrict__ Tp,
                                                        float* __restrict__ agg,
                                                        float* __restrict__ pstats) {
    __shared__ float es[4][64], es2[4][64];
    int wid = (blockIdx.x * 256 + threadIdx.x) >> 6;   // always < N_NODES (exact grid)
    int lane = threadIdx.x & 63;
    int w = threadIdx.x >> 6;
    int uwid = __builtin_amdgcn_readfirstlane(wid);
    int2 kk;
    asm volatile("s_load_dwordx2 %0, %1, 0x0\n\ts_waitcnt lgkmcnt(0)"
                 : "=s"(kk) : "s"(offs + uwid));
    int ko = kk.x, ke = kk.y;
    unsigned int pi = Pi[(size_t)uwid * 64 + lane];
    float gi = bf_lo(pi), ci = bf_hi(pi);
    float acc = 0.0f;
    int lane4 = lane * 4;
    const char* PjB = (const char*)Pj;
    const char* TpB = (const char*)Tp;
    int k0 = ko;
    for (; k0 + 16 <= ke; k0 += 16) {
        int8v e0, e1;
        asm volatile(
            "s_load_dwordx8 %0, %2, 0x0\n\t"
            "s_load_dwordx8 %1, %2, 0x20\n\t"
            "s_waitcnt lgkmcnt(0)"
            : "=&s"(e0), "=&s"(e1)
            : "s"(edesc + k0));
        unsigned int pjv[16], tjv[16];
#pragma unroll
        for (int j = 0; j < 16; ++j) {
            int v = (j < 8) ? e0[j & 7] : e1[j & 7];
            int sb = (v & 0x1FFFF) << 8;
            int tb = (v >> 17) << 8;
            pjv[j] = *(const unsigned int*)(PjB + sb + lane4);
            tjv[j] = *(const unsigned int*)(TpB + tb + lane4);
        }
#pragma unroll
        for (int j = 0; j < 16; ++j) {
            float g = gi + bf_lo(pjv[j]) + bf_lo(tjv[j]);
            float c = ci + bf_hi(pjv[j]) + bf_hi(tjv[j]);
            float sg = __builtin_amdgcn_rcpf(1.0f + __builtin_amdgcn_exp2f(-g));
            float sp = fmaxf(c, 0.0f) + __builtin_amdgcn_logf(1.0f + __builtin_amdgcn_exp2f(-fabsf(c)));
            acc = fmaf(sg, sp, acc);
        }
    }
    if (k0 < ke) {
        int8v e0, e1;
        asm volatile(
            "s_load_dwordx8 %0, %2, 0x0\n\t"
            "s_load_dwordx8 %1, %2, 0x20\n\t"
            "s_waitcnt lgkmcnt(0)"
            : "=&s"(e0), "=&s"(e1)
            : "s"(edesc + k0));
        unsigned int pjv[16], tjv[16];
#pragma unroll
        for (int j = 0; j < 16; ++j) {
            if (k0 + j < ke) {
                int v = (j < 8) ? e0[j & 7] : e1[j & 7];
                int sb = (v & 0x1FFFF) << 8;
                int tb = (v >> 17) << 8;
                pjv[j] = *(const unsigned int*)(PjB + sb + lane4);
                tjv[j] = *(const unsigned int*)(TpB + tb + lane4);
            }
        }
#pragma unroll
        for (int j = 0; j < 16; ++j) {
            if (k0 + j < ke) {
                float g = gi + bf_lo(pjv[j]) + bf_lo(tjv[j]);
                float c = ci + bf_hi(pjv[j]) + bf_hi(tjv[j]);
                float sg = __builtin_amdgcn_rcpf(1.0f + __builtin_amdgcn_exp2f(-g));
                float sp = fmaxf(c, 0.0f) + __builtin_amdgcn_logf(1.0f + __builtin_amdgcn_exp2f(-fabsf(c)));
                acc = fmaf(sg, sp, acc);
            }
        }
    }
    agg[(size_t)uwid * 64 + lane] = acc;   // NOTE: not scaled by LN2; BN compensates via EPS2
    // fused BN-stats: block-reduce 4 nodes, scatter into pstats slot
    es[w][lane] = acc;
    es2[w][lane] = acc * acc;
    __syncthreads();
    if (threadIdx.x < 64) {
        float s = es[0][threadIdx.x] + es[1][threadIdx.x] + es[2][threadIdx.x] + es[3][threadIdx.x];
        float s2 = es2[0][threadIdx.x] + es2[1][threadIdx.x] + es2[2][threadIdx.x] + es2[3][threadIdx.x];
        float* slot = pstats + (size_t)(blockIdx.x & (PSLOT - 1)) * 128;
        atomicAdd(&slot[threadIdx.x], s);
        atomicAdd(&slot[64 + threadIdx.x], s2);
    }
}

// reduce pstats -> ss, then re-zero pstats for the next layer
__global__ __launch_bounds__(128) void k_bnfinal(float* __restrict__ pstats,
                                                 const float* __restrict__ gamma,
                                                 const float* __restrict__ beta,
                                                 int l, float* __restrict__ ss) {
    __shared__ float ls[128];
    int t = threadIdx.x;
    float sum = 0.0f;
    for (int b = 0; b < PSLOT; ++b) sum += pstats[b * 128 + t];
    ls[t] = sum;
    for (int b = t; b < PSLOT * 128; b += 128) pstats[b] = 0.0f;
    __syncthreads();
    if (t < 64) {
        const float inv = 1.0f / (float)N_NODES;
        float mu = ls[t] * inv;
        float var = ls[64 + t] * inv - mu * mu;
        float sc = gamma[l * ATOM + t] * rsqrtf(var + EPS2);
        ss[t] = sc;
        ss[64 + t] = beta[l * ATOM + t] - mu * sc;
    }
}

// fused final update + pool; batch is sorted -> run-length accumulate
__global__ __launch_bounds__(256) void k_pool2(const float* __restrict__ agg,
                                               const float* __restrict__ ss,
                                               const float* __restrict__ h,
                                               const int* __restrict__ batch,
                                               float* __restrict__ g) {
    int w = threadIdx.x >> 6, lane = threadIdx.x & 63;
    int nbase = blockIdx.x * 64 + w * 16;
    float acc = 0.0f;
    int curg = -1;
    float sc = ss[lane], sh = ss[64 + lane];
    for (int i = 0; i < 16; ++i) {
        int n = nbase + i;
        if (n >= N_NODES) break;
        int gid = __builtin_amdgcn_readfirstlane(batch[n]);
        if (gid != curg) {
            if (curg >= 0) atomicAdd(&g[(size_t)curg * ATOM + lane], acc);
            curg = gid;
            acc = 0.0f;
        }
        float x = sc * agg[(size_t)n * 64 + lane] + sh + h[(size_t)n * 64 + lane];
        acc += sp_fast2(x);
    }
    if (curg >= 0) atomicAdd(&g[(size_t)curg * ATOM + lane], acc);
}

__global__ __launch_bounds__(128) void k_head(const float* __restrict__ g,
                                              const float* __restrict__ W1,
                                              const float* __restrict__ b1,
                                              const float* __restrict__ W2,
                                              const float* __restrict__ b2,
                                              float* __restrict__ out) {
    __shared__ float red[128];
    int gid = blockIdx.x, j = threadIdx.x;
    float acc = b1[j];
    for (int k = 0; k < ATOM; ++k) acc += g[gid * ATOM + k] * W1[k * HFEA + j];
    red[j] = softplus_f(acc) * W2[j];
    __syncthreads();
    for (int s = 64; s > 0; s >>= 1) {
        if (j < s) red[j] += red[j + s];
        __syncthreads();
    }
    if (j == 0) out[gid] = red[0] + b2[0];
}

extern "C" void kernel_launch(void* const* d_in, const int* in_sizes, int n_in,
                              void* d_out, int out_size, void* d_ws, size_t ws_size,
                              hipStream_t stream) {
    const float* x       = (const float*)d_in[0];
    const float* ea      = (const float*)d_in[1];
    const float* W_emb   = (const float*)d_in[2];
    const float* b_emb   = (const float*)d_in[3];
    const float* Wf      = (const float*)d_in[4];
    const float* bf      = (const float*)d_in[5];
    const float* Ws      = (const float*)d_in[6];
    const float* bs      = (const float*)d_in[7];
    const float* bn_g    = (const float*)d_in[8];
    const float* bn_b    = (const float*)d_in[9];
    const float* W1      = (const float*)d_in[10];
    const float* b1      = (const float*)d_in[11];
    const float* W2      = (const float*)d_in[12];
    const float* b2      = (const float*)d_in[13];
    const int*   ei      = (const int*)d_in[14];
    const int*   batch   = (const int*)d_in[15];
    float* out = (float*)d_out;

    char* wsb = (char*)d_ws;
    size_t off = 0;
    auto alloc = [&](size_t bytes) { char* p = wsb + off; off += (bytes + 255) & ~(size_t)255; return p; };
    float*        h        = (float*)alloc((size_t)N_NODES * 64 * 4);
    float*        agg      = (float*)alloc((size_t)N_NODES * 64 * 4);
    unsigned int* Pi       = (unsigned int*)alloc((size_t)N_NODES * 64 * 4);
    unsigned int* Pj       = (unsigned int*)alloc((size_t)N_NODES * 64 * 4);
    int*          edesc    = (int*)alloc((size_t)(N_EDGES + 16) * 4);
    int2*         staging  = (int2*)alloc((size_t)N_EDGES * 8);
    // zeroed region: [0..511] bucketCnt, [512] bhist flag, [1024..] pstats (128x128)
    int*          meta     = (int*)alloc((1024 + PSLOT * 128) * 4);
    int*          bucketCnt    = meta;
    int*          flag         = meta + 512;
    float*        pstats       = (float*)(meta + 1024);
    int*          bucketBase   = (int*)alloc(520 * 4);
    int*          bucketCursor = (int*)alloc(512 * 4);
    int*          offs     = (int*)alloc((size_t)(N_NODES + 1) * 4);
    unsigned int* Tp       = (unsigned int*)alloc((size_t)NCONV * TS * 4);
    unsigned int* Bp       = (unsigned int*)alloc((size_t)NCONV * 8192 * 4);
    unsigned int* BpE      = (unsigned int*)alloc((size_t)64 * 64 * 4);
    float*        ss       = (float*)alloc(128 * 4);
    float*        g        = (float*)alloc((size_t)NGRAPH * 64 * 4);

    (void)hipMemsetAsync(meta, 0, (1024 + PSLOT * 128) * 4, stream);
    k_bhist<<<256, 256, 0, stream>>>(ei, bucketCnt, flag, bucketBase, bucketCursor, offs);
    k_psort1<<<(N_EDGES + S3CH - 1) / S3CH, 256, 0, stream>>>(ei, ea, bucketCursor, staging);
    k_psort2<<<NBKT, 256, 0, stream>>>(bucketBase, staging, edesc, offs);

    dim3 tg(163, NCONV);
    k_table2<<<tg, 256, 0, stream>>>(Wf, bf, Ws, bs, W_emb, Tp, Bp, BpE);
    k_embed_nodeP<<<(N_NODES + 63) / 64, 256, 0, stream>>>(x, BpE, b_emb, Bp, h, Pi, Pj);

    for (int l = 0; l < NCONV; ++l) {
        if (l > 0)
            k_nodeP_mfma<<<(N_NODES + 63) / 64, 256, 0, stream>>>(h, agg, ss, Bp, l, Pi, Pj);
        k_edge_sorted<<<N_NODES * 64 / 256, 256, 0, stream>>>(
            offs, edesc, Pi, Pj, Tp + (size_t)l * TS, agg, pstats);
        k_bnfinal<<<1, 128, 0, stream>>>(pstats, bn_g, bn_b, l, ss);
    }

    (void)hipMemsetAsync(g, 0, (size_t)NGRAPH * 64 * 4, stream);
    k_pool2<<<(N_NODES + 63) / 64, 256, 0, stream>>>(agg, ss, h, batch, g);
    k_head<<<NGRAPH, 128, 0, stream>>>(g, W1, b1, W2, b2, out);
}